// Round 1
// baseline (1497.061 us; speedup 1.0000x reference)
//
#include <hip/hip_runtime.h>
#include <cstdint>
#include <cstddef>

#define NN 10000
#define NE 160000
#define ET (NE + NN)          // edges + self loops
#define FIN 2000

// ---------------------------------------------------------------------------
// CSR build
// ---------------------------------------------------------------------------
__device__ __forceinline__ void edge_sd(const int* ei, int e, int& s, int& d) {
    if (e < NE) { s = ei[e]; d = ei[NE + e]; }
    else        { s = e - NE; d = e - NE; }
}

__global__ void count_kernel(const int* ei, int* deg) {
    int e = blockIdx.x * blockDim.x + threadIdx.x;
    if (e >= ET) return;
    int s, d; edge_sd(ei, e, s, d);
    atomicAdd(&deg[d], 1);
}

__global__ void dinv_kernel(const int* deg, float* dinv) {
    int n = blockIdx.x * blockDim.x + threadIdx.x;
    if (n >= NN) return;
    int dg = deg[n];
    dinv[n] = dg > 0 ? rsqrtf((float)dg) : 0.f;
}

// single-block exclusive scan over deg -> rowstart[0..NN], rowstart[NN]=total
__global__ void scan_kernel(const int* deg, int* rowstart) {
    __shared__ int partial[256];
    const int T = 256;
    int chunk = (NN + T - 1) / T;
    int t = threadIdx.x;
    int begin = t * chunk;
    int end = begin + chunk; if (end > NN) end = NN;
    int s = 0;
    for (int i = begin; i < end && i >= begin; i++) s += deg[i];
    partial[t] = s;
    __syncthreads();
    if (t == 0) {
        int run = 0;
        for (int i = 0; i < T; i++) { int v = partial[i]; partial[i] = run; run += v; }
    }
    __syncthreads();
    int run = partial[t];
    for (int i = begin; i < end && i >= begin; i++) { rowstart[i] = run; run += deg[i]; }
    if (end == NN && begin <= NN) rowstart[NN] = run;
}

__global__ void scatter_kernel(const int* ei, const int* rowstart, int* cursor,
                               int* csr_src, int* csr_eid) {
    int e = blockIdx.x * blockDim.x + threadIdx.x;
    if (e >= ET) return;
    int s, d; edge_sd(ei, e, s, d);
    int pos = atomicAdd(&cursor[d], 1);
    int slot = rowstart[d] + pos;
    csr_src[slot] = s;
    csr_eid[slot] = e;
}

// ---------------------------------------------------------------------------
// Generic fp32 tiled GEMM: C[M,N] = A[M,K](lda) @ B[K,N](ldb) [+bias][relu]
// 64x64 block tile, 256 threads, 4x4 per-thread microtile, BK=16.
// Requires K % 16 == 0 and N % 64 == 0 (true for all uses here).
// ---------------------------------------------------------------------------
template<bool RELU, bool BIAS>
__global__ void gemm_kernel(const float* __restrict__ A, int lda,
                            const float* __restrict__ B, int ldb,
                            float* __restrict__ C, int ldc,
                            const float* __restrict__ bias,
                            int M, int N, int K) {
    __shared__ float As[16][65];
    __shared__ float Bs[16][64];
    int bi = blockIdx.y * 64, bj = blockIdx.x * 64;
    int tid = threadIdx.x;
    int tx = tid & 15, ty = tid >> 4;
    float acc[4][4] = {};
    for (int k0 = 0; k0 < K; k0 += 16) {
        {
            int kk = tid & 15, mm = tid >> 4;
#pragma unroll
            for (int it = 0; it < 4; it++) {
                int row = mm + 16 * it;
                int gr = bi + row;
                As[kk][row] = (gr < M) ? A[(size_t)gr * lda + k0 + kk] : 0.f;
            }
        }
        {
            int nn = tid & 63, kk = tid >> 6;
#pragma unroll
            for (int it = 0; it < 4; it++)
                Bs[kk + 4 * it][nn] = B[(size_t)(k0 + kk + 4 * it) * ldb + bj + nn];
        }
        __syncthreads();
#pragma unroll
        for (int kk = 0; kk < 16; kk++) {
            float av[4], bv[4];
#pragma unroll
            for (int a = 0; a < 4; a++) av[a] = As[kk][ty * 4 + a];
#pragma unroll
            for (int b = 0; b < 4; b++) bv[b] = Bs[kk][tx * 4 + b];
#pragma unroll
            for (int a = 0; a < 4; a++)
#pragma unroll
                for (int b = 0; b < 4; b++)
                    acc[a][b] += av[a] * bv[b];
        }
        __syncthreads();
    }
#pragma unroll
    for (int a = 0; a < 4; a++) {
        int gr = bi + ty * 4 + a;
        if (gr >= M) continue;
#pragma unroll
        for (int b = 0; b < 4; b++) {
            int gc = bj + tx * 4 + b;
            float v = acc[a][b];
            if (BIAS) v += bias[gc];
            if (RELU) v = fmaxf(v, 0.f);
            C[(size_t)gr * ldc + gc] = v;
        }
    }
}

// ---------------------------------------------------------------------------
// GAT pieces
// ---------------------------------------------------------------------------
// per-(node,head) dual dot: asrc[n*H+h] = sum_c h1[n, h*128+c]*a_src[h,c]
__global__ void alpha_kernel(const float* __restrict__ h,
                             const float* __restrict__ a_src,
                             const float* __restrict__ a_dst,
                             float* __restrict__ asrc_o, float* __restrict__ adst_o,
                             int H) {
    int b = blockIdx.x;          // = n*H + hh
    int n = b / H, hh = b % H;
    int l = threadIdx.x;         // 64 threads = 1 wave
    const float* hp = h + (size_t)n * (H * 128) + hh * 128;
    const float* as = a_src + hh * 128;
    const float* ad = a_dst + hh * 128;
    float v0 = hp[l], v1 = hp[l + 64];
    float s1 = v0 * as[l] + v1 * as[l + 64];
    float s2 = v0 * ad[l] + v1 * ad[l + 64];
#pragma unroll
    for (int off = 32; off; off >>= 1) {
        s1 += __shfl_down(s1, off);
        s2 += __shfl_down(s2, off);
    }
    if (l == 0) { asrc_o[b] = s1; adst_o[b] = s2; }
}

// per-edge: ew = exp(leaky_relu(asrc[src]+adst[dst])), denom[dst] += ew
// (segment-softmax is shift-invariant; alpha is O(1) so max-shift is skipped)
__global__ void edge_kernel(const int* __restrict__ ei,
                            const float* __restrict__ asrc,
                            const float* __restrict__ adst,
                            float* __restrict__ ew, float* __restrict__ denom, int H) {
    int e = blockIdx.x * blockDim.x + threadIdx.x;
    if (e >= ET) return;
    int s, d; edge_sd(ei, e, s, d);
    for (int h = 0; h < H; h++) {
        float al = asrc[s * H + h] + adst[d * H + h];
        al = al >= 0.f ? al : 0.2f * al;
        float ev = expf(al);
        ew[(size_t)e * H + h] = ev;
        atomicAdd(&denom[d * H + h], ev);
    }
}

// per-node GAT aggregation + head-mean + bias + LayerNorm + ReLU
template<int H>
__global__ void gat_agg_kernel(const float* __restrict__ h,
                               const float* __restrict__ ew,
                               const float* __restrict__ denom,
                               const int* __restrict__ rowstart,
                               const int* __restrict__ csr_src,
                               const int* __restrict__ csr_eid,
                               const float* __restrict__ bias,
                               const float* __restrict__ gamma,
                               const float* __restrict__ beta,
                               float* __restrict__ out, int ldo) {
    constexpr int CH = H * 128;
    constexpr int PER = CH / 256;
    int n = blockIdx.x;
    int t = threadIdx.x;
    __shared__ float invden[H];
    __shared__ float sm[CH];
    __shared__ float red[8];
    if (t < H) invden[t] = 1.f / denom[n * H + t];
    __syncthreads();
    float acc[PER] = {};
    int s0 = rowstart[n], s1 = rowstart[n + 1];
    for (int s = s0; s < s1; s++) {
        int src = csr_src[s];
        int eid = csr_eid[s];
        const float* hp = h + (size_t)src * CH;
        const float* ep = ew + (size_t)eid * H;
#pragma unroll
        for (int j = 0; j < PER; j++) {
            int ch = t + 256 * j;
            int hh = ch >> 7;
            acc[j] += hp[ch] * (ep[hh] * invden[hh]);
        }
    }
#pragma unroll
    for (int j = 0; j < PER; j++) sm[t + 256 * j] = acc[j];
    __syncthreads();
    float v = 0.f;
    if (t < 128) {
#pragma unroll
        for (int hh = 0; hh < H; hh++) v += sm[hh * 128 + t];
        v = v * (1.f / H) + bias[t];
    }
    float sv = (t < 128) ? v : 0.f;
    float sq = (t < 128) ? v * v : 0.f;
#pragma unroll
    for (int off = 32; off; off >>= 1) {
        sv += __shfl_down(sv, off);
        sq += __shfl_down(sq, off);
    }
    if ((t & 63) == 0) { red[(t >> 6) * 2] = sv; red[(t >> 6) * 2 + 1] = sq; }
    __syncthreads();
    float tot = red[0] + red[2] + red[4] + red[6];
    float tsq = red[1] + red[3] + red[5] + red[7];
    float mu = tot * (1.f / 128.f);
    float var = tsq * (1.f / 128.f) - mu * mu;
    float r = rsqrtf(var + 1e-5f);
    if (t < 128) {
        float o = (v - mu) * r * gamma[t] + beta[t];
        out[(size_t)n * ldo + t] = fmaxf(o, 0.f);
    }
}

// per-node GCN aggregation: out = relu(dinv[n]*sum(y[src]*dinv[src]) + b)
__global__ void gcn_agg_kernel(const float* __restrict__ y, int C,
                               const float* __restrict__ dinv,
                               const int* __restrict__ rowstart,
                               const int* __restrict__ csr_src,
                               const float* __restrict__ bias,
                               float* __restrict__ out, int ldo, int coloff) {
    int n = blockIdx.x;
    int t = threadIdx.x;  // blockDim == C
    float acc = 0.f;
    int s0 = rowstart[n], s1 = rowstart[n + 1];
    for (int s = s0; s < s1; s++) {
        int src = csr_src[s];
        acc += y[(size_t)src * C + t] * dinv[src];
    }
    float v = acc * dinv[n] + bias[t];
    out[(size_t)n * ldo + coloff + t] = fmaxf(v, 0.f);
}

// final = LN(fused+skip); then 64->32->16->5 MLP. One wave per node.
__global__ void final_kernel(const float* __restrict__ fused,
                             const float* __restrict__ skip,
                             const float* __restrict__ g3, const float* __restrict__ be3,
                             const float* __restrict__ Wc1, const float* __restrict__ bc1,
                             const float* __restrict__ Wc2, const float* __restrict__ bc2,
                             const float* __restrict__ Wc3, const float* __restrict__ bc3,
                             float* __restrict__ out) {
    int n = blockIdx.x;
    int l = threadIdx.x;  // 64
    __shared__ float f[64], h1s[32], h2s[16];
    float v = fused[(size_t)n * 64 + l] + skip[(size_t)n * 64 + l];
    float sv = v, sq = v * v;
#pragma unroll
    for (int off = 32; off; off >>= 1) {
        sv += __shfl_xor(sv, off);
        sq += __shfl_xor(sq, off);
    }
    float mu = sv * (1.f / 64.f);
    float var = sq * (1.f / 64.f) - mu * mu;
    float r = rsqrtf(var + 1e-5f);
    f[l] = (v - mu) * r * g3[l] + be3[l];
    __syncthreads();
    if (l < 32) {
        float a = bc1[l];
        for (int i = 0; i < 64; i++) a += f[i] * Wc1[i * 32 + l];
        h1s[l] = fmaxf(a, 0.f);
    }
    __syncthreads();
    if (l < 16) {
        float a = bc2[l];
        for (int i = 0; i < 32; i++) a += h1s[i] * Wc2[i * 16 + l];
        h2s[l] = fmaxf(a, 0.f);
    }
    __syncthreads();
    if (l < 5) {
        float a = bc3[l];
        for (int i = 0; i < 16; i++) a += h2s[i] * Wc3[i * 5 + l];
        out[(size_t)n * 5 + l] = a;
    }
}

// ---------------------------------------------------------------------------
extern "C" void kernel_launch(void* const* d_in, const int* in_sizes, int n_in,
                              void* d_out, int out_size, void* d_ws, size_t ws_size,
                              hipStream_t stream) {
    const float* x      = (const float*)d_in[0];
    const int*   ei     = (const int*)d_in[1];
    const float* W_gat1 = (const float*)d_in[2];
    const float* a_src1 = (const float*)d_in[3];
    const float* a_dst1 = (const float*)d_in[4];
    const float* b_gat1 = (const float*)d_in[5];
    const float* W_gcn1 = (const float*)d_in[6];
    const float* b_gcn1 = (const float*)d_in[7];
    const float* W_gat2 = (const float*)d_in[8];
    const float* a_src2 = (const float*)d_in[9];
    const float* a_dst2 = (const float*)d_in[10];
    const float* b_gat2 = (const float*)d_in[11];
    const float* W_gcn2 = (const float*)d_in[12];
    const float* b_gcn2 = (const float*)d_in[13];
    const float* W_skip = (const float*)d_in[14];
    const float* b_skip = (const float*)d_in[15];
    const float* W_fuse = (const float*)d_in[16];
    const float* b_fuse = (const float*)d_in[17];
    const float* W_c1   = (const float*)d_in[18];
    const float* b_c1   = (const float*)d_in[19];
    const float* W_c2   = (const float*)d_in[20];
    const float* b_c2   = (const float*)d_in[21];
    const float* W_c3   = (const float*)d_in[22];
    const float* b_c3   = (const float*)d_in[23];
    const float* g1     = (const float*)d_in[24];
    const float* be1    = (const float*)d_in[25];
    const float* g2     = (const float*)d_in[26];
    const float* be2    = (const float*)d_in[27];
    const float* g3     = (const float*)d_in[28];
    const float* be3    = (const float*)d_in[29];
    float* out = (float*)d_out;

    // workspace arena (~66 MB)
    char* p = (char*)d_ws;
    auto alloc = [&](size_t bytes) {
        char* r = p; p += (bytes + 255) & ~(size_t)255; return r;
    };
    float* h1     = (float*)alloc((size_t)NN * 768 * 4);   // reused as h2 [NN,512]
    float* asrc   = (float*)alloc((size_t)NN * 6 * 4);     // reused for layer 2 (H=4)
    float* adst   = (float*)alloc((size_t)NN * 6 * 4);
    float* ew     = (float*)alloc((size_t)ET * 6 * 4);     // reused for layer 2
    float* den1   = (float*)alloc((size_t)NN * 6 * 4);
    float* den2   = (float*)alloc((size_t)NN * 4 * 4);
    int*   deg    = (int*)  alloc((size_t)NN * 4);
    float* dinv   = (float*)alloc((size_t)NN * 4);
    int*   rowst  = (int*)  alloc((size_t)(NN + 1) * 4);
    int*   cursor = (int*)  alloc((size_t)NN * 4);
    int*   csrc   = (int*)  alloc((size_t)ET * 4);
    int*   ceid   = (int*)  alloc((size_t)ET * 4);
    float* x1gat  = (float*)alloc((size_t)NN * 128 * 4);
    float* ybuf   = (float*)alloc((size_t)NN * 128 * 4);   // y1, reused as y2 [NN,64]
    float* cat    = (float*)alloc((size_t)NN * 192 * 4);   // [x1_gcn | x2_gcn]
    float* x2gat  = (float*)alloc((size_t)NN * 128 * 4);
    float* skip   = (float*)alloc((size_t)NN * 64 * 4);
    float* fusedb = (float*)alloc((size_t)NN * 64 * 4);

    hipMemsetAsync(deg,    0, (size_t)NN * 4, stream);
    hipMemsetAsync(cursor, 0, (size_t)NN * 4, stream);
    hipMemsetAsync(den1,   0, (size_t)NN * 6 * 4, stream);
    hipMemsetAsync(den2,   0, (size_t)NN * 4 * 4, stream);

    const int EB = (ET + 255) / 256;
    const int MB = (NN + 63) / 64;   // 157 row-blocks for GEMMs

    // CSR by dst (also gives GCN degrees)
    count_kernel  <<<EB, 256, 0, stream>>>(ei, deg);
    dinv_kernel   <<<(NN + 255) / 256, 256, 0, stream>>>(deg, dinv);
    scan_kernel   <<<1, 256, 0, stream>>>(deg, rowst);
    scatter_kernel<<<EB, 256, 0, stream>>>(ei, rowst, cursor, csrc, ceid);

    // h1 = x @ W_gat1  [NN,768]   (dominant GEMM)
    gemm_kernel<false, false><<<dim3(768 / 64, MB), 256, 0, stream>>>(
        x, FIN, W_gat1, 768, h1, 768, nullptr, NN, 768, FIN);
    // skip = relu(x @ W_skip + b_skip)  [NN,64]
    gemm_kernel<true, true><<<dim3(1, MB), 256, 0, stream>>>(
        x, FIN, W_skip, 64, skip, 64, b_skip, NN, 64, FIN);

    // ---- GAT layer 1 (H=6) ----
    alpha_kernel<<<NN * 6, 64, 0, stream>>>(h1, a_src1, a_dst1, asrc, adst, 6);
    edge_kernel <<<EB, 256, 0, stream>>>(ei, asrc, adst, ew, den1, 6);
    gat_agg_kernel<6><<<NN, 256, 0, stream>>>(h1, ew, den1, rowst, csrc, ceid,
                                              b_gat1, g1, be1, x1gat, 128);
    // ---- GCN layer 1 ----
    gemm_kernel<false, false><<<dim3(2, MB), 256, 0, stream>>>(
        x1gat, 128, W_gcn1, 128, ybuf, 128, nullptr, NN, 128, 128);
    gcn_agg_kernel<<<NN, 128, 0, stream>>>(ybuf, 128, dinv, rowst, csrc,
                                           b_gcn1, cat, 192, 0);
    // ---- GAT layer 2 (H=4), input x1_gcn = cat[:, :128] (lda=192) ----
    gemm_kernel<false, false><<<dim3(8, MB), 256, 0, stream>>>(
        cat, 192, W_gat2, 512, h1, 512, nullptr, NN, 512, 128);
    alpha_kernel<<<NN * 4, 64, 0, stream>>>(h1, a_src2, a_dst2, asrc, adst, 4);
    edge_kernel <<<EB, 256, 0, stream>>>(ei, asrc, adst, ew, den2, 4);
    gat_agg_kernel<4><<<NN, 256, 0, stream>>>(h1, ew, den2, rowst, csrc, ceid,
                                              b_gat2, g2, be2, x2gat, 128);
    // ---- GCN layer 2 -> cat[:, 128:192] ----
    gemm_kernel<false, false><<<dim3(1, MB), 256, 0, stream>>>(
        x2gat, 128, W_gcn2, 64, ybuf, 64, nullptr, NN, 64, 128);
    gcn_agg_kernel<<<NN, 64, 0, stream>>>(ybuf, 64, dinv, rowst, csrc,
                                          b_gcn2, cat, 192, 128);
    // ---- fuse + final ----
    gemm_kernel<true, true><<<dim3(1, MB), 256, 0, stream>>>(
        cat, 192, W_fuse, 64, fusedb, 64, b_fuse, NN, 64, 192);
    final_kernel<<<NN, 64, 0, stream>>>(fusedb, skip, g3, be3,
                                        W_c1, b_c1, W_c2, b_c2, W_c3, b_c3, out);
}

// Round 2
// 745.810 us; speedup vs baseline: 2.0073x; 2.0073x over previous
//
#include <hip/hip_runtime.h>
#include <cstdint>
#include <cstddef>

#define NN 10000
#define NE 160000
#define ET (NE + NN)          // edges + self loops
#define FIN 2000
#define MPAD 10112            // 79 * 128
#define KPAD 2048
#define NPAD 896              // 7 * 128 (768 gat1 cols + 64 skip cols + 64 pad)

typedef __bf16 bf16x8 __attribute__((ext_vector_type(8)));
typedef __bf16 bf16x4 __attribute__((ext_vector_type(4)));
typedef float  f32x4  __attribute__((ext_vector_type(4)));

// ---------------------------------------------------------------------------
// CSR build
// ---------------------------------------------------------------------------
__device__ __forceinline__ void edge_sd(const int* ei, int e, int& s, int& d) {
    if (e < NE) { s = ei[e]; d = ei[NE + e]; }
    else        { s = e - NE; d = e - NE; }
}

__global__ void count_kernel(const int* ei, int* deg) {
    int e = blockIdx.x * blockDim.x + threadIdx.x;
    if (e >= ET) return;
    int s, d; edge_sd(ei, e, s, d);
    atomicAdd(&deg[d], 1);
}

__global__ void dinv_kernel(const int* deg, float* dinv) {
    int n = blockIdx.x * blockDim.x + threadIdx.x;
    if (n >= NN) return;
    int dg = deg[n];
    dinv[n] = dg > 0 ? rsqrtf((float)dg) : 0.f;
}

__global__ void scan_kernel(const int* deg, int* rowstart) {
    __shared__ int partial[256];
    const int T = 256;
    int chunk = (NN + T - 1) / T;
    int t = threadIdx.x;
    int begin = t * chunk;
    int end = begin + chunk; if (end > NN) end = NN;
    int s = 0;
    for (int i = begin; i < end && i >= begin; i++) s += deg[i];
    partial[t] = s;
    __syncthreads();
    if (t == 0) {
        int run = 0;
        for (int i = 0; i < T; i++) { int v = partial[i]; partial[i] = run; run += v; }
    }
    __syncthreads();
    int run = partial[t];
    for (int i = begin; i < end && i >= begin; i++) { rowstart[i] = run; run += deg[i]; }
    if (end == NN && begin <= NN) rowstart[NN] = run;
}

__global__ void scatter_kernel(const int* ei, const int* rowstart, int* cursor,
                               int* csr_src, int* csr_eid) {
    int e = blockIdx.x * blockDim.x + threadIdx.x;
    if (e >= ET) return;
    int s, d; edge_sd(ei, e, s, d);
    int pos = atomicAdd(&cursor[d], 1);
    int slot = rowstart[d] + pos;
    csr_src[slot] = s;
    csr_eid[slot] = e;
}

// ---------------------------------------------------------------------------
// bf16 conversion kernels for the dominant GEMM
// ---------------------------------------------------------------------------
// xb[MPAD][KPAD] = bf16(x[r][k]) zero-padded
__global__ void conv_x_kernel(const float* __restrict__ x, __bf16* __restrict__ xb) {
    int g = blockIdx.x * blockDim.x + threadIdx.x;   // over MPAD * (KPAD/4)
    if (g >= MPAD * (KPAD / 4)) return;
    int r = g / (KPAD / 4);
    int k4 = (g % (KPAD / 4)) * 4;
    bf16x4 o;
    if (r < NN && k4 + 3 < FIN) {
        const float4 v = *(const float4*)(x + (size_t)r * FIN + k4);
        o[0] = (__bf16)v.x; o[1] = (__bf16)v.y; o[2] = (__bf16)v.z; o[3] = (__bf16)v.w;
    } else {
        o[0] = o[1] = o[2] = o[3] = (__bf16)0.f;
    }
    *(bf16x4*)(xb + (size_t)r * KPAD + k4) = o;
}

// wt[n][k] = n<768 ? W_gat1[k*768+n] : n<832 ? W_skip[k*64+(n-768)] : 0 (k<2000)
__global__ void conv_w_kernel(const float* __restrict__ Wg, const float* __restrict__ Ws,
                              __bf16* __restrict__ wt) {
    int g = blockIdx.x * blockDim.x + threadIdx.x;   // over NPAD * (KPAD/4)
    if (g >= NPAD * (KPAD / 4)) return;
    int n = g / (KPAD / 4);
    int k4 = (g % (KPAD / 4)) * 4;
    bf16x4 o;
#pragma unroll
    for (int i = 0; i < 4; i++) {
        int k = k4 + i;
        float v = 0.f;
        if (k < FIN) {
            if (n < 768)      v = Wg[(size_t)k * 768 + n];
            else if (n < 832) v = Ws[(size_t)k * 64 + (n - 768)];
        }
        o[i] = (__bf16)v;
    }
    *(bf16x4*)(wt + (size_t)n * KPAD + k4) = o;
}

// ---------------------------------------------------------------------------
// MFMA bf16 GEMM: [MPAD,KPAD] @ [KPAD,NPAD(^T stored)] -> h1[NN,768], skippre[NN,64]
// 128x128 tile, 256 threads (4 waves in 2x2), BK=32, global_load_lds width 16.
// LDS layout: 4 k-planes (quad q covers k=q*8..q*8+7), each plane 128 rows x 16B.
// ---------------------------------------------------------------------------
__global__ __launch_bounds__(256)
void mfma_gemm_kernel(const __bf16* __restrict__ xb, const __bf16* __restrict__ wt,
                      float* __restrict__ h1, float* __restrict__ skippre) {
    __shared__ __bf16 As[4096];   // 8 KB
    __shared__ __bf16 Bs[4096];   // 8 KB
    const int tid = threadIdx.x;
    const int lane = tid & 63;
    const int w = tid >> 6;
    const int wm = w >> 1, wn = w & 1;
    const int bi = blockIdx.y * 128;
    const int bn = blockIdx.x * 128;
    const int q = lane >> 4, m16 = lane & 15;

    // staging chunk ids: chunk cl = plane*128 + row ; lds offset = cl*16B
    const int cl0 = w * 128 + lane;
    const int cl1 = cl0 + 64;
    const int cc0 = cl0 >> 7, r0 = cl0 & 127;
    const int cc1 = cl1 >> 7, r1 = cl1 & 127;

    f32x4 acc[4][4] = {};

    for (int k0 = 0; k0 < KPAD; k0 += 32) {
        // ---- stage A tile ----
        __builtin_amdgcn_global_load_lds(
            (const __attribute__((address_space(1))) void*)(xb + (size_t)(bi + r0) * KPAD + k0 + cc0 * 8),
            (__attribute__((address_space(3))) void*)(As + w * 1024), 16, 0, 0);
        __builtin_amdgcn_global_load_lds(
            (const __attribute__((address_space(1))) void*)(xb + (size_t)(bi + r1) * KPAD + k0 + cc1 * 8),
            (__attribute__((address_space(3))) void*)(As + w * 1024 + 512), 16, 0, 0);
        // ---- stage B tile (wt rows are N) ----
        __builtin_amdgcn_global_load_lds(
            (const __attribute__((address_space(1))) void*)(wt + (size_t)(bn + r0) * KPAD + k0 + cc0 * 8),
            (__attribute__((address_space(3))) void*)(Bs + w * 1024), 16, 0, 0);
        __builtin_amdgcn_global_load_lds(
            (const __attribute__((address_space(1))) void*)(wt + (size_t)(bn + r1) * KPAD + k0 + cc1 * 8),
            (__attribute__((address_space(3))) void*)(Bs + w * 1024 + 512), 16, 0, 0);
        __syncthreads();

        bf16x8 af[4], bf[4];
#pragma unroll
        for (int mt = 0; mt < 4; mt++)
            af[mt] = *(const bf16x8*)(As + q * 1024 + (wm * 64 + mt * 16 + m16) * 8);
#pragma unroll
        for (int nt = 0; nt < 4; nt++)
            bf[nt] = *(const bf16x8*)(Bs + q * 1024 + (wn * 64 + nt * 16 + m16) * 8);
#pragma unroll
        for (int mt = 0; mt < 4; mt++)
#pragma unroll
            for (int nt = 0; nt < 4; nt++)
                acc[mt][nt] = __builtin_amdgcn_mfma_f32_16x16x32_bf16(af[mt], bf[nt], acc[mt][nt], 0, 0, 0);
        __syncthreads();
    }

    // epilogue: C row = (lane>>4)*4 + reg, col = lane&15  (verified m89/m91)
#pragma unroll
    for (int mt = 0; mt < 4; mt++) {
#pragma unroll
        for (int r = 0; r < 4; r++) {
            int row = bi + wm * 64 + mt * 16 + q * 4 + r;
            if (row >= NN) continue;
#pragma unroll
            for (int nt = 0; nt < 4; nt++) {
                int col = bn + wn * 64 + nt * 16 + m16;
                float v = acc[mt][nt][r];
                if (col < 768)      h1[(size_t)row * 768 + col] = v;
                else if (col < 832) skippre[(size_t)row * 64 + (col - 768)] = v;
            }
        }
    }
}

// ---------------------------------------------------------------------------
// Generic fp32 tiled GEMM (small GEMMs): 64x64 tile, 256 thr, 4x4 microtile
// ---------------------------------------------------------------------------
template<bool RELU, bool BIAS>
__global__ void gemm_kernel(const float* __restrict__ A, int lda,
                            const float* __restrict__ B, int ldb,
                            float* __restrict__ C, int ldc,
                            const float* __restrict__ bias,
                            int M, int N, int K) {
    __shared__ float As[16][65];
    __shared__ float Bs[16][64];
    int bi = blockIdx.y * 64, bj = blockIdx.x * 64;
    int tid = threadIdx.x;
    int tx = tid & 15, ty = tid >> 4;
    float acc[4][4] = {};
    for (int k0 = 0; k0 < K; k0 += 16) {
        {
            int kk = tid & 15, mm = tid >> 4;
#pragma unroll
            for (int it = 0; it < 4; it++) {
                int row = mm + 16 * it;
                int gr = bi + row;
                As[kk][row] = (gr < M) ? A[(size_t)gr * lda + k0 + kk] : 0.f;
            }
        }
        {
            int nn = tid & 63, kk = tid >> 6;
#pragma unroll
            for (int it = 0; it < 4; it++)
                Bs[kk + 4 * it][nn] = B[(size_t)(k0 + kk + 4 * it) * ldb + bj + nn];
        }
        __syncthreads();
#pragma unroll
        for (int kk = 0; kk < 16; kk++) {
            float av[4], bv[4];
#pragma unroll
            for (int a = 0; a < 4; a++) av[a] = As[kk][ty * 4 + a];
#pragma unroll
            for (int b = 0; b < 4; b++) bv[b] = Bs[kk][tx * 4 + b];
#pragma unroll
            for (int a = 0; a < 4; a++)
#pragma unroll
                for (int b = 0; b < 4; b++)
                    acc[a][b] += av[a] * bv[b];
        }
        __syncthreads();
    }
#pragma unroll
    for (int a = 0; a < 4; a++) {
        int gr = bi + ty * 4 + a;
        if (gr >= M) continue;
#pragma unroll
        for (int b = 0; b < 4; b++) {
            int gc = bj + tx * 4 + b;
            float v = acc[a][b];
            if (BIAS) v += bias[gc];
            if (RELU) v = fmaxf(v, 0.f);
            C[(size_t)gr * ldc + gc] = v;
        }
    }
}

// ---------------------------------------------------------------------------
// GAT pieces
// ---------------------------------------------------------------------------
__global__ void alpha_kernel(const float* __restrict__ h,
                             const float* __restrict__ a_src,
                             const float* __restrict__ a_dst,
                             float* __restrict__ asrc_o, float* __restrict__ adst_o,
                             int H) {
    int b = blockIdx.x;          // = n*H + hh
    int n = b / H, hh = b % H;
    int l = threadIdx.x;         // 64 threads = 1 wave
    const float* hp = h + (size_t)n * (H * 128) + hh * 128;
    const float* as = a_src + hh * 128;
    const float* ad = a_dst + hh * 128;
    float v0 = hp[l], v1 = hp[l + 64];
    float s1 = v0 * as[l] + v1 * as[l + 64];
    float s2 = v0 * ad[l] + v1 * ad[l + 64];
#pragma unroll
    for (int off = 32; off; off >>= 1) {
        s1 += __shfl_down(s1, off);
        s2 += __shfl_down(s2, off);
    }
    if (l == 0) { asrc_o[b] = s1; adst_o[b] = s2; }
}

__global__ void edge_kernel(const int* __restrict__ ei,
                            const float* __restrict__ asrc,
                            const float* __restrict__ adst,
                            float* __restrict__ ew, float* __restrict__ denom, int H) {
    int e = blockIdx.x * blockDim.x + threadIdx.x;
    if (e >= ET) return;
    int s, d; edge_sd(ei, e, s, d);
    for (int h = 0; h < H; h++) {
        float al = asrc[s * H + h] + adst[d * H + h];
        al = al >= 0.f ? al : 0.2f * al;
        float ev = expf(al);
        ew[(size_t)e * H + h] = ev;
        atomicAdd(&denom[d * H + h], ev);
    }
}

template<int H>
__global__ void gat_agg_kernel(const float* __restrict__ h,
                               const float* __restrict__ ew,
                               const float* __restrict__ denom,
                               const int* __restrict__ rowstart,
                               const int* __restrict__ csr_src,
                               const int* __restrict__ csr_eid,
                               const float* __restrict__ bias,
                               const float* __restrict__ gamma,
                               const float* __restrict__ beta,
                               float* __restrict__ out, int ldo) {
    constexpr int CH = H * 128;
    constexpr int PER = CH / 256;
    int n = blockIdx.x;
    int t = threadIdx.x;
    __shared__ float invden[H];
    __shared__ float sm[CH];
    __shared__ float red[8];
    if (t < H) invden[t] = 1.f / denom[n * H + t];
    __syncthreads();
    float acc[PER] = {};
    int s0 = rowstart[n], s1 = rowstart[n + 1];
    for (int s = s0; s < s1; s++) {
        int src = csr_src[s];
        int eid = csr_eid[s];
        const float* hp = h + (size_t)src * CH;
        const float* ep = ew + (size_t)eid * H;
#pragma unroll
        for (int j = 0; j < PER; j++) {
            int ch = t + 256 * j;
            int hh = ch >> 7;
            acc[j] += hp[ch] * (ep[hh] * invden[hh]);
        }
    }
#pragma unroll
    for (int j = 0; j < PER; j++) sm[t + 256 * j] = acc[j];
    __syncthreads();
    float v = 0.f;
    if (t < 128) {
#pragma unroll
        for (int hh = 0; hh < H; hh++) v += sm[hh * 128 + t];
        v = v * (1.f / H) + bias[t];
    }
    float sv = (t < 128) ? v : 0.f;
    float sq = (t < 128) ? v * v : 0.f;
#pragma unroll
    for (int off = 32; off; off >>= 1) {
        sv += __shfl_down(sv, off);
        sq += __shfl_down(sq, off);
    }
    if ((t & 63) == 0) { red[(t >> 6) * 2] = sv; red[(t >> 6) * 2 + 1] = sq; }
    __syncthreads();
    float tot = red[0] + red[2] + red[4] + red[6];
    float tsq = red[1] + red[3] + red[5] + red[7];
    float mu = tot * (1.f / 128.f);
    float var = tsq * (1.f / 128.f) - mu * mu;
    float r = rsqrtf(var + 1e-5f);
    if (t < 128) {
        float o = (v - mu) * r * gamma[t] + beta[t];
        out[(size_t)n * ldo + t] = fmaxf(o, 0.f);
    }
}

__global__ void gcn_agg_kernel(const float* __restrict__ y, int C,
                               const float* __restrict__ dinv,
                               const int* __restrict__ rowstart,
                               const int* __restrict__ csr_src,
                               const float* __restrict__ bias,
                               float* __restrict__ out, int ldo, int coloff) {
    int n = blockIdx.x;
    int t = threadIdx.x;  // blockDim == C
    float acc = 0.f;
    int s0 = rowstart[n], s1 = rowstart[n + 1];
    for (int s = s0; s < s1; s++) {
        int src = csr_src[s];
        acc += y[(size_t)src * C + t] * dinv[src];
    }
    float v = acc * dinv[n] + bias[t];
    out[(size_t)n * ldo + coloff + t] = fmaxf(v, 0.f);
}

// final = LN(fused + relu(skippre + b_skip)); then 64->32->16->5 MLP.
__global__ void final_kernel(const float* __restrict__ fused,
                             const float* __restrict__ skippre,
                             const float* __restrict__ b_skip,
                             const float* __restrict__ g3, const float* __restrict__ be3,
                             const float* __restrict__ Wc1, const float* __restrict__ bc1,
                             const float* __restrict__ Wc2, const float* __restrict__ bc2,
                             const float* __restrict__ Wc3, const float* __restrict__ bc3,
                             float* __restrict__ out) {
    int n = blockIdx.x;
    int l = threadIdx.x;  // 64
    __shared__ float f[64], h1s[32], h2s[16];
    float sk = fmaxf(skippre[(size_t)n * 64 + l] + b_skip[l], 0.f);
    float v = fused[(size_t)n * 64 + l] + sk;
    float sv = v, sq = v * v;
#pragma unroll
    for (int off = 32; off; off >>= 1) {
        sv += __shfl_xor(sv, off);
        sq += __shfl_xor(sq, off);
    }
    float mu = sv * (1.f / 64.f);
    float var = sq * (1.f / 64.f) - mu * mu;
    float r = rsqrtf(var + 1e-5f);
    f[l] = (v - mu) * r * g3[l] + be3[l];
    __syncthreads();
    if (l < 32) {
        float a = bc1[l];
        for (int i = 0; i < 64; i++) a += f[i] * Wc1[i * 32 + l];
        h1s[l] = fmaxf(a, 0.f);
    }
    __syncthreads();
    if (l < 16) {
        float a = bc2[l];
        for (int i = 0; i < 32; i++) a += h1s[i] * Wc2[i * 16 + l];
        h2s[l] = fmaxf(a, 0.f);
    }
    __syncthreads();
    if (l < 5) {
        float a = bc3[l];
        for (int i = 0; i < 16; i++) a += h2s[i] * Wc3[i * 5 + l];
        out[(size_t)n * 5 + l] = a;
    }
}

// ---------------------------------------------------------------------------
extern "C" void kernel_launch(void* const* d_in, const int* in_sizes, int n_in,
                              void* d_out, int out_size, void* d_ws, size_t ws_size,
                              hipStream_t stream) {
    const float* x      = (const float*)d_in[0];
    const int*   ei     = (const int*)d_in[1];
    const float* W_gat1 = (const float*)d_in[2];
    const float* a_src1 = (const float*)d_in[3];
    const float* a_dst1 = (const float*)d_in[4];
    const float* b_gat1 = (const float*)d_in[5];
    const float* W_gcn1 = (const float*)d_in[6];
    const float* b_gcn1 = (const float*)d_in[7];
    const float* W_gat2 = (const float*)d_in[8];
    const float* a_src2 = (const float*)d_in[9];
    const float* a_dst2 = (const float*)d_in[10];
    const float* b_gat2 = (const float*)d_in[11];
    const float* W_gcn2 = (const float*)d_in[12];
    const float* b_gcn2 = (const float*)d_in[13];
    const float* W_skip = (const float*)d_in[14];
    const float* b_skip = (const float*)d_in[15];
    const float* W_fuse = (const float*)d_in[16];
    const float* b_fuse = (const float*)d_in[17];
    const float* W_c1   = (const float*)d_in[18];
    const float* b_c1   = (const float*)d_in[19];
    const float* W_c2   = (const float*)d_in[20];
    const float* b_c2   = (const float*)d_in[21];
    const float* W_c3   = (const float*)d_in[22];
    const float* b_c3   = (const float*)d_in[23];
    const float* g1     = (const float*)d_in[24];
    const float* be1    = (const float*)d_in[25];
    const float* g2     = (const float*)d_in[26];
    const float* be2    = (const float*)d_in[27];
    const float* g3     = (const float*)d_in[28];
    const float* be3    = (const float*)d_in[29];
    float* out = (float*)d_out;

    // workspace arena (~111 MB)
    char* p = (char*)d_ws;
    auto alloc = [&](size_t bytes) {
        char* r = p; p += (bytes + 255) & ~(size_t)255; return r;
    };
    __bf16* xb    = (__bf16*)alloc((size_t)MPAD * KPAD * 2);  // 41.4 MB
    __bf16* wt    = (__bf16*)alloc((size_t)NPAD * KPAD * 2);  // 3.7 MB
    float* h1     = (float*)alloc((size_t)NN * 768 * 4);      // reused as h2 [NN,512]
    float* asrc   = (float*)alloc((size_t)NN * 6 * 4);
    float* adst   = (float*)alloc((size_t)NN * 6 * 4);
    float* ew     = (float*)alloc((size_t)ET * 6 * 4);
    float* den1   = (float*)alloc((size_t)NN * 6 * 4);
    float* den2   = (float*)alloc((size_t)NN * 4 * 4);
    int*   deg    = (int*)  alloc((size_t)NN * 4);
    float* dinv   = (float*)alloc((size_t)NN * 4);
    int*   rowst  = (int*)  alloc((size_t)(NN + 1) * 4);
    int*   cursor = (int*)  alloc((size_t)NN * 4);
    int*   csrc   = (int*)  alloc((size_t)ET * 4);
    int*   ceid   = (int*)  alloc((size_t)ET * 4);
    float* x1gat  = (float*)alloc((size_t)NN * 128 * 4);
    float* ybuf   = (float*)alloc((size_t)NN * 128 * 4);
    float* cat    = (float*)alloc((size_t)NN * 192 * 4);
    float* x2gat  = (float*)alloc((size_t)NN * 128 * 4);
    float* skippre= (float*)alloc((size_t)NN * 64 * 4);
    float* fusedb = (float*)alloc((size_t)NN * 64 * 4);

    hipMemsetAsync(deg,    0, (size_t)NN * 4, stream);
    hipMemsetAsync(cursor, 0, (size_t)NN * 4, stream);
    hipMemsetAsync(den1,   0, (size_t)NN * 6 * 4, stream);
    hipMemsetAsync(den2,   0, (size_t)NN * 4 * 4, stream);

    const int EB = (ET + 255) / 256;
    const int MB = (NN + 63) / 64;

    // bf16 conversions for dominant GEMM
    conv_x_kernel<<<(MPAD * (KPAD / 4) + 255) / 256, 256, 0, stream>>>(x, xb);
    conv_w_kernel<<<(NPAD * (KPAD / 4) + 255) / 256, 256, 0, stream>>>(W_gat1, W_skip, wt);

    // CSR by dst (also gives GCN degrees)
    count_kernel  <<<EB, 256, 0, stream>>>(ei, deg);
    dinv_kernel   <<<(NN + 255) / 256, 256, 0, stream>>>(deg, dinv);
    scan_kernel   <<<1, 256, 0, stream>>>(deg, rowst);
    scatter_kernel<<<EB, 256, 0, stream>>>(ei, rowst, cursor, csrc, ceid);

    // h1 = x @ W_gat1 [NN,768] and skippre = x @ W_skip [NN,64] in one MFMA GEMM
    mfma_gemm_kernel<<<dim3(NPAD / 128, MPAD / 128), 256, 0, stream>>>(xb, wt, h1, skippre);

    // ---- GAT layer 1 (H=6) ----
    alpha_kernel<<<NN * 6, 64, 0, stream>>>(h1, a_src1, a_dst1, asrc, adst, 6);
    edge_kernel <<<EB, 256, 0, stream>>>(ei, asrc, adst, ew, den1, 6);
    gat_agg_kernel<6><<<NN, 256, 0, stream>>>(h1, ew, den1, rowst, csrc, ceid,
                                              b_gat1, g1, be1, x1gat, 128);
    // ---- GCN layer 1 ----
    gemm_kernel<false, false><<<dim3(2, MB), 256, 0, stream>>>(
        x1gat, 128, W_gcn1, 128, ybuf, 128, nullptr, NN, 128, 128);
    gcn_agg_kernel<<<NN, 128, 0, stream>>>(ybuf, 128, dinv, rowst, csrc,
                                           b_gcn1, cat, 192, 0);
    // ---- GAT layer 2 (H=4) ----
    gemm_kernel<false, false><<<dim3(8, MB), 256, 0, stream>>>(
        cat, 192, W_gat2, 512, h1, 512, nullptr, NN, 512, 128);
    alpha_kernel<<<NN * 4, 64, 0, stream>>>(h1, a_src2, a_dst2, asrc, adst, 4);
    edge_kernel <<<EB, 256, 0, stream>>>(ei, asrc, adst, ew, den2, 4);
    gat_agg_kernel<4><<<NN, 256, 0, stream>>>(h1, ew, den2, rowst, csrc, ceid,
                                              b_gat2, g2, be2, x2gat, 128);
    // ---- GCN layer 2 -> cat[:, 128:192] ----
    gemm_kernel<false, false><<<dim3(1, MB), 256, 0, stream>>>(
        x2gat, 128, W_gcn2, 64, ybuf, 64, nullptr, NN, 64, 128);
    gcn_agg_kernel<<<NN, 64, 0, stream>>>(ybuf, 64, dinv, rowst, csrc,
                                          b_gcn2, cat, 192, 128);
    // ---- fuse + final ----
    gemm_kernel<true, true><<<dim3(1, MB), 256, 0, stream>>>(
        cat, 192, W_fuse, 64, fusedb, 64, b_fuse, NN, 64, 192);
    final_kernel<<<NN, 64, 0, stream>>>(fusedb, skippre, b_skip, g3, be3,
                                        W_c1, b_c1, W_c2, b_c2, W_c3, b_c3, out);
}

// Round 3
// 670.750 us; speedup vs baseline: 2.2319x; 1.1119x over previous
//
#include <hip/hip_runtime.h>
#include <cstdint>
#include <cstddef>

#define NN 10000
#define NE 160000
#define ET (NE + NN)          // edges + self loops
#define FIN 2000
#define MPAD 10112            // 79 * 128
#define KPAD 2048
#define NPAD 896              // 7 * 128 (768 gat1 cols + 64 skip cols + 64 pad)

typedef __bf16 bf16x8 __attribute__((ext_vector_type(8)));
typedef __bf16 bf16x4 __attribute__((ext_vector_type(4)));
typedef float  f32x4  __attribute__((ext_vector_type(4)));

// ---------------------------------------------------------------------------
// CSR build
// ---------------------------------------------------------------------------
__device__ __forceinline__ void edge_sd(const int* ei, int e, int& s, int& d) {
    if (e < NE) { s = ei[e]; d = ei[NE + e]; }
    else        { s = e - NE; d = e - NE; }
}

__global__ void count_kernel(const int* ei, int* deg) {
    int e = blockIdx.x * blockDim.x + threadIdx.x;
    if (e >= ET) return;
    int s, d; edge_sd(ei, e, s, d);
    atomicAdd(&deg[d], 1);
}

__global__ void dinv_kernel(const int* deg, float* dinv) {
    int n = blockIdx.x * blockDim.x + threadIdx.x;
    if (n >= NN) return;
    int dg = deg[n];
    dinv[n] = dg > 0 ? rsqrtf((float)dg) : 0.f;
}

__global__ void scan_kernel(const int* deg, int* rowstart) {
    __shared__ int partial[256];
    const int T = 256;
    int chunk = (NN + T - 1) / T;
    int t = threadIdx.x;
    int begin = t * chunk;
    int end = begin + chunk; if (end > NN) end = NN;
    int s = 0;
    for (int i = begin; i < end && i >= begin; i++) s += deg[i];
    partial[t] = s;
    __syncthreads();
    if (t == 0) {
        int run = 0;
        for (int i = 0; i < T; i++) { int v = partial[i]; partial[i] = run; run += v; }
    }
    __syncthreads();
    int run = partial[t];
    for (int i = begin; i < end && i >= begin; i++) { rowstart[i] = run; run += deg[i]; }
    if (end == NN && begin <= NN) rowstart[NN] = run;
}

__global__ void scatter_kernel(const int* ei, const int* rowstart, int* cursor,
                               int* csr_src, int* csr_eid) {
    int e = blockIdx.x * blockDim.x + threadIdx.x;
    if (e >= ET) return;
    int s, d; edge_sd(ei, e, s, d);
    int pos = atomicAdd(&cursor[d], 1);
    int slot = rowstart[d] + pos;
    csr_src[slot] = s;
    csr_eid[slot] = e;
}

// ---------------------------------------------------------------------------
// bf16 conversion kernels
// ---------------------------------------------------------------------------
__global__ void conv_x_kernel(const float* __restrict__ x, __bf16* __restrict__ xb) {
    int g = blockIdx.x * blockDim.x + threadIdx.x;   // over MPAD * (KPAD/4)
    if (g >= MPAD * (KPAD / 4)) return;
    int r = g / (KPAD / 4);
    int k4 = (g % (KPAD / 4)) * 4;
    bf16x4 o;
    if (r < NN && k4 + 3 < FIN) {
        const float4 v = *(const float4*)(x + (size_t)r * FIN + k4);
        o[0] = (__bf16)v.x; o[1] = (__bf16)v.y; o[2] = (__bf16)v.z; o[3] = (__bf16)v.w;
    } else {
        o[0] = o[1] = o[2] = o[3] = (__bf16)0.f;
    }
    *(bf16x4*)(xb + (size_t)r * KPAD + k4) = o;
}

// wt[n][k] = n<768 ? W_gat1[k*768+n] : n<832 ? W_skip[k*64+(n-768)] : 0 (k<2000)
__global__ void conv_w_kernel(const float* __restrict__ Wg, const float* __restrict__ Ws,
                              __bf16* __restrict__ wt) {
    int g = blockIdx.x * blockDim.x + threadIdx.x;   // over NPAD * (KPAD/4)
    if (g >= NPAD * (KPAD / 4)) return;
    int n = g / (KPAD / 4);
    int k4 = (g % (KPAD / 4)) * 4;
    bf16x4 o;
#pragma unroll
    for (int i = 0; i < 4; i++) {
        int k = k4 + i;
        float v = 0.f;
        if (k < FIN) {
            if (n < 768)      v = Wg[(size_t)k * 768 + n];
            else if (n < 832) v = Ws[(size_t)k * 64 + (n - 768)];
        }
        o[i] = (__bf16)v;
    }
    *(bf16x4*)(wt + (size_t)n * KPAD + k4) = o;
}

// W_gat2 [128,512] -> w2t [512,128] bf16
__global__ void conv_w2_kernel(const float* __restrict__ W, __bf16* __restrict__ wt) {
    int g = blockIdx.x * blockDim.x + threadIdx.x;
    if (g >= 512 * 128) return;
    int n = g >> 7, k = g & 127;
    wt[g] = (__bf16)W[(size_t)k * 512 + n];
}

// ---------------------------------------------------------------------------
// MFMA bf16 GEMM 1: xb[MPAD,KPAD] @ wt[NPAD,KPAD]^T -> h1b bf16[NN,768], skippre f32[NN,64]
// 128x128 tile, 4 waves, BK=32, global_load_lds w16. XCD-swizzled 1D grid (560).
// ---------------------------------------------------------------------------
__global__ __launch_bounds__(256)
void mfma_gemm_kernel(const __bf16* __restrict__ xb, const __bf16* __restrict__ wt,
                      __bf16* __restrict__ h1b, float* __restrict__ skippre) {
    __shared__ __bf16 As[4096];
    __shared__ __bf16 Bs[4096];
    // XCD swizzle: blocks with same (b&7) go to the same XCD (round-robin
    // heuristic); give each XCD whole row-tiles so the 7 col-tiles sharing an
    // A-stripe share one L2, and B (3.7MB) stays L2-resident per XCD.
    int b = blockIdx.x;
    int xcd = b & 7, j = b >> 3;          // j in 0..69
    int jq = j / 7;
    int rt = xcd + 8 * jq;                // row tile 0..79
    int ct = j - 7 * jq;                  // col tile 0..6
    if (rt >= MPAD / 128) return;
    const int bi = rt * 128;
    const int bn = ct * 128;

    const int tid = threadIdx.x;
    const int lane = tid & 63;
    const int w = tid >> 6;
    const int wm = w >> 1, wn = w & 1;
    const int q = lane >> 4, m16 = lane & 15;

    const int cl0 = w * 128 + lane;
    const int cl1 = cl0 + 64;
    const int cc0 = cl0 >> 7, r0 = cl0 & 127;
    const int cc1 = cl1 >> 7, r1 = cl1 & 127;

    f32x4 acc[4][4] = {};

    for (int k0 = 0; k0 < KPAD; k0 += 32) {
        __builtin_amdgcn_global_load_lds(
            (const __attribute__((address_space(1))) void*)(xb + (size_t)(bi + r0) * KPAD + k0 + cc0 * 8),
            (__attribute__((address_space(3))) void*)(As + w * 1024), 16, 0, 0);
        __builtin_amdgcn_global_load_lds(
            (const __attribute__((address_space(1))) void*)(xb + (size_t)(bi + r1) * KPAD + k0 + cc1 * 8),
            (__attribute__((address_space(3))) void*)(As + w * 1024 + 512), 16, 0, 0);
        __builtin_amdgcn_global_load_lds(
            (const __attribute__((address_space(1))) void*)(wt + (size_t)(bn + r0) * KPAD + k0 + cc0 * 8),
            (__attribute__((address_space(3))) void*)(Bs + w * 1024), 16, 0, 0);
        __builtin_amdgcn_global_load_lds(
            (const __attribute__((address_space(1))) void*)(wt + (size_t)(bn + r1) * KPAD + k0 + cc1 * 8),
            (__attribute__((address_space(3))) void*)(Bs + w * 1024 + 512), 16, 0, 0);
        __syncthreads();

        bf16x8 af[4], bfr[4];
#pragma unroll
        for (int mt = 0; mt < 4; mt++)
            af[mt] = *(const bf16x8*)(As + q * 1024 + (wm * 64 + mt * 16 + m16) * 8);
#pragma unroll
        for (int nt = 0; nt < 4; nt++)
            bfr[nt] = *(const bf16x8*)(Bs + q * 1024 + (wn * 64 + nt * 16 + m16) * 8);
#pragma unroll
        for (int mt = 0; mt < 4; mt++)
#pragma unroll
            for (int nt = 0; nt < 4; nt++)
                acc[mt][nt] = __builtin_amdgcn_mfma_f32_16x16x32_bf16(af[mt], bfr[nt], acc[mt][nt], 0, 0, 0);
        __syncthreads();
    }

#pragma unroll
    for (int mt = 0; mt < 4; mt++) {
#pragma unroll
        for (int r = 0; r < 4; r++) {
            int row = bi + wm * 64 + mt * 16 + q * 4 + r;
            if (row >= NN) continue;
#pragma unroll
            for (int nt = 0; nt < 4; nt++) {
                int col = bn + wn * 64 + nt * 16 + m16;
                float v = acc[mt][nt][r];
                if (col < 768)      h1b[(size_t)row * 768 + col] = (__bf16)v;
                else if (col < 832) skippre[(size_t)row * 64 + (col - 768)] = v;
            }
        }
    }
}

// ---------------------------------------------------------------------------
// MFMA bf16 GEMM 2: A[MPAD,128] @ B[512,128]^T -> h2b bf16[NN,512]. K=128.
// ---------------------------------------------------------------------------
__global__ __launch_bounds__(256)
void mfma_gemm2_kernel(const __bf16* __restrict__ A, const __bf16* __restrict__ B,
                       __bf16* __restrict__ Cb) {
    __shared__ __bf16 As[4096];
    __shared__ __bf16 Bs[4096];
    const int bi = blockIdx.y * 128;
    const int bn = blockIdx.x * 128;
    const int tid = threadIdx.x;
    const int lane = tid & 63;
    const int w = tid >> 6;
    const int wm = w >> 1, wn = w & 1;
    const int q = lane >> 4, m16 = lane & 15;

    const int cl0 = w * 128 + lane;
    const int cl1 = cl0 + 64;
    const int cc0 = cl0 >> 7, r0 = cl0 & 127;
    const int cc1 = cl1 >> 7, r1 = cl1 & 127;

    f32x4 acc[4][4] = {};

    for (int k0 = 0; k0 < 128; k0 += 32) {
        __builtin_amdgcn_global_load_lds(
            (const __attribute__((address_space(1))) void*)(A + (size_t)(bi + r0) * 128 + k0 + cc0 * 8),
            (__attribute__((address_space(3))) void*)(As + w * 1024), 16, 0, 0);
        __builtin_amdgcn_global_load_lds(
            (const __attribute__((address_space(1))) void*)(A + (size_t)(bi + r1) * 128 + k0 + cc1 * 8),
            (__attribute__((address_space(3))) void*)(As + w * 1024 + 512), 16, 0, 0);
        __builtin_amdgcn_global_load_lds(
            (const __attribute__((address_space(1))) void*)(B + (size_t)(bn + r0) * 128 + k0 + cc0 * 8),
            (__attribute__((address_space(3))) void*)(Bs + w * 1024), 16, 0, 0);
        __builtin_amdgcn_global_load_lds(
            (const __attribute__((address_space(1))) void*)(B + (size_t)(bn + r1) * 128 + k0 + cc1 * 8),
            (__attribute__((address_space(3))) void*)(Bs + w * 1024 + 512), 16, 0, 0);
        __syncthreads();

        bf16x8 af[4], bfr[4];
#pragma unroll
        for (int mt = 0; mt < 4; mt++)
            af[mt] = *(const bf16x8*)(As + q * 1024 + (wm * 64 + mt * 16 + m16) * 8);
#pragma unroll
        for (int nt = 0; nt < 4; nt++)
            bfr[nt] = *(const bf16x8*)(Bs + q * 1024 + (wn * 64 + nt * 16 + m16) * 8);
#pragma unroll
        for (int mt = 0; mt < 4; mt++)
#pragma unroll
            for (int nt = 0; nt < 4; nt++)
                acc[mt][nt] = __builtin_amdgcn_mfma_f32_16x16x32_bf16(af[mt], bfr[nt], acc[mt][nt], 0, 0, 0);
        __syncthreads();
    }

#pragma unroll
    for (int mt = 0; mt < 4; mt++) {
#pragma unroll
        for (int r = 0; r < 4; r++) {
            int row = bi + wm * 64 + mt * 16 + q * 4 + r;
            if (row >= NN) continue;
#pragma unroll
            for (int nt = 0; nt < 4; nt++) {
                int col = bn + wn * 64 + nt * 16 + m16;
                Cb[(size_t)row * 512 + col] = (__bf16)acc[mt][nt][r];
            }
        }
    }
}

// ---------------------------------------------------------------------------
// Generic fp32-accum tiled GEMM (small GEMMs), templated output type
// ---------------------------------------------------------------------------
template<bool RELU, bool BIAS, typename OUT>
__global__ void gemm_kernel(const float* __restrict__ A, int lda,
                            const float* __restrict__ B, int ldb,
                            OUT* __restrict__ C, int ldc,
                            const float* __restrict__ bias,
                            int M, int N, int K) {
    __shared__ float As[16][65];
    __shared__ float Bs[16][64];
    int bi = blockIdx.y * 64, bj = blockIdx.x * 64;
    int tid = threadIdx.x;
    int tx = tid & 15, ty = tid >> 4;
    float acc[4][4] = {};
    for (int k0 = 0; k0 < K; k0 += 16) {
        {
            int kk = tid & 15, mm = tid >> 4;
#pragma unroll
            for (int it = 0; it < 4; it++) {
                int row = mm + 16 * it;
                int gr = bi + row;
                As[kk][row] = (gr < M) ? A[(size_t)gr * lda + k0 + kk] : 0.f;
            }
        }
        {
            int nn = tid & 63, kk = tid >> 6;
#pragma unroll
            for (int it = 0; it < 4; it++)
                Bs[kk + 4 * it][nn] = B[(size_t)(k0 + kk + 4 * it) * ldb + bj + nn];
        }
        __syncthreads();
#pragma unroll
        for (int kk = 0; kk < 16; kk++) {
            float av[4], bv[4];
#pragma unroll
            for (int a = 0; a < 4; a++) av[a] = As[kk][ty * 4 + a];
#pragma unroll
            for (int b = 0; b < 4; b++) bv[b] = Bs[kk][tx * 4 + b];
#pragma unroll
            for (int a = 0; a < 4; a++)
#pragma unroll
                for (int b = 0; b < 4; b++)
                    acc[a][b] += av[a] * bv[b];
        }
        __syncthreads();
    }
#pragma unroll
    for (int a = 0; a < 4; a++) {
        int gr = bi + ty * 4 + a;
        if (gr >= M) continue;
#pragma unroll
        for (int b = 0; b < 4; b++) {
            int gc = bj + tx * 4 + b;
            float v = acc[a][b];
            if (BIAS) v += bias[gc];
            if (RELU) v = fmaxf(v, 0.f);
            C[(size_t)gr * ldc + gc] = (OUT)v;
        }
    }
}

// ---------------------------------------------------------------------------
// GAT pieces (bf16 feature reads)
// ---------------------------------------------------------------------------
__global__ void alpha_kernel(const __bf16* __restrict__ h,
                             const float* __restrict__ a_src,
                             const float* __restrict__ a_dst,
                             float* __restrict__ asrc_o, float* __restrict__ adst_o,
                             int H) {
    int b = blockIdx.x;          // = n*H + hh
    int n = b / H, hh = b % H;
    int l = threadIdx.x;         // 64 threads = 1 wave
    const __bf16* hp = h + (size_t)n * (H * 128) + hh * 128;
    const float* as = a_src + hh * 128;
    const float* ad = a_dst + hh * 128;
    float v0 = (float)hp[l], v1 = (float)hp[l + 64];
    float s1 = v0 * as[l] + v1 * as[l + 64];
    float s2 = v0 * ad[l] + v1 * ad[l + 64];
#pragma unroll
    for (int off = 32; off; off >>= 1) {
        s1 += __shfl_down(s1, off);
        s2 += __shfl_down(s2, off);
    }
    if (l == 0) { asrc_o[b] = s1; adst_o[b] = s2; }
}

__global__ void edge_kernel(const int* __restrict__ ei,
                            const float* __restrict__ asrc,
                            const float* __restrict__ adst,
                            float* __restrict__ ew, float* __restrict__ denom, int H) {
    int e = blockIdx.x * blockDim.x + threadIdx.x;
    if (e >= ET) return;
    int s, d; edge_sd(ei, e, s, d);
    for (int h = 0; h < H; h++) {
        float al = asrc[s * H + h] + adst[d * H + h];
        al = al >= 0.f ? al : 0.2f * al;
        float ev = expf(al);
        ew[(size_t)e * H + h] = ev;
        atomicAdd(&denom[d * H + h], ev);
    }
}

// per-node GAT aggregation: 4 waves split neighbors, bf16x4 loads, LDS combine,
// then head-mean + bias + LayerNorm + ReLU.
template<int H>
__global__ void gat_agg_kernel(const __bf16* __restrict__ hb,
                               const float* __restrict__ ew,
                               const float* __restrict__ denom,
                               const int* __restrict__ rowstart,
                               const int* __restrict__ csr_src,
                               const int* __restrict__ csr_eid,
                               const float* __restrict__ bias,
                               const float* __restrict__ gamma,
                               const float* __restrict__ beta,
                               float* __restrict__ out) {
    constexpr int CH = H * 128;
    constexpr int J = CH / 256;      // bf16x4 groups per lane
    int n = blockIdx.x;
    int t = threadIdx.x;
    int w = t >> 6, l = t & 63;
    __shared__ float invden[H];
    __shared__ float sm[4 * CH];
    __shared__ float red[8];
    if (t < H) invden[t] = 1.f / denom[n * H + t];
    __syncthreads();

    float acc[J][4] = {};
    int s0 = rowstart[n], s1 = rowstart[n + 1];
    for (int s = s0 + w; s < s1; s += 4) {
        int src = csr_src[s];
        int eid = csr_eid[s];
        const __bf16* hp = hb + (size_t)src * CH;
        const float* ep = ew + (size_t)eid * H;
#pragma unroll
        for (int jj = 0; jj < J; jj++) {
            int ch = jj * 256 + l * 4;
            int hh = ch >> 7;
            float wgt = ep[hh] * invden[hh];
            bf16x4 hv = *(const bf16x4*)(hp + ch);
            acc[jj][0] += (float)hv[0] * wgt;
            acc[jj][1] += (float)hv[1] * wgt;
            acc[jj][2] += (float)hv[2] * wgt;
            acc[jj][3] += (float)hv[3] * wgt;
        }
    }
#pragma unroll
    for (int jj = 0; jj < J; jj++)
        *(f32x4*)(sm + w * CH + jj * 256 + l * 4) = *(f32x4*)acc[jj];
    __syncthreads();

    float v = 0.f;
    if (t < 128) {
#pragma unroll
        for (int ww = 0; ww < 4; ww++)
#pragma unroll
            for (int hh = 0; hh < H; hh++)
                v += sm[ww * CH + hh * 128 + t];
        v = v * (1.f / H) + bias[t];
    }
    float sv = (t < 128) ? v : 0.f;
    float sq = (t < 128) ? v * v : 0.f;
#pragma unroll
    for (int off = 32; off; off >>= 1) {
        sv += __shfl_down(sv, off);
        sq += __shfl_down(sq, off);
    }
    if ((t & 63) == 0) { red[w * 2] = sv; red[w * 2 + 1] = sq; }
    __syncthreads();
    float tot = red[0] + red[2] + red[4] + red[6];
    float tsq = red[1] + red[3] + red[5] + red[7];
    float mu = tot * (1.f / 128.f);
    float var = tsq * (1.f / 128.f) - mu * mu;
    float r = rsqrtf(var + 1e-5f);
    if (t < 128) {
        float o = (v - mu) * r * gamma[t] + beta[t];
        out[(size_t)n * 128 + t] = fmaxf(o, 0.f);
    }
}

// per-node GCN aggregation from bf16 y; writes fp32 cat slice + optional bf16 copy
__global__ void gcn_agg_kernel(const __bf16* __restrict__ y, int C,
                               const float* __restrict__ dinv,
                               const int* __restrict__ rowstart,
                               const int* __restrict__ csr_src,
                               const float* __restrict__ bias,
                               float* __restrict__ out, int ldo, int coloff,
                               __bf16* __restrict__ bout) {
    int n = blockIdx.x;
    int t = threadIdx.x;  // blockDim == C
    float acc = 0.f;
    int s0 = rowstart[n], s1 = rowstart[n + 1];
    for (int s = s0; s < s1; s++) {
        int src = csr_src[s];
        acc += (float)y[(size_t)src * C + t] * dinv[src];
    }
    float v = fmaxf(acc * dinv[n] + bias[t], 0.f);
    out[(size_t)n * ldo + coloff + t] = v;
    if (bout) bout[(size_t)n * C + t] = (__bf16)v;
}

// final = LN(fused + relu(skippre + b_skip)); then 64->32->16->5 MLP.
__global__ void final_kernel(const float* __restrict__ fused,
                             const float* __restrict__ skippre,
                             const float* __restrict__ b_skip,
                             const float* __restrict__ g3, const float* __restrict__ be3,
                             const float* __restrict__ Wc1, const float* __restrict__ bc1,
                             const float* __restrict__ Wc2, const float* __restrict__ bc2,
                             const float* __restrict__ Wc3, const float* __restrict__ bc3,
                             float* __restrict__ out) {
    int n = blockIdx.x;
    int l = threadIdx.x;  // 64
    __shared__ float f[64], h1s[32], h2s[16];
    float sk = fmaxf(skippre[(size_t)n * 64 + l] + b_skip[l], 0.f);
    float v = fused[(size_t)n * 64 + l] + sk;
    float sv = v, sq = v * v;
#pragma unroll
    for (int off = 32; off; off >>= 1) {
        sv += __shfl_xor(sv, off);
        sq += __shfl_xor(sq, off);
    }
    float mu = sv * (1.f / 64.f);
    float var = sq * (1.f / 64.f) - mu * mu;
    float r = rsqrtf(var + 1e-5f);
    f[l] = (v - mu) * r * g3[l] + be3[l];
    __syncthreads();
    if (l < 32) {
        float a = bc1[l];
        for (int i = 0; i < 64; i++) a += f[i] * Wc1[i * 32 + l];
        h1s[l] = fmaxf(a, 0.f);
    }
    __syncthreads();
    if (l < 16) {
        float a = bc2[l];
        for (int i = 0; i < 32; i++) a += h1s[i] * Wc2[i * 16 + l];
        h2s[l] = fmaxf(a, 0.f);
    }
    __syncthreads();
    if (l < 5) {
        float a = bc3[l];
        for (int i = 0; i < 16; i++) a += h2s[i] * Wc3[i * 5 + l];
        out[(size_t)n * 5 + l] = a;
    }
}

// ---------------------------------------------------------------------------
extern "C" void kernel_launch(void* const* d_in, const int* in_sizes, int n_in,
                              void* d_out, int out_size, void* d_ws, size_t ws_size,
                              hipStream_t stream) {
    const float* x      = (const float*)d_in[0];
    const int*   ei     = (const int*)d_in[1];
    const float* W_gat1 = (const float*)d_in[2];
    const float* a_src1 = (const float*)d_in[3];
    const float* a_dst1 = (const float*)d_in[4];
    const float* b_gat1 = (const float*)d_in[5];
    const float* W_gcn1 = (const float*)d_in[6];
    const float* b_gcn1 = (const float*)d_in[7];
    const float* W_gat2 = (const float*)d_in[8];
    const float* a_src2 = (const float*)d_in[9];
    const float* a_dst2 = (const float*)d_in[10];
    const float* b_gat2 = (const float*)d_in[11];
    const float* W_gcn2 = (const float*)d_in[12];
    const float* b_gcn2 = (const float*)d_in[13];
    const float* W_skip = (const float*)d_in[14];
    const float* b_skip = (const float*)d_in[15];
    const float* W_fuse = (const float*)d_in[16];
    const float* b_fuse = (const float*)d_in[17];
    const float* W_c1   = (const float*)d_in[18];
    const float* b_c1   = (const float*)d_in[19];
    const float* W_c2   = (const float*)d_in[20];
    const float* b_c2   = (const float*)d_in[21];
    const float* W_c3   = (const float*)d_in[22];
    const float* b_c3   = (const float*)d_in[23];
    const float* g1     = (const float*)d_in[24];
    const float* be1    = (const float*)d_in[25];
    const float* g2     = (const float*)d_in[26];
    const float* be2    = (const float*)d_in[27];
    const float* g3     = (const float*)d_in[28];
    const float* be3    = (const float*)d_in[29];
    float* out = (float*)d_out;

    // workspace arena (~104 MB)
    char* p = (char*)d_ws;
    auto alloc = [&](size_t bytes) {
        char* r = p; p += (bytes + 255) & ~(size_t)255; return r;
    };
    __bf16* xb     = (__bf16*)alloc((size_t)MPAD * KPAD * 2);   // 41.4 MB
    __bf16* wt     = (__bf16*)alloc((size_t)NPAD * KPAD * 2);   // 3.7 MB
    __bf16* w2t    = (__bf16*)alloc((size_t)512 * 128 * 2);     // 0.13 MB
    __bf16* h1b    = (__bf16*)alloc((size_t)NN * 768 * 2);      // 15.4 MB
    __bf16* h2b    = (__bf16*)alloc((size_t)NN * 512 * 2);      // 10.2 MB
    __bf16* ybufb  = (__bf16*)alloc((size_t)NN * 128 * 2);      // 2.6 MB (y1, reused y2)
    __bf16* x1gcnb = (__bf16*)alloc((size_t)MPAD * 128 * 2);    // 2.6 MB (padded rows for MFMA2)
    float* asrc    = (float*)alloc((size_t)NN * 6 * 4);
    float* adst    = (float*)alloc((size_t)NN * 6 * 4);
    float* ew      = (float*)alloc((size_t)ET * 6 * 4);
    float* den1    = (float*)alloc((size_t)NN * 6 * 4);
    float* den2    = (float*)alloc((size_t)NN * 4 * 4);
    int*   deg     = (int*)  alloc((size_t)NN * 4);
    float* dinv    = (float*)alloc((size_t)NN * 4);
    int*   rowst   = (int*)  alloc((size_t)(NN + 1) * 4);
    int*   cursor  = (int*)  alloc((size_t)NN * 4);
    int*   csrc    = (int*)  alloc((size_t)ET * 4);
    int*   ceid    = (int*)  alloc((size_t)ET * 4);
    float* x1gat   = (float*)alloc((size_t)NN * 128 * 4);
    float* cat     = (float*)alloc((size_t)NN * 192 * 4);
    float* x2gat   = (float*)alloc((size_t)NN * 128 * 4);
    float* skippre = (float*)alloc((size_t)NN * 64 * 4);
    float* fusedb  = (float*)alloc((size_t)NN * 64 * 4);

    hipMemsetAsync(deg,    0, (size_t)NN * 4, stream);
    hipMemsetAsync(cursor, 0, (size_t)NN * 4, stream);
    hipMemsetAsync(den1,   0, (size_t)NN * 6 * 4, stream);
    hipMemsetAsync(den2,   0, (size_t)NN * 4 * 4, stream);

    const int EB = (ET + 255) / 256;
    const int MB = (NN + 63) / 64;

    // bf16 conversions
    conv_x_kernel<<<(MPAD * (KPAD / 4) + 255) / 256, 256, 0, stream>>>(x, xb);
    conv_w_kernel<<<(NPAD * (KPAD / 4) + 255) / 256, 256, 0, stream>>>(W_gat1, W_skip, wt);
    conv_w2_kernel<<<(512 * 128 + 255) / 256, 256, 0, stream>>>(W_gat2, w2t);

    // CSR by dst
    count_kernel  <<<EB, 256, 0, stream>>>(ei, deg);
    dinv_kernel   <<<(NN + 255) / 256, 256, 0, stream>>>(deg, dinv);
    scan_kernel   <<<1, 256, 0, stream>>>(deg, rowst);
    scatter_kernel<<<EB, 256, 0, stream>>>(ei, rowst, cursor, csrc, ceid);

    // h1 (bf16) + skippre in one XCD-swizzled MFMA GEMM
    mfma_gemm_kernel<<<560, 256, 0, stream>>>(xb, wt, h1b, skippre);

    // ---- GAT layer 1 (H=6) ----
    alpha_kernel<<<NN * 6, 64, 0, stream>>>(h1b, a_src1, a_dst1, asrc, adst, 6);
    edge_kernel <<<EB, 256, 0, stream>>>(ei, asrc, adst, ew, den1, 6);
    gat_agg_kernel<6><<<NN, 256, 0, stream>>>(h1b, ew, den1, rowst, csrc, ceid,
                                              b_gat1, g1, be1, x1gat);
    // ---- GCN layer 1 ----
    gemm_kernel<false, false, __bf16><<<dim3(2, MB), 256, 0, stream>>>(
        x1gat, 128, W_gcn1, 128, ybufb, 128, nullptr, NN, 128, 128);
    gcn_agg_kernel<<<NN, 128, 0, stream>>>(ybufb, 128, dinv, rowst, csrc,
                                           b_gcn1, cat, 192, 0, x1gcnb);
    // ---- GAT layer 2 (H=4): h2 = x1_gcn @ W_gat2 via MFMA ----
    mfma_gemm2_kernel<<<dim3(4, MPAD / 128), 256, 0, stream>>>(x1gcnb, w2t, h2b);
    alpha_kernel<<<NN * 4, 64, 0, stream>>>(h2b, a_src2, a_dst2, asrc, adst, 4);
    edge_kernel <<<EB, 256, 0, stream>>>(ei, asrc, adst, ew, den2, 4);
    gat_agg_kernel<4><<<NN, 256, 0, stream>>>(h2b, ew, den2, rowst, csrc, ceid,
                                              b_gat2, g2, be2, x2gat);
    // ---- GCN layer 2 -> cat[:, 128:192] ----
    gemm_kernel<false, false, __bf16><<<dim3(1, MB), 256, 0, stream>>>(
        x2gat, 128, W_gcn2, 64, ybufb, 64, nullptr, NN, 64, 128);
    gcn_agg_kernel<<<NN, 64, 0, stream>>>(ybufb, 64, dinv, rowst, csrc,
                                          b_gcn2, cat, 192, 128, nullptr);
    // ---- fuse + final ----
    gemm_kernel<true, true, float><<<dim3(1, MB), 256, 0, stream>>>(
        cat, 192, W_fuse, 64, fusedb, 64, b_fuse, NN, 64, 192);
    final_kernel<<<NN, 64, 0, stream>>>(fusedb, skippre, b_skip, g3, be3,
                                        W_c1, b_c1, W_c2, b_c2, W_c3, b_c3, out);
}

// Round 5
// 593.407 us; speedup vs baseline: 2.5228x; 1.1303x over previous
//
#include <hip/hip_runtime.h>
#include <cstdint>
#include <cstddef>

#define NN 10000
#define NE 160000
#define ET (NE + NN)          // edges + self loops
#define FIN 2000
#define MPAD 10112            // 158 * 64 = 79 * 128
#define KPAD 2048
#define NPAD 896              // 7 * 128 (768 gat1 cols + 64 skip + 64 pad)

typedef __bf16 bf16x8 __attribute__((ext_vector_type(8)));
typedef __bf16 bf16x4 __attribute__((ext_vector_type(4)));
typedef float  f32x4  __attribute__((ext_vector_type(4)));

// ---------------------------------------------------------------------------
// CSR build
// ---------------------------------------------------------------------------
__device__ __forceinline__ void edge_sd(const int* ei, int e, int& s, int& d) {
    if (e < NE) { s = ei[e]; d = ei[NE + e]; }
    else        { s = e - NE; d = e - NE; }
}

__global__ void count_kernel(const int* ei, int* deg) {
    int e = blockIdx.x * blockDim.x + threadIdx.x;
    if (e >= ET) return;
    int s, d; edge_sd(ei, e, s, d);
    atomicAdd(&deg[d], 1);
}

// exclusive scan over deg -> rowstart[0..NN]; also dinv = deg^-1/2
__global__ void scan_kernel(const int* deg, int* rowstart, float* dinv) {
    __shared__ int partial[256];
    const int T = 256;
    int chunk = (NN + T - 1) / T;
    int t = threadIdx.x;
    int begin = t * chunk;
    int end = begin + chunk; if (end > NN) end = NN;
    int s = 0;
    for (int i = begin; i < end && i >= begin; i++) s += deg[i];
    partial[t] = s;
    __syncthreads();
    if (t == 0) {
        int run = 0;
        for (int i = 0; i < T; i++) { int v = partial[i]; partial[i] = run; run += v; }
    }
    __syncthreads();
    int run = partial[t];
    for (int i = begin; i < end && i >= begin; i++) {
        rowstart[i] = run; run += deg[i];
        int dg = deg[i];
        dinv[i] = dg > 0 ? rsqrtf((float)dg) : 0.f;
    }
    if (end == NN && begin <= NN) rowstart[NN] = run;
}

__global__ void scatter_kernel(const int* ei, const int* rowstart, int* cursor,
                               int* csr_src) {
    int e = blockIdx.x * blockDim.x + threadIdx.x;
    if (e >= ET) return;
    int s, d; edge_sd(ei, e, s, d);
    int pos = atomicAdd(&cursor[d], 1);
    csr_src[rowstart[d] + pos] = s;
}

// ---------------------------------------------------------------------------
// bf16 conversion kernels
// ---------------------------------------------------------------------------
__global__ void conv_x_kernel(const float* __restrict__ x, __bf16* __restrict__ xb) {
    int g = blockIdx.x * blockDim.x + threadIdx.x;   // over MPAD * (KPAD/4)
    if (g >= MPAD * (KPAD / 4)) return;
    int r = g / (KPAD / 4);
    int k4 = (g % (KPAD / 4)) * 4;
    bf16x4 o;
    if (r < NN && k4 + 3 < FIN) {
        const float4 v = *(const float4*)(x + (size_t)r * FIN + k4);
        o[0] = (__bf16)v.x; o[1] = (__bf16)v.y; o[2] = (__bf16)v.z; o[3] = (__bf16)v.w;
    } else {
        o[0] = o[1] = o[2] = o[3] = (__bf16)0.f;
    }
    *(bf16x4*)(xb + (size_t)r * KPAD + k4) = o;
}

// wt[n][k] = n<768 ? W_gat1[k*768+n] : n<832 ? W_skip[k*64+(n-768)] : 0 (k<2000)
__global__ void conv_w_kernel(const float* __restrict__ Wg, const float* __restrict__ Ws,
                              __bf16* __restrict__ wt) {
    int g = blockIdx.x * blockDim.x + threadIdx.x;   // over NPAD * (KPAD/4)
    if (g >= NPAD * (KPAD / 4)) return;
    int n = g / (KPAD / 4);
    int k4 = (g % (KPAD / 4)) * 4;
    bf16x4 o;
#pragma unroll
    for (int i = 0; i < 4; i++) {
        int k = k4 + i;
        float v = 0.f;
        if (k < FIN) {
            if (n < 768)      v = Wg[(size_t)k * 768 + n];
            else if (n < 832) v = Ws[(size_t)k * 64 + (n - 768)];
        }
        o[i] = (__bf16)v;
    }
    *(bf16x4*)(wt + (size_t)n * KPAD + k4) = o;
}

// W_gat2 [128,512] -> w2t [512,128] bf16
__global__ void conv_w2_kernel(const float* __restrict__ W, __bf16* __restrict__ wt) {
    int g = blockIdx.x * blockDim.x + threadIdx.x;
    if (g >= 512 * 128) return;
    int n = g >> 7, k = g & 127;
    wt[g] = (__bf16)W[(size_t)k * 512 + n];
}

// ---------------------------------------------------------------------------
// MFMA GEMM 1: xb[MPAD,KPAD] @ wt[NPAD,KPAD]^T -> h1b bf16[NN,768], skippre f32[NN,64]
// 64M x 128N tile, 4 waves (2x2 over 32x64), BK=32, XCD-swizzled 1D grid (1120).
// ---------------------------------------------------------------------------
__global__ __launch_bounds__(256)
void mfma_gemm1_kernel(const __bf16* __restrict__ xb, const __bf16* __restrict__ wt,
                       __bf16* __restrict__ h1b, float* __restrict__ skippre) {
    __shared__ __bf16 As[2048];   // 4 planes x 64 rows x 8
    __shared__ __bf16 Bs[4096];   // 4 planes x 128 rows x 8
    int b = blockIdx.x;
    int xcd = b & 7, j = b >> 3;          // j in 0..139
    int jq = j / 7;
    int rt = xcd + 8 * jq;                // row tile 0..159
    int ct = j - 7 * jq;                  // col tile 0..6
    if (rt >= MPAD / 64) return;
    const int bi = rt * 64;
    const int bn = ct * 128;

    const int tid = threadIdx.x;
    const int lane = tid & 63;
    const int w = tid >> 6;
    const int wm = w >> 1, wn = w & 1;
    const int q = lane >> 4, m16 = lane & 15;

    const int a_pl = tid >> 6, a_row = tid & 63;
    const int b_pl0 = tid >> 7, b_row0 = tid & 127;
    const int b_pl1 = (tid + 256) >> 7, b_row1 = tid & 127;

    f32x4 acc[2][4] = {};

    for (int k0 = 0; k0 < KPAD; k0 += 32) {
        __builtin_amdgcn_global_load_lds(
            (const __attribute__((address_space(1))) void*)(xb + (size_t)(bi + a_row) * KPAD + k0 + a_pl * 8),
            (__attribute__((address_space(3))) void*)(As + w * 512), 16, 0, 0);
        __builtin_amdgcn_global_load_lds(
            (const __attribute__((address_space(1))) void*)(wt + (size_t)(bn + b_row0) * KPAD + k0 + b_pl0 * 8),
            (__attribute__((address_space(3))) void*)(Bs + w * 512), 16, 0, 0);
        __builtin_amdgcn_global_load_lds(
            (const __attribute__((address_space(1))) void*)(wt + (size_t)(bn + b_row1) * KPAD + k0 + b_pl1 * 8),
            (__attribute__((address_space(3))) void*)(Bs + 2048 + w * 512), 16, 0, 0);
        __syncthreads();

        bf16x8 af[2], bfr[4];
#pragma unroll
        for (int mt = 0; mt < 2; mt++)
            af[mt] = *(const bf16x8*)(As + q * 512 + (wm * 32 + mt * 16 + m16) * 8);
#pragma unroll
        for (int nt = 0; nt < 4; nt++)
            bfr[nt] = *(const bf16x8*)(Bs + q * 1024 + (wn * 64 + nt * 16 + m16) * 8);
#pragma unroll
        for (int mt = 0; mt < 2; mt++)
#pragma unroll
            for (int nt = 0; nt < 4; nt++)
                acc[mt][nt] = __builtin_amdgcn_mfma_f32_16x16x32_bf16(af[mt], bfr[nt], acc[mt][nt], 0, 0, 0);
        __syncthreads();
    }

#pragma unroll
    for (int mt = 0; mt < 2; mt++) {
#pragma unroll
        for (int r = 0; r < 4; r++) {
            int row = bi + wm * 32 + mt * 16 + q * 4 + r;
            if (row >= NN) continue;
#pragma unroll
            for (int nt = 0; nt < 4; nt++) {
                int col = bn + wn * 64 + nt * 16 + m16;
                float v = acc[mt][nt][r];
                if (col < 768)      h1b[(size_t)row * 768 + col] = (__bf16)v;
                else if (col < 832) skippre[(size_t)row * 64 + (col - 768)] = v;
            }
        }
    }
}

// ---------------------------------------------------------------------------
// MFMA bf16 GEMM 2: A[MPAD,128] @ B[512,128]^T -> h2b bf16[NN,512]. K=128.
// (round-3 verified kernel, verbatim)
// ---------------------------------------------------------------------------
__global__ __launch_bounds__(256)
void mfma_gemm2_kernel(const __bf16* __restrict__ A, const __bf16* __restrict__ B,
                       __bf16* __restrict__ Cb) {
    __shared__ __bf16 As[4096];
    __shared__ __bf16 Bs[4096];
    const int bi = blockIdx.y * 128;
    const int bn = blockIdx.x * 128;
    const int tid = threadIdx.x;
    const int lane = tid & 63;
    const int w = tid >> 6;
    const int wm = w >> 1, wn = w & 1;
    const int q = lane >> 4, m16 = lane & 15;

    const int cl0 = w * 128 + lane;
    const int cl1 = cl0 + 64;
    const int cc0 = cl0 >> 7, r0 = cl0 & 127;
    const int cc1 = cl1 >> 7, r1 = cl1 & 127;

    f32x4 acc[4][4] = {};

    for (int k0 = 0; k0 < 128; k0 += 32) {
        __builtin_amdgcn_global_load_lds(
            (const __attribute__((address_space(1))) void*)(A + (size_t)(bi + r0) * 128 + k0 + cc0 * 8),
            (__attribute__((address_space(3))) void*)(As + w * 1024), 16, 0, 0);
        __builtin_amdgcn_global_load_lds(
            (const __attribute__((address_space(1))) void*)(A + (size_t)(bi + r1) * 128 + k0 + cc1 * 8),
            (__attribute__((address_space(3))) void*)(As + w * 1024 + 512), 16, 0, 0);
        __builtin_amdgcn_global_load_lds(
            (const __attribute__((address_space(1))) void*)(B + (size_t)(bn + r0) * 128 + k0 + cc0 * 8),
            (__attribute__((address_space(3))) void*)(Bs + w * 1024), 16, 0, 0);
        __builtin_amdgcn_global_load_lds(
            (const __attribute__((address_space(1))) void*)(B + (size_t)(bn + r1) * 128 + k0 + cc1 * 8),
            (__attribute__((address_space(3))) void*)(Bs + w * 1024 + 512), 16, 0, 0);
        __syncthreads();

        bf16x8 af[4], bfr[4];
#pragma unroll
        for (int mt = 0; mt < 4; mt++)
            af[mt] = *(const bf16x8*)(As + q * 1024 + (wm * 64 + mt * 16 + m16) * 8);
#pragma unroll
        for (int nt = 0; nt < 4; nt++)
            bfr[nt] = *(const bf16x8*)(Bs + q * 1024 + (wn * 64 + nt * 16 + m16) * 8);
#pragma unroll
        for (int mt = 0; mt < 4; mt++)
#pragma unroll
            for (int nt = 0; nt < 4; nt++)
                acc[mt][nt] = __builtin_amdgcn_mfma_f32_16x16x32_bf16(af[mt], bfr[nt], acc[mt][nt], 0, 0, 0);
        __syncthreads();
    }

#pragma unroll
    for (int mt = 0; mt < 4; mt++) {
#pragma unroll
        for (int r = 0; r < 4; r++) {
            int row = bi + wm * 64 + mt * 16 + q * 4 + r;
            if (row >= NN) continue;
#pragma unroll
            for (int nt = 0; nt < 4; nt++) {
                int col = bn + wn * 64 + nt * 16 + m16;
                Cb[(size_t)row * 512 + col] = (__bf16)acc[mt][nt][r];
            }
        }
    }
}

// ---------------------------------------------------------------------------
// Generic fp32-accum tiled GEMM (small GEMMs), templated output type
// ---------------------------------------------------------------------------
template<bool RELU, bool BIAS, typename OUT>
__global__ void gemm_kernel(const float* __restrict__ A, int lda,
                            const float* __restrict__ B, int ldb,
                            OUT* __restrict__ C, int ldc,
                            const float* __restrict__ bias,
                            int M, int N, int K) {
    __shared__ float As[16][65];
    __shared__ float Bs[16][64];
    int bi = blockIdx.y * 64, bj = blockIdx.x * 64;
    int tid = threadIdx.x;
    int tx = tid & 15, ty = tid >> 4;
    float acc[4][4] = {};
    for (int k0 = 0; k0 < K; k0 += 16) {
        {
            int kk = tid & 15, mm = tid >> 4;
#pragma unroll
            for (int it = 0; it < 4; it++) {
                int row = mm + 16 * it;
                int gr = bi + row;
                As[kk][row] = (gr < M) ? A[(size_t)gr * lda + k0 + kk] : 0.f;
            }
        }
        {
            int nn = tid & 63, kk = tid >> 6;
#pragma unroll
            for (int it = 0; it < 4; it++)
                Bs[kk + 4 * it][nn] = B[(size_t)(k0 + kk + 4 * it) * ldb + bj + nn];
        }
        __syncthreads();
#pragma unroll
        for (int kk = 0; kk < 16; kk++) {
            float av[4], bv[4];
#pragma unroll
            for (int a = 0; a < 4; a++) av[a] = As[kk][ty * 4 + a];
#pragma unroll
            for (int b = 0; b < 4; b++) bv[b] = Bs[kk][tx * 4 + b];
#pragma unroll
            for (int a = 0; a < 4; a++)
#pragma unroll
                for (int b = 0; b < 4; b++)
                    acc[a][b] += av[a] * bv[b];
        }
        __syncthreads();
    }
#pragma unroll
    for (int a = 0; a < 4; a++) {
        int gr = bi + ty * 4 + a;
        if (gr >= M) continue;
#pragma unroll
        for (int b = 0; b < 4; b++) {
            int gc = bj + tx * 4 + b;
            float v = acc[a][b];
            if (BIAS) v += bias[gc];
            if (RELU) v = fmaxf(v, 0.f);
            C[(size_t)gr * ldc + gc] = (OUT)v;
        }
    }
}

// ---------------------------------------------------------------------------
// GAT pieces (bf16 features)
// ---------------------------------------------------------------------------
__global__ void alpha_kernel(const __bf16* __restrict__ h,
                             const float* __restrict__ a_src,
                             const float* __restrict__ a_dst,
                             float* __restrict__ asrc_o, float* __restrict__ adst_o,
                             int H) {
    int b = blockIdx.x;          // = n*H + hh
    int n = b / H, hh = b % H;
    int l = threadIdx.x;         // 64 threads = 1 wave
    const __bf16* hp = h + (size_t)n * (H * 128) + hh * 128;
    const float* as = a_src + hh * 128;
    const float* ad = a_dst + hh * 128;
    float v0 = (float)hp[l], v1 = (float)hp[l + 64];
    float s1 = v0 * as[l] + v1 * as[l + 64];
    float s2 = v0 * ad[l] + v1 * ad[l + 64];
#pragma unroll
    for (int off = 32; off; off >>= 1) {
        s1 += __shfl_down(s1, off);
        s2 += __shfl_down(s2, off);
    }
    if (l == 0) { asrc_o[b] = s1; adst_o[b] = s2; }
}

// Fused segment-softmax + aggregation + head-mean + bias + LN + ReLU.
// Phase 1: per-wave denom accumulation (lane h<H owns head h), LDS combine.
// Phase 2: recompute exp per edge (lane<H), shfl-broadcast, weight features.
// Softmax is shift-free (mathematically identical; alpha is O(1)).
template<int H>
__global__ void gat_agg_kernel(const __bf16* __restrict__ hb,
                               const float* __restrict__ asrc,
                               const float* __restrict__ adst,
                               const int* __restrict__ rowstart,
                               const int* __restrict__ csr_src,
                               const float* __restrict__ bias,
                               const float* __restrict__ gamma,
                               const float* __restrict__ beta,
                               float* __restrict__ out) {
    constexpr int CH = H * 128;
    constexpr int J = CH / 256;
    int n = blockIdx.x;
    int t = threadIdx.x;
    int w = t >> 6, l = t & 63;
    __shared__ float invden[H];
    __shared__ float denw[4][H];
    __shared__ float sm[4 * CH];
    __shared__ float red[8];

    int s0 = rowstart[n], s1 = rowstart[n + 1];
    float adst_n = (l < H) ? adst[n * H + l] : 0.f;

    // phase 1: denominators
    float dloc = 0.f;
    for (int s = s0 + w; s < s1; s += 4) {
        int src = csr_src[s];
        if (l < H) {
            float al = asrc[src * H + l] + adst_n;
            al = al >= 0.f ? al : 0.2f * al;
            dloc += __expf(al);
        }
    }
    if (l < H) denw[w][l] = dloc;
    __syncthreads();
    if (t < H) invden[t] = 1.f / (denw[0][t] + denw[1][t] + denw[2][t] + denw[3][t]);
    __syncthreads();

    // phase 2: weighted feature accumulation
    float acc[J][4] = {};
    for (int s = s0 + w; s < s1; s += 4) {
        int src = csr_src[s];
        float ev = 0.f;
        if (l < H) {
            float al = asrc[src * H + l] + adst_n;
            al = al >= 0.f ? al : 0.2f * al;
            ev = __expf(al);
        }
        const __bf16* hp = hb + (size_t)src * CH;
#pragma unroll
        for (int jj = 0; jj < J; jj++) {
            int ch = jj * 256 + l * 4;
            int hh = ch >> 7;
            float wgt = __shfl(ev, hh);
            bf16x4 hv = *(const bf16x4*)(hp + ch);
            acc[jj][0] += (float)hv[0] * wgt;
            acc[jj][1] += (float)hv[1] * wgt;
            acc[jj][2] += (float)hv[2] * wgt;
            acc[jj][3] += (float)hv[3] * wgt;
        }
    }
#pragma unroll
    for (int jj = 0; jj < J; jj++)
        *(f32x4*)(sm + w * CH + jj * 256 + l * 4) = *(f32x4*)acc[jj];
    __syncthreads();

    // combine waves, apply invden per head, head-mean, bias, LN, relu
    float v = 0.f;
    if (t < 128) {
#pragma unroll
        for (int hh = 0; hh < H; hh++) {
            float hsum = 0.f;
#pragma unroll
            for (int ww = 0; ww < 4; ww++) hsum += sm[ww * CH + hh * 128 + t];
            v += hsum * invden[hh];
        }
        v = v * (1.f / H) + bias[t];
    }
    float sv = (t < 128) ? v : 0.f;
    float sq = (t < 128) ? v * v : 0.f;
#pragma unroll
    for (int off = 32; off; off >>= 1) {
        sv += __shfl_down(sv, off);
        sq += __shfl_down(sq, off);
    }
    if ((t & 63) == 0) { red[w * 2] = sv; red[w * 2 + 1] = sq; }
    __syncthreads();
    float tot = red[0] + red[2] + red[4] + red[6];
    float tsq = red[1] + red[3] + red[5] + red[7];
    float mu = tot * (1.f / 128.f);
    float var = tsq * (1.f / 128.f) - mu * mu;
    float r = rsqrtf(var + 1e-5f);
    if (t < 128) {
        float o = (v - mu) * r * gamma[t] + beta[t];
        out[(size_t)n * 128 + t] = fmaxf(o, 0.f);
    }
}

// per-node GCN aggregation from bf16 y; fp32 cat slice + optional bf16 copy
__global__ void gcn_agg_kernel(const __bf16* __restrict__ y, int C,
                               const float* __restrict__ dinv,
                               const int* __restrict__ rowstart,
                               const int* __restrict__ csr_src,
                               const float* __restrict__ bias,
                               float* __restrict__ out, int ldo, int coloff,
                               __bf16* __restrict__ bout) {
    int n = blockIdx.x;
    int t = threadIdx.x;  // blockDim == C
    float acc = 0.f;
    int s0 = rowstart[n], s1 = rowstart[n + 1];
    for (int s = s0; s < s1; s++) {
        int src = csr_src[s];
        acc += (float)y[(size_t)src * C + t] * dinv[src];
    }
    float v = fmaxf(acc * dinv[n] + bias[t], 0.f);
    out[(size_t)n * ldo + coloff + t] = v;
    if (bout) bout[(size_t)n * C + t] = (__bf16)v;
}

// final = LN(fused + relu(skippre + b_skip)); then 64->32->16->5 MLP.
__global__ void final_kernel(const float* __restrict__ fused,
                             const float* __restrict__ skippre,
                             const float* __restrict__ b_skip,
                             const float* __restrict__ g3, const float* __restrict__ be3,
                             const float* __restrict__ Wc1, const float* __restrict__ bc1,
                             const float* __restrict__ Wc2, const float* __restrict__ bc2,
                             const float* __restrict__ Wc3, const float* __restrict__ bc3,
                             float* __restrict__ out) {
    int n = blockIdx.x;
    int l = threadIdx.x;  // 64
    __shared__ float f[64], h1s[32], h2s[16];
    float sk = fmaxf(skippre[(size_t)n * 64 + l] + b_skip[l], 0.f);
    float v = fused[(size_t)n * 64 + l] + sk;
    float sv = v, sq = v * v;
#pragma unroll
    for (int off = 32; off; off >>= 1) {
        sv += __shfl_xor(sv, off);
        sq += __shfl_xor(sq, off);
    }
    float mu = sv * (1.f / 64.f);
    float var = sq * (1.f / 64.f) - mu * mu;
    float r = rsqrtf(var + 1e-5f);
    f[l] = (v - mu) * r * g3[l] + be3[l];
    __syncthreads();
    if (l < 32) {
        float a = bc1[l];
        for (int i = 0; i < 64; i++) a += f[i] * Wc1[i * 32 + l];
        h1s[l] = fmaxf(a, 0.f);
    }
    __syncthreads();
    if (l < 16) {
        float a = bc2[l];
        for (int i = 0; i < 32; i++) a += h1s[i] * Wc2[i * 16 + l];
        h2s[l] = fmaxf(a, 0.f);
    }
    __syncthreads();
    if (l < 5) {
        float a = bc3[l];
        for (int i = 0; i < 16; i++) a += h2s[i] * Wc3[i * 5 + l];
        out[(size_t)n * 5 + l] = a;
    }
}

// ---------------------------------------------------------------------------
extern "C" void kernel_launch(void* const* d_in, const int* in_sizes, int n_in,
                              void* d_out, int out_size, void* d_ws, size_t ws_size,
                              hipStream_t stream) {
    const float* x      = (const float*)d_in[0];
    const int*   ei     = (const int*)d_in[1];
    const float* W_gat1 = (const float*)d_in[2];
    const float* a_src1 = (const float*)d_in[3];
    const float* a_dst1 = (const float*)d_in[4];
    const float* b_gat1 = (const float*)d_in[5];
    const float* W_gcn1 = (const float*)d_in[6];
    const float* b_gcn1 = (const float*)d_in[7];
    const float* W_gat2 = (const float*)d_in[8];
    const float* a_src2 = (const float*)d_in[9];
    const float* a_dst2 = (const float*)d_in[10];
    const float* b_gat2 = (const float*)d_in[11];
    const float* W_gcn2 = (const float*)d_in[12];
    const float* b_gcn2 = (const float*)d_in[13];
    const float* W_skip = (const float*)d_in[14];
    const float* b_skip = (const float*)d_in[15];
    const float* W_fuse = (const float*)d_in[16];
    const float* b_fuse = (const float*)d_in[17];
    const float* W_c1   = (const float*)d_in[18];
    const float* b_c1   = (const float*)d_in[19];
    const float* W_c2   = (const float*)d_in[20];
    const float* b_c2   = (const float*)d_in[21];
    const float* W_c3   = (const float*)d_in[22];
    const float* b_c3   = (const float*)d_in[23];
    const float* g1     = (const float*)d_in[24];
    const float* be1    = (const float*)d_in[25];
    const float* g2     = (const float*)d_in[26];
    const float* be2    = (const float*)d_in[27];
    const float* g3     = (const float*)d_in[28];
    const float* be3    = (const float*)d_in[29];
    float* out = (float*)d_out;

    // workspace arena
    char* p = (char*)d_ws;
    auto alloc = [&](size_t bytes) {
        char* r = p; p += (bytes + 255) & ~(size_t)255; return r;
    };
    __bf16* xb      = (__bf16*)alloc((size_t)MPAD * KPAD * 2);   // 41.4 MB
    __bf16* wt      = (__bf16*)alloc((size_t)NPAD * KPAD * 2);   // 3.7 MB
    __bf16* w2t     = (__bf16*)alloc((size_t)512 * 128 * 2);
    __bf16* h1b     = (__bf16*)alloc((size_t)NN * 768 * 2);      // 15.4 MB
    __bf16* h2b     = (__bf16*)alloc((size_t)NN * 512 * 2);      // 10.2 MB
    __bf16* ybufb   = (__bf16*)alloc((size_t)NN * 128 * 2);      // y1 reused y2
    __bf16* x1gcnb  = (__bf16*)alloc((size_t)MPAD * 128 * 2);    // padded, MFMA2 A
    float* asrc     = (float*)alloc((size_t)NN * 6 * 4);
    float* adst     = (float*)alloc((size_t)NN * 6 * 4);
    int*   deg      = (int*)  alloc((size_t)2 * NN * 4);         // deg | cursor
    int*   cursor   = deg + NN;
    float* dinv     = (float*)alloc((size_t)NN * 4);
    int*   rowst    = (int*)  alloc((size_t)(NN + 1) * 4);
    int*   csrc     = (int*)  alloc((size_t)ET * 4);
    float* x1gat    = (float*)alloc((size_t)NN * 128 * 4);
    float* cat      = (float*)alloc((size_t)NN * 192 * 4);
    float* x2gat    = (float*)alloc((size_t)NN * 128 * 4);
    float* skippre  = (float*)alloc((size_t)NN * 64 * 4);
    float* fusedb   = (float*)alloc((size_t)NN * 64 * 4);

    hipMemsetAsync(deg, 0, (size_t)2 * NN * 4, stream);
    hipMemsetAsync(x1gcnb + (size_t)NN * 128, 0, (size_t)(MPAD - NN) * 128 * 2, stream);

    const int EB = (ET + 255) / 256;
    const int MB = (NN + 63) / 64;

    // bf16 conversions
    conv_x_kernel<<<(MPAD * (KPAD / 4) + 255) / 256, 256, 0, stream>>>(x, xb);
    conv_w_kernel<<<(NPAD * (KPAD / 4) + 255) / 256, 256, 0, stream>>>(W_gat1, W_skip, wt);
    conv_w2_kernel<<<(512 * 128 + 255) / 256, 256, 0, stream>>>(W_gat2, w2t);

    // CSR by dst
    count_kernel  <<<EB, 256, 0, stream>>>(ei, deg);
    scan_kernel   <<<1, 256, 0, stream>>>(deg, rowst, dinv);
    scatter_kernel<<<EB, 256, 0, stream>>>(ei, rowst, cursor, csrc);

    // h1 (bf16) + skippre, XCD-swizzled 64x128-tile MFMA GEMM (1120 blocks)
    mfma_gemm1_kernel<<<1120, 256, 0, stream>>>(xb, wt, h1b, skippre);

    // ---- GAT layer 1 (H=6), softmax fused into aggregation ----
    alpha_kernel<<<NN * 6, 64, 0, stream>>>(h1b, a_src1, a_dst1, asrc, adst, 6);
    gat_agg_kernel<6><<<NN, 256, 0, stream>>>(h1b, asrc, adst, rowst, csrc,
                                              b_gat1, g1, be1, x1gat);
    // ---- GCN layer 1 (fp32 GEMM -> bf16 y) ----
    gemm_kernel<false, false, __bf16><<<dim3(2, MB), 256, 0, stream>>>(
        x1gat, 128, W_gcn1, 128, ybufb, 128, nullptr, NN, 128, 128);
    gcn_agg_kernel<<<NN, 128, 0, stream>>>(ybufb, 128, dinv, rowst, csrc,
                                           b_gcn1, cat, 192, 0, x1gcnb);
    // ---- GAT layer 2 (H=4): h2 = x1_gcn @ W_gat2 (bf16 MFMA) ----
    mfma_gemm2_kernel<<<dim3(4, MPAD / 128), 256, 0, stream>>>(x1gcnb, w2t, h2b);
    alpha_kernel<<<NN * 4, 64, 0, stream>>>(h2b, a_src2, a_dst2, asrc, adst, 4);
    gat_agg_kernel<4><<<NN, 256, 0, stream>>>(h2b, asrc, adst, rowst, csrc,
                                              b_gat2, g2, be2, x2gat);
    // ---- GCN layer 2 (fp32 GEMM -> bf16 y) -> cat[:, 128:192] ----
    gemm_kernel<false, false, __bf16><<<dim3(1, MB), 256, 0, stream>>>(
        x2gat, 128, W_gcn2, 64, ybufb, 64, nullptr, NN, 64, 128);
    gcn_agg_kernel<<<NN, 64, 0, stream>>>(ybufb, 64, dinv, rowst, csrc,
                                          b_gcn2, cat, 192, 128, nullptr);
    // ---- fuse (fp32) + final ----
    gemm_kernel<true, true, float><<<dim3(1, MB), 256, 0, stream>>>(
        cat, 192, W_fuse, 64, fusedb, 64, b_fuse, NN, 64, 192);
    final_kernel<<<NN, 64, 0, stream>>>(fusedb, skippre, b_skip, g3, be3,
                                        W_c1, b_c1, W_c2, b_c2, W_c3, b_c3, out);
}

// Round 6
// 533.534 us; speedup vs baseline: 2.8059x; 1.1122x over previous
//
#include <hip/hip_runtime.h>
#include <cstdint>
#include <cstddef>

#define NN 10000
#define NE 160000
#define ET (NE + NN)          // edges + self loops
#define FIN 2000
#define MPAD 10112            // 158 * 64
#define KPAD 2048
#define NPAD 896              // 7 * 128 (768 gat1 cols + 64 skip + 64 pad)

typedef __bf16 bf16x8 __attribute__((ext_vector_type(8)));
typedef __bf16 bf16x4 __attribute__((ext_vector_type(4)));
typedef float  f32x4  __attribute__((ext_vector_type(4)));

// ---------------------------------------------------------------------------
// CSR build
// ---------------------------------------------------------------------------
__device__ __forceinline__ void edge_sd(const int* ei, int e, int& s, int& d) {
    if (e < NE) { s = ei[e]; d = ei[NE + e]; }
    else        { s = e - NE; d = e - NE; }
}

__global__ void count_kernel(const int* ei, int* deg) {
    int e = blockIdx.x * blockDim.x + threadIdx.x;
    if (e >= ET) return;
    int s, d; edge_sd(ei, e, s, d);
    atomicAdd(&deg[d], 1);
}

// exclusive scan over deg -> rowstart[0..NN]; also dinv = deg^-1/2
__global__ void scan_kernel(const int* deg, int* rowstart, float* dinv) {
    __shared__ int partial[256];
    const int T = 256;
    int chunk = (NN + T - 1) / T;
    int t = threadIdx.x;
    int begin = t * chunk;
    int end = begin + chunk; if (end > NN) end = NN;
    int s = 0;
    for (int i = begin; i < end && i >= begin; i++) s += deg[i];
    partial[t] = s;
    __syncthreads();
    if (t == 0) {
        int run = 0;
        for (int i = 0; i < T; i++) { int v = partial[i]; partial[i] = run; run += v; }
    }
    __syncthreads();
    int run = partial[t];
    for (int i = begin; i < end && i >= begin; i++) {
        rowstart[i] = run; run += deg[i];
        int dg = deg[i];
        dinv[i] = dg > 0 ? rsqrtf((float)dg) : 0.f;
    }
    if (end == NN && begin <= NN) rowstart[NN] = run;
}

__global__ void scatter_kernel(const int* ei, const int* rowstart, int* cursor,
                               int* csr_src) {
    int e = blockIdx.x * blockDim.x + threadIdx.x;
    if (e >= ET) return;
    int s, d; edge_sd(ei, e, s, d);
    int pos = atomicAdd(&cursor[d], 1);
    csr_src[rowstart[d] + pos] = s;
}

// ---------------------------------------------------------------------------
// Swizzled bf16 conversions.
// xb layout (64-row tiles, BK=64 slabs, 8 planes of 8 k-elems):
//   chunk c = ((rt*32 + ks)*8 + p)*64 + r  holds x[rt*64+r][ks*64+p*8 .. +8)
// wt layout (128-row tiles): c = ((ct*32 + ks)*8 + p)*128 + r
// => every GEMM staging instruction reads 64 consecutive 16B chunks.
// ---------------------------------------------------------------------------
__global__ void conv_x_kernel(const float* __restrict__ x, __bf16* __restrict__ xb) {
    // block: 4 rows x 64 k-chunks; grid = (MPAD/4) * (KPAD/512)
    int bg = blockIdx.x;
    int bg_k = bg & 3, bg_row = bg >> 2;
    int tid = threadIdx.x;
    int row = bg_row * 4 + (tid >> 6);
    int kc = bg_k * 64 + (tid & 63);     // k-chunk index, k = kc*8
    int k = kc * 8;
    int rt = row >> 6, r = row & 63;
    int ks = kc >> 3, p = kc & 7;
    size_t c = ((size_t)(rt * 32 + ks) * 8 + p) * 64 + r;
    bf16x8 o;
    if (row < NN && k < FIN) {           // 8 | 2000, chunks fully valid or pad
        const float4 v0 = *(const float4*)(x + (size_t)row * FIN + k);
        const float4 v1 = *(const float4*)(x + (size_t)row * FIN + k + 4);
        o[0] = (__bf16)v0.x; o[1] = (__bf16)v0.y; o[2] = (__bf16)v0.z; o[3] = (__bf16)v0.w;
        o[4] = (__bf16)v1.x; o[5] = (__bf16)v1.y; o[6] = (__bf16)v1.z; o[7] = (__bf16)v1.w;
    } else {
#pragma unroll
        for (int i = 0; i < 8; i++) o[i] = (__bf16)0.f;
    }
    *(bf16x8*)(xb + c * 8) = o;
}

__global__ void conv_w_kernel(const float* __restrict__ Wg, const float* __restrict__ Ws,
                              __bf16* __restrict__ wt) {
    int g = blockIdx.x * blockDim.x + threadIdx.x;   // chunk id, NPAD*KPAD/8 total
    if (g >= NPAD * KPAD / 8) return;
    int r = g & 127, p = (g >> 7) & 7, ks = (g >> 10) & 31, ct = g >> 15;
    int n = ct * 128 + r;
    int k0 = ks * 64 + p * 8;
    bf16x8 o;
#pragma unroll
    for (int j = 0; j < 8; j++) {
        int k = k0 + j;
        float v = 0.f;
        if (k < FIN) {
            if (n < 768)      v = Wg[(size_t)k * 768 + n];
            else if (n < 832) v = Ws[(size_t)k * 64 + (n - 768)];
        }
        o[j] = (__bf16)v;
    }
    *(bf16x8*)(wt + (size_t)g * 8) = o;
}

// W_gat2 [128,512] -> w2t [512,128] bf16 (row-major, for mfma_gemm2)
__global__ void conv_w2_kernel(const float* __restrict__ W, __bf16* __restrict__ wt) {
    int g = blockIdx.x * blockDim.x + threadIdx.x;
    if (g >= 512 * 128) return;
    int n = g >> 7, k = g & 127;
    wt[g] = (__bf16)W[(size_t)k * 512 + n];
}

// ---------------------------------------------------------------------------
// MFMA GEMM 1: xb(swizzled)[MPAD,KPAD] @ wt(swizzled)[NPAD,KPAD]^T
//   -> h1b bf16[NN,768], skippre f32[NN,64]
// 64M x 128N tile, 4 waves (2x2 over 32x64), BK=64, fully-coalesced staging.
// ---------------------------------------------------------------------------
__global__ __launch_bounds__(256)
void mfma_gemm1_kernel(const __bf16* __restrict__ xb, const __bf16* __restrict__ wt,
                       __bf16* __restrict__ h1b, float* __restrict__ skippre) {
    __shared__ __bf16 As[4096];    // 8 planes x 64 rows x 8  (8 KB)
    __shared__ __bf16 Bs[8192];    // 8 planes x 128 rows x 8 (16 KB)
    int b = blockIdx.x;
    int xcd = b & 7, j = b >> 3;
    int jq = j / 7;
    int rt = xcd + 8 * jq;                // row tile 0..157
    int ct = j - 7 * jq;                  // col tile 0..6
    if (rt >= MPAD / 64) return;
    const int bi = rt * 64;
    const int bn = ct * 128;

    const int tid = threadIdx.x;
    const int lane = tid & 63;
    const int w = tid >> 6;
    const int wm = w >> 1, wn = w & 1;
    const int q = lane >> 4, m16 = lane & 15;

    f32x4 acc[2][4] = {};

    for (int ks = 0; ks < KPAD / 64; ks++) {
        const size_t slabA = (size_t)(rt * 32 + ks) * 512;    // chunk index
        const size_t slabB = (size_t)(ct * 32 + ks) * 1024;
        // A: 8 planes x 64 rows = 512 chunks, 2 insts/wave, contiguous src
#pragma unroll
        for (int i = 0; i < 2; i++) {
            int p = i * 4 + w;
            __builtin_amdgcn_global_load_lds(
                (const __attribute__((address_space(1))) void*)(xb + (slabA + p * 64 + lane) * 8),
                (__attribute__((address_space(3))) void*)(As + p * 512), 16, 0, 0);
        }
        // B: 8 planes x 128 rows = 1024 chunks, 4 insts/wave, contiguous src
#pragma unroll
        for (int i = 0; i < 4; i++) {
            int seg = i * 4 + w;           // 0..15, 64 chunks each
            __builtin_amdgcn_global_load_lds(
                (const __attribute__((address_space(1))) void*)(wt + (slabB + seg * 64 + lane) * 8),
                (__attribute__((address_space(3))) void*)(Bs + seg * 512), 16, 0, 0);
        }
        __syncthreads();

#pragma unroll
        for (int kk = 0; kk < 2; kk++) {
            const int pb = kk * 4 + q;
            bf16x8 af[2], bfr[4];
#pragma unroll
            for (int mt = 0; mt < 2; mt++)
                af[mt] = *(const bf16x8*)(As + (pb * 64 + wm * 32 + mt * 16 + m16) * 8);
#pragma unroll
            for (int nt = 0; nt < 4; nt++)
                bfr[nt] = *(const bf16x8*)(Bs + (pb * 128 + wn * 64 + nt * 16 + m16) * 8);
#pragma unroll
            for (int mt = 0; mt < 2; mt++)
#pragma unroll
                for (int nt = 0; nt < 4; nt++)
                    acc[mt][nt] = __builtin_amdgcn_mfma_f32_16x16x32_bf16(af[mt], bfr[nt], acc[mt][nt], 0, 0, 0);
        }
        __syncthreads();
    }

#pragma unroll
    for (int mt = 0; mt < 2; mt++) {
#pragma unroll
        for (int r = 0; r < 4; r++) {
            int row = bi + wm * 32 + mt * 16 + q * 4 + r;
            if (row >= NN) continue;
#pragma unroll
            for (int nt = 0; nt < 4; nt++) {
                int col = bn + wn * 64 + nt * 16 + m16;
                float v = acc[mt][nt][r];
                if (col < 768)      h1b[(size_t)row * 768 + col] = (__bf16)v;
                else if (col < 832) skippre[(size_t)row * 64 + (col - 768)] = v;
            }
        }
    }
}

// ---------------------------------------------------------------------------
// MFMA bf16 GEMM 2: A[MPAD,128] @ B[512,128]^T -> h2b bf16[NN,512]. K=128.
// (round-3 verified kernel, verbatim)
// ---------------------------------------------------------------------------
__global__ __launch_bounds__(256)
void mfma_gemm2_kernel(const __bf16* __restrict__ A, const __bf16* __restrict__ B,
                       __bf16* __restrict__ Cb) {
    __shared__ __bf16 As[4096];
    __shared__ __bf16 Bs[4096];
    const int bi = blockIdx.y * 128;
    const int bn = blockIdx.x * 128;
    const int tid = threadIdx.x;
    const int lane = tid & 63;
    const int w = tid >> 6;
    const int wm = w >> 1, wn = w & 1;
    const int q = lane >> 4, m16 = lane & 15;

    const int cl0 = w * 128 + lane;
    const int cl1 = cl0 + 64;
    const int cc0 = cl0 >> 7, r0 = cl0 & 127;
    const int cc1 = cl1 >> 7, r1 = cl1 & 127;

    f32x4 acc[4][4] = {};

    for (int k0 = 0; k0 < 128; k0 += 32) {
        __builtin_amdgcn_global_load_lds(
            (const __attribute__((address_space(1))) void*)(A + (size_t)(bi + r0) * 128 + k0 + cc0 * 8),
            (__attribute__((address_space(3))) void*)(As + w * 1024), 16, 0, 0);
        __builtin_amdgcn_global_load_lds(
            (const __attribute__((address_space(1))) void*)(A + (size_t)(bi + r1) * 128 + k0 + cc1 * 8),
            (__attribute__((address_space(3))) void*)(As + w * 1024 + 512), 16, 0, 0);
        __builtin_amdgcn_global_load_lds(
            (const __attribute__((address_space(1))) void*)(B + (size_t)(bn + r0) * 128 + k0 + cc0 * 8),
            (__attribute__((address_space(3))) void*)(Bs + w * 1024), 16, 0, 0);
        __builtin_amdgcn_global_load_lds(
            (const __attribute__((address_space(1))) void*)(B + (size_t)(bn + r1) * 128 + k0 + cc1 * 8),
            (__attribute__((address_space(3))) void*)(Bs + w * 1024 + 512), 16, 0, 0);
        __syncthreads();

        bf16x8 af[4], bfr[4];
#pragma unroll
        for (int mt = 0; mt < 4; mt++)
            af[mt] = *(const bf16x8*)(As + q * 1024 + (wm * 64 + mt * 16 + m16) * 8);
#pragma unroll
        for (int nt = 0; nt < 4; nt++)
            bfr[nt] = *(const bf16x8*)(Bs + q * 1024 + (wn * 64 + nt * 16 + m16) * 8);
#pragma unroll
        for (int mt = 0; mt < 4; mt++)
#pragma unroll
            for (int nt = 0; nt < 4; nt++)
                acc[mt][nt] = __builtin_amdgcn_mfma_f32_16x16x32_bf16(af[mt], bfr[nt], acc[mt][nt], 0, 0, 0);
        __syncthreads();
    }

#pragma unroll
    for (int mt = 0; mt < 4; mt++) {
#pragma unroll
        for (int r = 0; r < 4; r++) {
            int row = bi + wm * 64 + mt * 16 + q * 4 + r;
            if (row >= NN) continue;
#pragma unroll
            for (int nt = 0; nt < 4; nt++) {
                int col = bn + wn * 64 + nt * 16 + m16;
                Cb[(size_t)row * 512 + col] = (__bf16)acc[mt][nt][r];
            }
        }
    }
}

// ---------------------------------------------------------------------------
// Generic fp32-accum tiled GEMM (small GEMMs), templated output type
// ---------------------------------------------------------------------------
template<bool RELU, bool BIAS, typename OUT>
__global__ void gemm_kernel(const float* __restrict__ A, int lda,
                            const float* __restrict__ B, int ldb,
                            OUT* __restrict__ C, int ldc,
                            const float* __restrict__ bias,
                            int M, int N, int K) {
    __shared__ float As[16][65];
    __shared__ float Bs[16][64];
    int bi = blockIdx.y * 64, bj = blockIdx.x * 64;
    int tid = threadIdx.x;
    int tx = tid & 15, ty = tid >> 4;
    float acc[4][4] = {};
    for (int k0 = 0; k0 < K; k0 += 16) {
        {
            int kk = tid & 15, mm = tid >> 4;
#pragma unroll
            for (int it = 0; it < 4; it++) {
                int row = mm + 16 * it;
                int gr = bi + row;
                As[kk][row] = (gr < M) ? A[(size_t)gr * lda + k0 + kk] : 0.f;
            }
        }
        {
            int nn = tid & 63, kk = tid >> 6;
#pragma unroll
            for (int it = 0; it < 4; it++)
                Bs[kk + 4 * it][nn] = B[(size_t)(k0 + kk + 4 * it) * ldb + bj + nn];
        }
        __syncthreads();
#pragma unroll
        for (int kk = 0; kk < 16; kk++) {
            float av[4], bv[4];
#pragma unroll
            for (int a = 0; a < 4; a++) av[a] = As[kk][ty * 4 + a];
#pragma unroll
            for (int b = 0; b < 4; b++) bv[b] = Bs[kk][tx * 4 + b];
#pragma unroll
            for (int a = 0; a < 4; a++)
#pragma unroll
                for (int b = 0; b < 4; b++)
                    acc[a][b] += av[a] * bv[b];
        }
        __syncthreads();
    }
#pragma unroll
    for (int a = 0; a < 4; a++) {
        int gr = bi + ty * 4 + a;
        if (gr >= M) continue;
#pragma unroll
        for (int b = 0; b < 4; b++) {
            int gc = bj + tx * 4 + b;
            float v = acc[a][b];
            if (BIAS) v += bias[gc];
            if (RELU) v = fmaxf(v, 0.f);
            C[(size_t)gr * ldc + gc] = (OUT)v;
        }
    }
}

// ---------------------------------------------------------------------------
// GAT pieces (bf16 features)
// ---------------------------------------------------------------------------
// 4 (n,head) units per block (one wave each)
__global__ void alpha_kernel(const __bf16* __restrict__ h,
                             const float* __restrict__ a_src,
                             const float* __restrict__ a_dst,
                             float* __restrict__ asrc_o, float* __restrict__ adst_o,
                             int H) {
    int u = blockIdx.x * 4 + (threadIdx.x >> 6);
    if (u >= NN * H) return;
    int n = u / H, hh = u % H;
    int l = threadIdx.x & 63;
    const __bf16* hp = h + (size_t)n * (H * 128) + hh * 128;
    const float* as = a_src + hh * 128;
    const float* ad = a_dst + hh * 128;
    float v0 = (float)hp[l], v1 = (float)hp[l + 64];
    float s1 = v0 * as[l] + v1 * as[l + 64];
    float s2 = v0 * ad[l] + v1 * ad[l + 64];
#pragma unroll
    for (int off = 32; off; off >>= 1) {
        s1 += __shfl_down(s1, off);
        s2 += __shfl_down(s2, off);
    }
    if (l == 0) { asrc_o[u] = s1; adst_o[u] = s2; }
}

// Fused segment-softmax + aggregation + head-mean + bias + LN + ReLU.
template<int H>
__global__ void gat_agg_kernel(const __bf16* __restrict__ hb,
                               const float* __restrict__ asrc,
                               const float* __restrict__ adst,
                               const int* __restrict__ rowstart,
                               const int* __restrict__ csr_src,
                               const float* __restrict__ bias,
                               const float* __restrict__ gamma,
                               const float* __restrict__ beta,
                               float* __restrict__ out) {
    constexpr int CH = H * 128;
    int n = blockIdx.x;
    int t = threadIdx.x;
    int w = t >> 6, l = t & 63;
    __shared__ float invden[H];
    __shared__ float denw[4][H];
    __shared__ float sm[4 * CH];
    __shared__ float red[8];

    int s0 = rowstart[n], s1 = rowstart[n + 1];
    float adst_n = (l < H) ? adst[n * H + l] : 0.f;

    // phase 1: denominators
    float dloc = 0.f;
    for (int s = s0 + w; s < s1; s += 4) {
        int src = csr_src[s];
        if (l < H) {
            float al = asrc[src * H + l] + adst_n;
            al = al >= 0.f ? al : 0.2f * al;
            dloc += __expf(al);
        }
    }
    if (l < H) denw[w][l] = dloc;
    __syncthreads();
    if (t < H) invden[t] = 1.f / (denw[0][t] + denw[1][t] + denw[2][t] + denw[3][t]);
    __syncthreads();

    // phase 2: weighted feature accumulation, bf16x8 loads
    constexpr int NA = (H == 6) ? 12 : 8;
    float acc[NA] = {};
    for (int s = s0 + w; s < s1; s += 4) {
        int src = csr_src[s];
        float ev = 0.f;
        if (l < H) {
            float al = asrc[src * H + l] + adst_n;
            al = al >= 0.f ? al : 0.2f * al;
            ev = __expf(al);
        }
        const __bf16* hp = hb + (size_t)src * CH;
        {   // group 0: channels l*8 .. l*8+7, head = l>>4
            float wgt = __shfl(ev, l >> 4);
            bf16x8 hv = *(const bf16x8*)(hp + l * 8);
#pragma unroll
            for (int jj = 0; jj < 8; jj++) acc[jj] += (float)hv[jj] * wgt;
        }
        if (H == 6) {   // group 1: channels 512 + l*4, head = 4 + (l>>5)
            float wgt = __shfl(ev, 4 + (l >> 5));
            bf16x4 hv = *(const bf16x4*)(hp + 512 + l * 4);
#pragma unroll
            for (int jj = 0; jj < 4; jj++) acc[8 + jj] += (float)hv[jj] * wgt;
        }
    }
    *(f32x4*)(sm + w * CH + l * 8)     = *(f32x4*)(acc);
    *(f32x4*)(sm + w * CH + l * 8 + 4) = *(f32x4*)(acc + 4);
    if (H == 6)
        *(f32x4*)(sm + w * CH + 512 + l * 4) = *(f32x4*)(acc + 8);
    __syncthreads();

    // combine waves, apply invden per head, head-mean, bias, LN, relu
    float v = 0.f;
    if (t < 128) {
#pragma unroll
        for (int hh = 0; hh < H; hh++) {
            float hsum = 0.f;
#pragma unroll
            for (int ww = 0; ww < 4; ww++) hsum += sm[ww * CH + hh * 128 + t];
            v += hsum * invden[hh];
        }
        v = v * (1.f / H) + bias[t];
    }
    float sv = (t < 128) ? v : 0.f;
    float sq = (t < 128) ? v * v : 0.f;
#pragma unroll
    for (int off = 32; off; off >>= 1) {
        sv += __shfl_down(sv, off);
        sq += __shfl_down(sq, off);
    }
    if ((t & 63) == 0) { red[w * 2] = sv; red[w * 2 + 1] = sq; }
    __syncthreads();
    float tot = red[0] + red[2] + red[4] + red[6];
    float tsq = red[1] + red[3] + red[5] + red[7];
    float mu = tot * (1.f / 128.f);
    float var = tsq * (1.f / 128.f) - mu * mu;
    float r = rsqrtf(var + 1e-5f);
    if (t < 128) {
        float o = (v - mu) * r * gamma[t] + beta[t];
        out[(size_t)n * 128 + t] = fmaxf(o, 0.f);
    }
}

// per-node GCN aggregation from bf16 y; fp32 cat slice + optional bf16 copy
__global__ void gcn_agg_kernel(const __bf16* __restrict__ y, int C,
                               const float* __restrict__ dinv,
                               const int* __restrict__ rowstart,
                               const int* __restrict__ csr_src,
                               const float* __restrict__ bias,
                               float* __restrict__ out, int ldo, int coloff,
                               __bf16* __restrict__ bout) {
    int n = blockIdx.x;
    int t = threadIdx.x;  // blockDim == C
    float acc = 0.f;
    int s0 = rowstart[n], s1 = rowstart[n + 1];
    for (int s = s0; s < s1; s++) {
        int src = csr_src[s];
        acc += (float)y[(size_t)src * C + t] * dinv[src];
    }
    float v = fmaxf(acc * dinv[n] + bias[t], 0.f);
    out[(size_t)n * ldo + coloff + t] = v;
    if (bout) bout[(size_t)n * C + t] = (__bf16)v;
}

// final = LN(fused + relu(skippre + b_skip)); then 64->32->16->5 MLP.
__global__ void final_kernel(const float* __restrict__ fused,
                             const float* __restrict__ skippre,
                             const float* __restrict__ b_skip,
                             const float* __restrict__ g3, const float* __restrict__ be3,
                             const float* __restrict__ Wc1, const float* __restrict__ bc1,
                             const float* __restrict__ Wc2, const float* __restrict__ bc2,
                             const float* __restrict__ Wc3, const float* __restrict__ bc3,
                             float* __restrict__ out) {
    int n = blockIdx.x;
    int l = threadIdx.x;  // 64
    __shared__ float f[64], h1s[32], h2s[16];
    float sk = fmaxf(skippre[(size_t)n * 64 + l] + b_skip[l], 0.f);
    float v = fused[(size_t)n * 64 + l] + sk;
    float sv = v, sq = v * v;
#pragma unroll
    for (int off = 32; off; off >>= 1) {
        sv += __shfl_xor(sv, off);
        sq += __shfl_xor(sq, off);
    }
    float mu = sv * (1.f / 64.f);
    float var = sq * (1.f / 64.f) - mu * mu;
    float r = rsqrtf(var + 1e-5f);
    f[l] = (v - mu) * r * g3[l] + be3[l];
    __syncthreads();
    if (l < 32) {
        float a = bc1[l];
        for (int i = 0; i < 64; i++) a += f[i] * Wc1[i * 32 + l];
        h1s[l] = fmaxf(a, 0.f);
    }
    __syncthreads();
    if (l < 16) {
        float a = bc2[l];
        for (int i = 0; i < 32; i++) a += h1s[i] * Wc2[i * 16 + l];
        h2s[l] = fmaxf(a, 0.f);
    }
    __syncthreads();
    if (l < 5) {
        float a = bc3[l];
        for (int i = 0; i < 16; i++) a += h2s[i] * Wc3[i * 5 + l];
        out[(size_t)n * 5 + l] = a;
    }
}

// ---------------------------------------------------------------------------
extern "C" void kernel_launch(void* const* d_in, const int* in_sizes, int n_in,
                              void* d_out, int out_size, void* d_ws, size_t ws_size,
                              hipStream_t stream) {
    const float* x      = (const float*)d_in[0];
    const int*   ei     = (const int*)d_in[1];
    const float* W_gat1 = (const float*)d_in[2];
    const float* a_src1 = (const float*)d_in[3];
    const float* a_dst1 = (const float*)d_in[4];
    const float* b_gat1 = (const float*)d_in[5];
    const float* W_gcn1 = (const float*)d_in[6];
    const float* b_gcn1 = (const float*)d_in[7];
    const float* W_gat2 = (const float*)d_in[8];
    const float* a_src2 = (const float*)d_in[9];
    const float* a_dst2 = (const float*)d_in[10];
    const float* b_gat2 = (const float*)d_in[11];
    const float* W_gcn2 = (const float*)d_in[12];
    const float* b_gcn2 = (const float*)d_in[13];
    const float* W_skip = (const float*)d_in[14];
    const float* b_skip = (const float*)d_in[15];
    const float* W_fuse = (const float*)d_in[16];
    const float* b_fuse = (const float*)d_in[17];
    const float* W_c1   = (const float*)d_in[18];
    const float* b_c1   = (const float*)d_in[19];
    const float* W_c2   = (const float*)d_in[20];
    const float* b_c2   = (const float*)d_in[21];
    const float* W_c3   = (const float*)d_in[22];
    const float* b_c3   = (const float*)d_in[23];
    const float* g1     = (const float*)d_in[24];
    const float* be1    = (const float*)d_in[25];
    const float* g2     = (const float*)d_in[26];
    const float* be2    = (const float*)d_in[27];
    const float* g3     = (const float*)d_in[28];
    const float* be3    = (const float*)d_in[29];
    float* out = (float*)d_out;

    // workspace arena
    char* p = (char*)d_ws;
    auto alloc = [&](size_t bytes) {
        char* r = p; p += (bytes + 255) & ~(size_t)255; return r;
    };
    __bf16* xb      = (__bf16*)alloc((size_t)MPAD * KPAD * 2);   // 41.4 MB (swizzled)
    __bf16* wt      = (__bf16*)alloc((size_t)NPAD * KPAD * 2);   // 3.7 MB  (swizzled)
    __bf16* w2t     = (__bf16*)alloc((size_t)512 * 128 * 2);
    __bf16* h1b     = (__bf16*)alloc((size_t)NN * 768 * 2);      // 15.4 MB
    __bf16* h2b     = (__bf16*)alloc((size_t)NN * 512 * 2);      // 10.2 MB
    __bf16* ybufb   = (__bf16*)alloc((size_t)NN * 128 * 2);      // y1 reused y2
    __bf16* x1gcnb  = (__bf16*)alloc((size_t)MPAD * 128 * 2);    // padded, MFMA2 A
    float* asrc     = (float*)alloc((size_t)NN * 6 * 4);
    float* adst     = (float*)alloc((size_t)NN * 6 * 4);
    int*   deg      = (int*)  alloc((size_t)2 * NN * 4);         // deg | cursor
    int*   cursor   = deg + NN;
    float* dinv     = (float*)alloc((size_t)NN * 4);
    int*   rowst    = (int*)  alloc((size_t)(NN + 1) * 4);
    int*   csrc     = (int*)  alloc((size_t)ET * 4);
    float* x1gat    = (float*)alloc((size_t)NN * 128 * 4);
    float* cat      = (float*)alloc((size_t)NN * 192 * 4);
    float* x2gat    = (float*)alloc((size_t)NN * 128 * 4);
    float* skippre  = (float*)alloc((size_t)NN * 64 * 4);
    float* fusedb   = (float*)alloc((size_t)NN * 64 * 4);

    hipMemsetAsync(deg, 0, (size_t)2 * NN * 4, stream);
    hipMemsetAsync(x1gcnb + (size_t)NN * 128, 0, (size_t)(MPAD - NN) * 128 * 2, stream);

    const int EB = (ET + 255) / 256;
    const int MB = (NN + 63) / 64;

    // bf16 conversions (swizzled layouts for GEMM1)
    conv_x_kernel<<<(MPAD / 4) * (KPAD / 512), 256, 0, stream>>>(x, xb);
    conv_w_kernel<<<(NPAD * KPAD / 8 + 255) / 256, 256, 0, stream>>>(W_gat1, W_skip, wt);
    conv_w2_kernel<<<(512 * 128 + 255) / 256, 256, 0, stream>>>(W_gat2, w2t);

    // CSR by dst
    count_kernel  <<<EB, 256, 0, stream>>>(ei, deg);
    scan_kernel   <<<1, 256, 0, stream>>>(deg, rowst, dinv);
    scatter_kernel<<<EB, 256, 0, stream>>>(ei, rowst, cursor, csrc);

    // h1 (bf16) + skippre, XCD-swizzled 64x128-tile BK=64 MFMA GEMM
    mfma_gemm1_kernel<<<1120, 256, 0, stream>>>(xb, wt, h1b, skippre);

    // ---- GAT layer 1 (H=6), softmax fused into aggregation ----
    alpha_kernel<<<(NN * 6 + 3) / 4, 256, 0, stream>>>(h1b, a_src1, a_dst1, asrc, adst, 6);
    gat_agg_kernel<6><<<NN, 256, 0, stream>>>(h1b, asrc, adst, rowst, csrc,
                                              b_gat1, g1, be1, x1gat);
    // ---- GCN layer 1 (fp32 GEMM -> bf16 y) ----
    gemm_kernel<false, false, __bf16><<<dim3(2, MB), 256, 0, stream>>>(
        x1gat, 128, W_gcn1, 128, ybufb, 128, nullptr, NN, 128, 128);
    gcn_agg_kernel<<<NN, 128, 0, stream>>>(ybufb, 128, dinv, rowst, csrc,
                                           b_gcn1, cat, 192, 0, x1gcnb);
    // ---- GAT layer 2 (H=4): h2 = x1_gcn @ W_gat2 (bf16 MFMA) ----
    mfma_gemm2_kernel<<<dim3(4, MPAD / 128), 256, 0, stream>>>(x1gcnb, w2t, h2b);
    alpha_kernel<<<(NN * 4 + 3) / 4, 256, 0, stream>>>(h2b, a_src2, a_dst2, asrc, adst, 4);
    gat_agg_kernel<4><<<NN, 256, 0, stream>>>(h2b, asrc, adst, rowst, csrc,
                                              b_gat2, g2, be2, x2gat);
    // ---- GCN layer 2 (fp32 GEMM -> bf16 y) -> cat[:, 128:192] ----
    gemm_kernel<false, false, __bf16><<<dim3(1, MB), 256, 0, stream>>>(
        x2gat, 128, W_gcn2, 64, ybufb, 64, nullptr, NN, 64, 128);
    gcn_agg_kernel<<<NN, 64, 0, stream>>>(ybufb, 64, dinv, rowst, csrc,
                                          b_gcn2, cat, 192, 128, nullptr);
    // ---- fuse (fp32) + final ----
    gemm_kernel<true, true, float><<<dim3(1, MB), 256, 0, stream>>>(
        cat, 192, W_fuse, 64, fusedb, 64, b_fuse, NN, 64, 192);
    final_kernel<<<NN, 64, 0, stream>>>(fusedb, skippre, b_skip, g3, be3,
                                        W_c1, b_c1, W_c2, b_c2, W_c3, b_c3, out);
}

// Round 7
// 531.392 us; speedup vs baseline: 2.8172x; 1.0040x over previous
//
#include <hip/hip_runtime.h>
#include <cstdint>
#include <cstddef>

#define NN 10000
#define NE 160000
#define ET (NE + NN)          // edges + self loops
#define FIN 2000
#define MPAD 10112            // 158 * 64
#define KPAD 2048
#define NPAD 896              // 7 * 128 (768 gat1 cols + 64 skip + 64 pad)

typedef __bf16 bf16x8 __attribute__((ext_vector_type(8)));
typedef __bf16 bf16x4 __attribute__((ext_vector_type(4)));
typedef float  f32x4  __attribute__((ext_vector_type(4)));

#define GLL(src, dst) __builtin_amdgcn_global_load_lds( \
    (const __attribute__((address_space(1))) void*)(src), \
    (__attribute__((address_space(3))) void*)(dst), 16, 0, 0)

// ---------------------------------------------------------------------------
// CSR build
// ---------------------------------------------------------------------------
__device__ __forceinline__ void edge_sd(const int* ei, int e, int& s, int& d) {
    if (e < NE) { s = ei[e]; d = ei[NE + e]; }
    else        { s = e - NE; d = e - NE; }
}

__global__ void count_kernel(const int* ei, int* deg) {
    int e = blockIdx.x * blockDim.x + threadIdx.x;
    if (e >= ET) return;
    int s, d; edge_sd(ei, e, s, d);
    atomicAdd(&deg[d], 1);
}

// exclusive scan over deg -> rowstart[0..NN]; also dinv = deg^-1/2
__global__ void scan_kernel(const int* deg, int* rowstart, float* dinv) {
    __shared__ int partial[256];
    const int T = 256;
    int chunk = (NN + T - 1) / T;
    int t = threadIdx.x;
    int begin = t * chunk;
    int end = begin + chunk; if (end > NN) end = NN;
    int s = 0;
    for (int i = begin; i < end && i >= begin; i++) s += deg[i];
    partial[t] = s;
    __syncthreads();
    if (t == 0) {
        int run = 0;
        for (int i = 0; i < T; i++) { int v = partial[i]; partial[i] = run; run += v; }
    }
    __syncthreads();
    int run = partial[t];
    for (int i = begin; i < end && i >= begin; i++) {
        rowstart[i] = run; run += deg[i];
        int dg = deg[i];
        dinv[i] = dg > 0 ? rsqrtf((float)dg) : 0.f;
    }
    if (end == NN && begin <= NN) rowstart[NN] = run;
}

__global__ void scatter_kernel(const int* ei, const int* rowstart, int* cursor,
                               int* csr_src) {
    int e = blockIdx.x * blockDim.x + threadIdx.x;
    if (e >= ET) return;
    int s, d; edge_sd(ei, e, s, d);
    int pos = atomicAdd(&cursor[d], 1);
    csr_src[rowstart[d] + pos] = s;
}

// ---------------------------------------------------------------------------
// Swizzled bf16 conversions.
// xb (64-row tiles, BK=64 slabs, 8 planes of 8 k):
//   chunk c = ((rt*32 + ks)*8 + p)*64 + r  holds x[rt*64+r][ks*64+p*8 ..+8)
// wt (128-row tiles): c = ((ct*32 + ks)*8 + p)*128 + r
// w2t (128-row tiles, K=128, 16 planes): c = (ct*16 + p)*128 + r
// ---------------------------------------------------------------------------
__global__ void conv_x_kernel(const float* __restrict__ x, __bf16* __restrict__ xb) {
    int bg = blockIdx.x;
    int bg_k = bg & 3, bg_row = bg >> 2;
    int tid = threadIdx.x;
    int row = bg_row * 4 + (tid >> 6);
    int kc = bg_k * 64 + (tid & 63);
    int k = kc * 8;
    int rt = row >> 6, r = row & 63;
    int ks = kc >> 3, p = kc & 7;
    size_t c = ((size_t)(rt * 32 + ks) * 8 + p) * 64 + r;
    bf16x8 o;
    if (row < NN && k < FIN) {
        const float4 v0 = *(const float4*)(x + (size_t)row * FIN + k);
        const float4 v1 = *(const float4*)(x + (size_t)row * FIN + k + 4);
        o[0] = (__bf16)v0.x; o[1] = (__bf16)v0.y; o[2] = (__bf16)v0.z; o[3] = (__bf16)v0.w;
        o[4] = (__bf16)v1.x; o[5] = (__bf16)v1.y; o[6] = (__bf16)v1.z; o[7] = (__bf16)v1.w;
    } else {
#pragma unroll
        for (int i = 0; i < 8; i++) o[i] = (__bf16)0.f;
    }
    *(bf16x8*)(xb + c * 8) = o;
}

#define NW1 (NPAD * KPAD / 8)
__global__ void conv_w_kernel(const float* __restrict__ Wg, const float* __restrict__ Ws,
                              const float* __restrict__ W2,
                              __bf16* __restrict__ wt, __bf16* __restrict__ w2t) {
    int g = blockIdx.x * blockDim.x + threadIdx.x;
    if (g < NW1) {
        int r = g & 127, p = (g >> 7) & 7, ks = (g >> 10) & 31, ct = g >> 15;
        int n = ct * 128 + r;
        int k0 = ks * 64 + p * 8;
        bf16x8 o;
#pragma unroll
        for (int j = 0; j < 8; j++) {
            int k = k0 + j;
            float v = 0.f;
            if (k < FIN) {
                if (n < 768)      v = Wg[(size_t)k * 768 + n];
                else if (n < 832) v = Ws[(size_t)k * 64 + (n - 768)];
            }
            o[j] = (__bf16)v;
        }
        *(bf16x8*)(wt + (size_t)g * 8) = o;
    } else if (g < NW1 + 512 * 128 / 8) {
        int g2 = g - NW1;
        int c = g2 & 2047;            // chunk within ct-tile (16 planes x 128)
        int ct = g2 >> 11;
        int p = c >> 7, r = c & 127;
        int n = ct * 128 + r;
        int k0 = p * 8;
        bf16x8 o;
#pragma unroll
        for (int j = 0; j < 8; j++)
            o[j] = (__bf16)W2[(size_t)(k0 + j) * 512 + n];
        *(bf16x8*)(w2t + (size_t)g2 * 8) = o;
    }
}

// ---------------------------------------------------------------------------
// MFMA GEMM 1: xb @ wt^T -> h1b bf16[NN,768], skippre f32[NN,64], + fused
// alpha1 (asrc/adst per node/head from fp32 accumulators).
// 64M x 128N block, 2 waves (64x64 each), BK=64, coalesced swizzled staging.
// ---------------------------------------------------------------------------
__global__ __launch_bounds__(128)
void mfma_gemm1_kernel(const __bf16* __restrict__ xb, const __bf16* __restrict__ wt,
                       const float* __restrict__ a_src1, const float* __restrict__ a_dst1,
                       __bf16* __restrict__ h1b, float* __restrict__ skippre,
                       float* __restrict__ asrc, float* __restrict__ adst) {
    __shared__ __bf16 As[4096];    // 8 planes x 64 rows x 8  (8 KB)
    __shared__ __bf16 Bs[8192];    // 8 planes x 128 rows x 8 (16 KB)
    __shared__ float sA[64], sD[64];
    __shared__ float asd[256];
    int b = blockIdx.x;
    int xcd = b & 7, j = b >> 3;          // j 0..139
    int jq = j / 7;                        // 0..19
    int rt = xcd + 8 * jq;                 // 0..159
    int ct = j - 7 * jq;                   // 0..6
    if (rt >= MPAD / 64) return;
    const int bi = rt * 64;
    const int bn = ct * 128;

    const int tid = threadIdx.x;
    const int lane = tid & 63;
    const int w = tid >> 6;                // 0,1 = N halves
    const int q = lane >> 4, m16 = lane & 15;

    if (tid < 64) { sA[tid] = 0.f; sD[tid] = 0.f; }
    if (ct < 6) {
        asd[tid]       = a_src1[ct * 128 + tid];
        asd[128 + tid] = a_dst1[ct * 128 + tid];
    }

    f32x4 acc[4][4] = {};

    for (int ks = 0; ks < KPAD / 64; ks++) {
        const size_t slabA = (size_t)(rt * 32 + ks) * 512;
        const size_t slabB = (size_t)(ct * 32 + ks) * 1024;
#pragma unroll
        for (int i = 0; i < 4; i++) {
            int seg = i * 2 + w;           // 0..7
            GLL(xb + (slabA + seg * 64 + lane) * 8, As + seg * 512);
        }
#pragma unroll
        for (int i = 0; i < 8; i++) {
            int seg = i * 2 + w;           // 0..15
            GLL(wt + (slabB + seg * 64 + lane) * 8, Bs + seg * 512);
        }
        __syncthreads();

#pragma unroll
        for (int kk = 0; kk < 2; kk++) {
            const int pb = kk * 4 + q;
            bf16x8 af[4], bfr[4];
#pragma unroll
            for (int mt = 0; mt < 4; mt++)
                af[mt] = *(const bf16x8*)(As + (pb * 64 + mt * 16 + m16) * 8);
#pragma unroll
            for (int nt = 0; nt < 4; nt++)
                bfr[nt] = *(const bf16x8*)(Bs + (pb * 128 + w * 64 + nt * 16 + m16) * 8);
#pragma unroll
            for (int mt = 0; mt < 4; mt++)
#pragma unroll
                for (int nt = 0; nt < 4; nt++)
                    acc[mt][nt] = __builtin_amdgcn_mfma_f32_16x16x32_bf16(af[mt], bfr[nt], acc[mt][nt], 0, 0, 0);
        }
        __syncthreads();
    }

    // epilogue: stores + fused alpha. C map: row=bi+mt*16+q*4+r, col=bn+w*64+nt*16+m16
#pragma unroll
    for (int mt = 0; mt < 4; mt++) {
#pragma unroll
        for (int r = 0; r < 4; r++) {
            int rowl = mt * 16 + q * 4 + r;
            int row = bi + rowl;
            float ps = 0.f, pd = 0.f;
#pragma unroll
            for (int nt = 0; nt < 4; nt++) {
                int coll = w * 64 + nt * 16 + m16;
                int col = bn + coll;
                float v = acc[mt][nt][r];
                if (ct < 6) { ps += v * asd[coll]; pd += v * asd[128 + coll]; }
                if (row < NN) {
                    if (col < 768)      h1b[(size_t)row * 768 + col] = (__bf16)v;
                    else if (col < 832) skippre[(size_t)row * 64 + (col - 768)] = v;
                }
            }
            if (ct < 6) {
#pragma unroll
                for (int off = 1; off < 16; off <<= 1) {
                    ps += __shfl_xor(ps, off);
                    pd += __shfl_xor(pd, off);
                }
                if (m16 == 0) { atomicAdd(&sA[rowl], ps); atomicAdd(&sD[rowl], pd); }
            }
        }
    }
    if (ct < 6) {
        __syncthreads();
        if (tid < 64) {
            int row = bi + tid;
            if (row < NN) { asrc[row * 6 + ct] = sA[tid]; adst[row * 6 + ct] = sD[tid]; }
        }
    }
}

// ---------------------------------------------------------------------------
// MFMA GEMM 2: x1gcnb(swizzled)[MPAD,128] @ w2t(swizzled)[512,128]^T -> h2b
// bf16[NN,512], + fused alpha2. 64x128 block, 2 waves, BK=64 (2 iters).
// ---------------------------------------------------------------------------
__global__ __launch_bounds__(128)
void mfma_gemm2_kernel(const __bf16* __restrict__ A, const __bf16* __restrict__ B,
                       const float* __restrict__ a_src2, const float* __restrict__ a_dst2,
                       __bf16* __restrict__ h2b,
                       float* __restrict__ asrc, float* __restrict__ adst) {
    __shared__ __bf16 As[4096];
    __shared__ __bf16 Bs[8192];
    __shared__ float sA[64], sD[64];
    __shared__ float asd[256];
    const int rt = blockIdx.y, ct = blockIdx.x;
    const int bi = rt * 64, bn = ct * 128;
    const int tid = threadIdx.x, lane = tid & 63, w = tid >> 6;
    const int q = lane >> 4, m16 = lane & 15;

    if (tid < 64) { sA[tid] = 0.f; sD[tid] = 0.f; }
    asd[tid]       = a_src2[ct * 128 + tid];
    asd[128 + tid] = a_dst2[ct * 128 + tid];

    f32x4 acc[4][4] = {};

    for (int ks = 0; ks < 2; ks++) {
        const size_t slabA = (size_t)rt * 1024 + ks * 512;
        const size_t slabB = (size_t)ct * 2048 + ks * 1024;
#pragma unroll
        for (int i = 0; i < 4; i++) {
            int seg = i * 2 + w;
            GLL(A + (slabA + seg * 64 + lane) * 8, As + seg * 512);
        }
#pragma unroll
        for (int i = 0; i < 8; i++) {
            int seg = i * 2 + w;
            GLL(B + (slabB + seg * 64 + lane) * 8, Bs + seg * 512);
        }
        __syncthreads();

#pragma unroll
        for (int kk = 0; kk < 2; kk++) {
            const int pb = kk * 4 + q;
            bf16x8 af[4], bfr[4];
#pragma unroll
            for (int mt = 0; mt < 4; mt++)
                af[mt] = *(const bf16x8*)(As + (pb * 64 + mt * 16 + m16) * 8);
#pragma unroll
            for (int nt = 0; nt < 4; nt++)
                bfr[nt] = *(const bf16x8*)(Bs + (pb * 128 + w * 64 + nt * 16 + m16) * 8);
#pragma unroll
            for (int mt = 0; mt < 4; mt++)
#pragma unroll
                for (int nt = 0; nt < 4; nt++)
                    acc[mt][nt] = __builtin_amdgcn_mfma_f32_16x16x32_bf16(af[mt], bfr[nt], acc[mt][nt], 0, 0, 0);
        }
        __syncthreads();
    }

#pragma unroll
    for (int mt = 0; mt < 4; mt++) {
#pragma unroll
        for (int r = 0; r < 4; r++) {
            int rowl = mt * 16 + q * 4 + r;
            int row = bi + rowl;
            float ps = 0.f, pd = 0.f;
#pragma unroll
            for (int nt = 0; nt < 4; nt++) {
                int coll = w * 64 + nt * 16 + m16;
                float v = acc[mt][nt][r];
                ps += v * asd[coll]; pd += v * asd[128 + coll];
                if (row < NN) h2b[(size_t)row * 512 + bn + coll] = (__bf16)v;
            }
#pragma unroll
            for (int off = 1; off < 16; off <<= 1) {
                ps += __shfl_xor(ps, off);
                pd += __shfl_xor(pd, off);
            }
            if (m16 == 0) { atomicAdd(&sA[rowl], ps); atomicAdd(&sD[rowl], pd); }
        }
    }
    __syncthreads();
    if (tid < 64) {
        int row = bi + tid;
        if (row < NN) { asrc[row * 4 + ct] = sA[tid]; adst[row * 4 + ct] = sD[tid]; }
    }
}

// ---------------------------------------------------------------------------
// Generic fp32-accum tiled GEMM (small GEMMs), templated output type
// ---------------------------------------------------------------------------
template<bool RELU, bool BIAS, typename OUT>
__global__ void gemm_kernel(const float* __restrict__ A, int lda,
                            const float* __restrict__ B, int ldb,
                            OUT* __restrict__ C, int ldc,
                            const float* __restrict__ bias,
                            int M, int N, int K) {
    __shared__ float As[16][65];
    __shared__ float Bs[16][64];
    int bi = blockIdx.y * 64, bj = blockIdx.x * 64;
    int tid = threadIdx.x;
    int tx = tid & 15, ty = tid >> 4;
    float acc[4][4] = {};
    for (int k0 = 0; k0 < K; k0 += 16) {
        {
            int kk = tid & 15, mm = tid >> 4;
#pragma unroll
            for (int it = 0; it < 4; it++) {
                int row = mm + 16 * it;
                int gr = bi + row;
                As[kk][row] = (gr < M) ? A[(size_t)gr * lda + k0 + kk] : 0.f;
            }
        }
        {
            int nn = tid & 63, kk = tid >> 6;
#pragma unroll
            for (int it = 0; it < 4; it++)
                Bs[kk + 4 * it][nn] = B[(size_t)(k0 + kk + 4 * it) * ldb + bj + nn];
        }
        __syncthreads();
#pragma unroll
        for (int kk = 0; kk < 16; kk++) {
            float av[4], bv[4];
#pragma unroll
            for (int a = 0; a < 4; a++) av[a] = As[kk][ty * 4 + a];
#pragma unroll
            for (int b = 0; b < 4; b++) bv[b] = Bs[kk][tx * 4 + b];
#pragma unroll
            for (int a = 0; a < 4; a++)
#pragma unroll
                for (int b = 0; b < 4; b++)
                    acc[a][b] += av[a] * bv[b];
        }
        __syncthreads();
    }
#pragma unroll
    for (int a = 0; a < 4; a++) {
        int gr = bi + ty * 4 + a;
        if (gr >= M) continue;
#pragma unroll
        for (int b = 0; b < 4; b++) {
            int gc = bj + tx * 4 + b;
            float v = acc[a][b];
            if (BIAS) v += bias[gc];
            if (RELU) v = fmaxf(v, 0.f);
            C[(size_t)gr * ldc + gc] = (OUT)v;
        }
    }
}

// ---------------------------------------------------------------------------
// Fused segment-softmax + aggregation + head-mean + bias + LN + ReLU.
// ---------------------------------------------------------------------------
template<int H>
__global__ void gat_agg_kernel(const __bf16* __restrict__ hb,
                               const float* __restrict__ asrc,
                               const float* __restrict__ adst,
                               const int* __restrict__ rowstart,
                               const int* __restrict__ csr_src,
                               const float* __restrict__ bias,
                               const float* __restrict__ gamma,
                               const float* __restrict__ beta,
                               float* __restrict__ out) {
    constexpr int CH = H * 128;
    int n = blockIdx.x;
    int t = threadIdx.x;
    int w = t >> 6, l = t & 63;
    __shared__ float invden[H];
    __shared__ float denw[4][H];
    __shared__ float sm[4 * CH];
    __shared__ float red[8];

    int s0 = rowstart[n], s1 = rowstart[n + 1];
    float adst_n = (l < H) ? adst[n * H + l] : 0.f;

    // phase 1: denominators
    float dloc = 0.f;
    for (int s = s0 + w; s < s1; s += 4) {
        int src = csr_src[s];
        if (l < H) {
            float al = asrc[src * H + l] + adst_n;
            al = al >= 0.f ? al : 0.2f * al;
            dloc += __expf(al);
        }
    }
    if (l < H) denw[w][l] = dloc;
    __syncthreads();
    if (t < H) invden[t] = 1.f / (denw[0][t] + denw[1][t] + denw[2][t] + denw[3][t]);
    __syncthreads();

    // phase 2: weighted feature accumulation, bf16x8 loads
    constexpr int NA = (H == 6) ? 12 : 8;
    float acc[NA] = {};
    for (int s = s0 + w; s < s1; s += 4) {
        int src = csr_src[s];
        float ev = 0.f;
        if (l < H) {
            float al = asrc[src * H + l] + adst_n;
            al = al >= 0.f ? al : 0.2f * al;
            ev = __expf(al);
        }
        const __bf16* hp = hb + (size_t)src * CH;
        {   // group 0: channels l*8..l*8+7, head = l>>4
            float wgt = __shfl(ev, l >> 4);
            bf16x8 hv = *(const bf16x8*)(hp + l * 8);
#pragma unroll
            for (int jj = 0; jj < 8; jj++) acc[jj] += (float)hv[jj] * wgt;
        }
        if (H == 6) {   // group 1: channels 512 + l*4, head = 4 + (l>>5)
            float wgt = __shfl(ev, 4 + (l >> 5));
            bf16x4 hv = *(const bf16x4*)(hp + 512 + l * 4);
#pragma unroll
            for (int jj = 0; jj < 4; jj++) acc[8 + jj] += (float)hv[jj] * wgt;
        }
    }
    *(f32x4*)(sm + w * CH + l * 8)     = *(f32x4*)(acc);
    *(f32x4*)(sm + w * CH + l * 8 + 4) = *(f32x4*)(acc + 4);
    if (H == 6)
        *(f32x4*)(sm + w * CH + 512 + l * 4) = *(f32x4*)(acc + 8);
    __syncthreads();

    float v = 0.f;
    if (t < 128) {
#pragma unroll
        for (int hh = 0; hh < H; hh++) {
            float hsum = 0.f;
#pragma unroll
            for (int ww = 0; ww < 4; ww++) hsum += sm[ww * CH + hh * 128 + t];
            v += hsum * invden[hh];
        }
        v = v * (1.f / H) + bias[t];
    }
    float sv = (t < 128) ? v : 0.f;
    float sq = (t < 128) ? v * v : 0.f;
#pragma unroll
    for (int off = 32; off; off >>= 1) {
        sv += __shfl_down(sv, off);
        sq += __shfl_down(sq, off);
    }
    if ((t & 63) == 0) { red[w * 2] = sv; red[w * 2 + 1] = sq; }
    __syncthreads();
    float tot = red[0] + red[2] + red[4] + red[6];
    float tsq = red[1] + red[3] + red[5] + red[7];
    float mu = tot * (1.f / 128.f);
    float var = tsq * (1.f / 128.f) - mu * mu;
    float r = rsqrtf(var + 1e-5f);
    if (t < 128) {
        float o = (v - mu) * r * gamma[t] + beta[t];
        out[(size_t)n * 128 + t] = fmaxf(o, 0.f);
    }
}

// per-node GCN aggregation from bf16 y; fp32 cat slice + optional swizzled bf16
__global__ void gcn_agg_kernel(const __bf16* __restrict__ y, int C,
                               const float* __restrict__ dinv,
                               const int* __restrict__ rowstart,
                               const int* __restrict__ csr_src,
                               const float* __restrict__ bias,
                               float* __restrict__ out, int ldo, int coloff,
                               __bf16* __restrict__ bout) {
    int n = blockIdx.x;
    int t = threadIdx.x;  // blockDim == C
    float acc = 0.f;
    int s0 = rowstart[n], s1 = rowstart[n + 1];
    for (int s = s0; s < s1; s++) {
        int src = csr_src[s];
        acc += (float)y[(size_t)src * C + t] * dinv[src];
    }
    float v = fmaxf(acc * dinv[n] + bias[t], 0.f);
    out[(size_t)n * ldo + coloff + t] = v;
    if (bout) {
        // swizzled layout for mfma_gemm2: idx = ((rt*16 + p)*64 + r)*8 + off
        int rt = n >> 6, r = n & 63, p = t >> 3, off = t & 7;
        bout[((size_t)(rt * 16 + p) * 64 + r) * 8 + off] = (__bf16)v;
    }
}

// final = LN(fused + relu(skippre + b_skip)); then 64->32->16->5 MLP.
__global__ void final_kernel(const float* __restrict__ fused,
                             const float* __restrict__ skippre,
                             const float* __restrict__ b_skip,
                             const float* __restrict__ g3, const float* __restrict__ be3,
                             const float* __restrict__ Wc1, const float* __restrict__ bc1,
                             const float* __restrict__ Wc2, const float* __restrict__ bc2,
                             const float* __restrict__ Wc3, const float* __restrict__ bc3,
                             float* __restrict__ out) {
    int n = blockIdx.x;
    int l = threadIdx.x;  // 64
    __shared__ float f[64], h1s[32], h2s[16];
    float sk = fmaxf(skippre[(size_t)n * 64 + l] + b_skip[l], 0.f);
    float v = fused[(size_t)n * 64 + l] + sk;
    float sv = v, sq = v * v;
#pragma unroll
    for (int off = 32; off; off >>= 1) {
        sv += __shfl_xor(sv, off);
        sq += __shfl_xor(sq, off);
    }
    float mu = sv * (1.f / 64.f);
    float var = sq * (1.f / 64.f) - mu * mu;
    float r = rsqrtf(var + 1e-5f);
    f[l] = (v - mu) * r * g3[l] + be3[l];
    __syncthreads();
    if (l < 32) {
        float a = bc1[l];
        for (int i = 0; i < 64; i++) a += f[i] * Wc1[i * 32 + l];
        h1s[l] = fmaxf(a, 0.f);
    }
    __syncthreads();
    if (l < 16) {
        float a = bc2[l];
        for (int i = 0; i < 32; i++) a += h1s[i] * Wc2[i * 16 + l];
        h2s[l] = fmaxf(a, 0.f);
    }
    __syncthreads();
    if (l < 5) {
        float a = bc3[l];
        for (int i = 0; i < 16; i++) a += h2s[i] * Wc3[i * 5 + l];
        out[(size_t)n * 5 + l] = a;
    }
}

// ---------------------------------------------------------------------------
extern "C" void kernel_launch(void* const* d_in, const int* in_sizes, int n_in,
                              void* d_out, int out_size, void* d_ws, size_t ws_size,
                              hipStream_t stream) {
    const float* x      = (const float*)d_in[0];
    const int*   ei     = (const int*)d_in[1];
    const float* W_gat1 = (const float*)d_in[2];
    const float* a_src1 = (const float*)d_in[3];
    const float* a_dst1 = (const float*)d_in[4];
    const float* b_gat1 = (const float*)d_in[5];
    const float* W_gcn1 = (const float*)d_in[6];
    const float* b_gcn1 = (const float*)d_in[7];
    const float* W_gat2 = (const float*)d_in[8];
    const float* a_src2 = (const float*)d_in[9];
    const float* a_dst2 = (const float*)d_in[10];
    const float* b_gat2 = (const float*)d_in[11];
    const float* W_gcn2 = (const float*)d_in[12];
    const float* b_gcn2 = (const float*)d_in[13];
    const float* W_skip = (const float*)d_in[14];
    const float* b_skip = (const float*)d_in[15];
    const float* W_fuse = (const float*)d_in[16];
    const float* b_fuse = (const float*)d_in[17];
    const float* W_c1   = (const float*)d_in[18];
    const float* b_c1   = (const float*)d_in[19];
    const float* W_c2   = (const float*)d_in[20];
    const float* b_c2   = (const float*)d_in[21];
    const float* W_c3   = (const float*)d_in[22];
    const float* b_c3   = (const float*)d_in[23];
    const float* g1     = (const float*)d_in[24];
    const float* be1    = (const float*)d_in[25];
    const float* g2     = (const float*)d_in[26];
    const float* be2    = (const float*)d_in[27];
    const float* g3     = (const float*)d_in[28];
    const float* be3    = (const float*)d_in[29];
    float* out = (float*)d_out;

    // workspace arena
    char* p = (char*)d_ws;
    auto alloc = [&](size_t bytes) {
        char* r = p; p += (bytes + 255) & ~(size_t)255; return r;
    };
    __bf16* xb      = (__bf16*)alloc((size_t)MPAD * KPAD * 2);   // 41.4 MB (swizzled)
    __bf16* wt      = (__bf16*)alloc((size_t)NPAD * KPAD * 2);   // 3.7 MB  (swizzled)
    __bf16* w2t     = (__bf16*)alloc((size_t)512 * 128 * 2);     // swizzled
    __bf16* h1b     = (__bf16*)alloc((size_t)NN * 768 * 2);      // 15.4 MB
    __bf16* h2b     = (__bf16*)alloc((size_t)NN * 512 * 2);      // 10.2 MB
    __bf16* ybufb   = (__bf16*)alloc((size_t)NN * 128 * 2);      // y1 reused y2
    __bf16* x1gcnb  = (__bf16*)alloc((size_t)MPAD * 128 * 2);    // swizzled, MFMA2 A
    float* asrc     = (float*)alloc((size_t)NN * 6 * 4);
    float* adst     = (float*)alloc((size_t)NN * 6 * 4);
    int*   deg      = (int*)  alloc((size_t)2 * NN * 4);         // deg | cursor
    int*   cursor   = deg + NN;
    float* dinv     = (float*)alloc((size_t)NN * 4);
    int*   rowst    = (int*)  alloc((size_t)(NN + 1) * 4);
    int*   csrc     = (int*)  alloc((size_t)ET * 4);
    float* x1gat    = (float*)alloc((size_t)NN * 128 * 4);
    float* cat      = (float*)alloc((size_t)NN * 192 * 4);
    float* x2gat    = (float*)alloc((size_t)NN * 128 * 4);
    float* skippre  = (float*)alloc((size_t)NN * 64 * 4);
    float* fusedb   = (float*)alloc((size_t)NN * 64 * 4);

    hipMemsetAsync(deg, 0, (size_t)2 * NN * 4, stream);
    hipMemsetAsync(x1gcnb, 0, (size_t)MPAD * 128 * 2, stream);  // pad rows interleaved

    const int EB = (ET + 255) / 256;
    const int MB = (NN + 63) / 64;

    // bf16 conversions (swizzled layouts)
    conv_x_kernel<<<(MPAD / 4) * (KPAD / 512), 256, 0, stream>>>(x, xb);
    conv_w_kernel<<<(NW1 + 512 * 128 / 8 + 255) / 256, 256, 0, stream>>>(
        W_gat1, W_skip, W_gat2, wt, w2t);

    // CSR by dst
    count_kernel  <<<EB, 256, 0, stream>>>(ei, deg);
    scan_kernel   <<<1, 256, 0, stream>>>(deg, rowst, dinv);
    scatter_kernel<<<EB, 256, 0, stream>>>(ei, rowst, cursor, csrc);

    // h1 (bf16) + skippre + fused alpha1, XCD-swizzled 64x128 BK=64 MFMA GEMM
    mfma_gemm1_kernel<<<1120, 128, 0, stream>>>(xb, wt, a_src1, a_dst1,
                                                h1b, skippre, asrc, adst);

    // ---- GAT layer 1 (H=6) ----
    gat_agg_kernel<6><<<NN, 256, 0, stream>>>(h1b, asrc, adst, rowst, csrc,
                                              b_gat1, g1, be1, x1gat);
    // ---- GCN layer 1 (fp32 GEMM -> bf16 y) ----
    gemm_kernel<false, false, __bf16><<<dim3(2, MB), 256, 0, stream>>>(
        x1gat, 128, W_gcn1, 128, ybufb, 128, nullptr, NN, 128, 128);
    gcn_agg_kernel<<<NN, 128, 0, stream>>>(ybufb, 128, dinv, rowst, csrc,
                                           b_gcn1, cat, 192, 0, x1gcnb);
    // ---- GAT layer 2 (H=4): h2 + fused alpha2 (bf16 MFMA) ----
    mfma_gemm2_kernel<<<dim3(4, MPAD / 64), 128, 0, stream>>>(
        x1gcnb, w2t, a_src2, a_dst2, h2b, asrc, adst);
    gat_agg_kernel<4><<<NN, 256, 0, stream>>>(h2b, asrc, adst, rowst, csrc,
                                              b_gat2, g2, be2, x2gat);
    // ---- GCN layer 2 (fp32 GEMM -> bf16 y) -> cat[:, 128:192] ----
    gemm_kernel<false, false, __bf16><<<dim3(1, MB), 256, 0, stream>>>(
        x2gat, 128, W_gcn2, 64, ybufb, 64, nullptr, NN, 64, 128);
    gcn_agg_kernel<<<NN, 64, 0, stream>>>(ybufb, 64, dinv, rowst, csrc,
                                          b_gcn2, cat, 192, 128, nullptr);
    // ---- fuse (fp32) + final ----
    gemm_kernel<true, true, float><<<dim3(1, MB), 256, 0, stream>>>(
        cat, 192, W_fuse, 64, fusedb, 64, b_fuse, NN, 64, 192);
    final_kernel<<<NN, 64, 0, stream>>>(fusedb, skippre, b_skip, g3, be3,
                                        W_c1, b_c1, W_c2, b_c2, W_c3, b_c3, out);
}

// Round 8
// 504.164 us; speedup vs baseline: 2.9694x; 1.0540x over previous
//
#include <hip/hip_runtime.h>
#include <cstdint>
#include <cstddef>

#define NN 10000
#define NE 160000
#define ET (NE + NN)          // edges + self loops
#define FIN 2000
#define MPAD 10112            // 158 * 64
#define KPAD 2048
#define NPAD 896              // 7 * 128 (768 gat1 cols + 64 skip + 64 pad)

typedef __bf16 bf16x8 __attribute__((ext_vector_type(8)));
typedef __bf16 bf16x4 __attribute__((ext_vector_type(4)));
typedef float  f32x4  __attribute__((ext_vector_type(4)));

#define GLL(src, dst) __builtin_amdgcn_global_load_lds( \
    (const __attribute__((address_space(1))) void*)(src), \
    (__attribute__((address_space(3))) void*)(dst), 16, 0, 0)

// ---------------------------------------------------------------------------
// CSR build
// ---------------------------------------------------------------------------
__device__ __forceinline__ void edge_sd(const int* ei, int e, int& s, int& d) {
    if (e < NE) { s = ei[e]; d = ei[NE + e]; }
    else        { s = e - NE; d = e - NE; }
}

__global__ void count_kernel(const int* ei, int* deg) {
    int e = blockIdx.x * blockDim.x + threadIdx.x;
    if (e >= ET) return;
    int s, d; edge_sd(ei, e, s, d);
    atomicAdd(&deg[d], 1);
}

// exclusive scan over deg -> rowstart[0..NN]; also dinv = deg^-1/2
__global__ void scan_kernel(const int* deg, int* rowstart, float* dinv) {
    __shared__ int partial[256];
    const int T = 256;
    int chunk = (NN + T - 1) / T;
    int t = threadIdx.x;
    int begin = t * chunk;
    int end = begin + chunk; if (end > NN) end = NN;
    int s = 0;
    for (int i = begin; i < end && i >= begin; i++) s += deg[i];
    partial[t] = s;
    __syncthreads();
    if (t == 0) {
        int run = 0;
        for (int i = 0; i < T; i++) { int v = partial[i]; partial[i] = run; run += v; }
    }
    __syncthreads();
    int run = partial[t];
    for (int i = begin; i < end && i >= begin; i++) {
        rowstart[i] = run; run += deg[i];
        int dg = deg[i];
        dinv[i] = dg > 0 ? rsqrtf((float)dg) : 0.f;
    }
    if (end == NN && begin <= NN) rowstart[NN] = run;
}

__global__ void scatter_kernel(const int* ei, const int* rowstart, int* cursor,
                               int* csr_src) {
    int e = blockIdx.x * blockDim.x + threadIdx.x;
    if (e >= ET) return;
    int s, d; edge_sd(ei, e, s, d);
    int pos = atomicAdd(&cursor[d], 1);
    csr_src[rowstart[d] + pos] = s;
}

// ---------------------------------------------------------------------------
// Swizzled bf16 conversions.
// xb (64-row tiles, BK=64 slabs, 8 planes of 8 k):
//   chunk c = ((rt*32 + ks)*8 + p)*64 + r  holds x[rt*64+r][ks*64+p*8 ..+8)
// wt (128-row tiles): c = ((ct*32 + ks)*8 + p)*128 + r
// w2t (128-row tiles, K=128, 16 planes): c = (ct*16 + p)*128 + r
// ---------------------------------------------------------------------------
__global__ void conv_x_kernel(const float* __restrict__ x, __bf16* __restrict__ xb) {
    int bg = blockIdx.x;
    int bg_k = bg & 3, bg_row = bg >> 2;
    int tid = threadIdx.x;
    int row = bg_row * 4 + (tid >> 6);
    int kc = bg_k * 64 + (tid & 63);
    int k = kc * 8;
    int rt = row >> 6, r = row & 63;
    int ks = kc >> 3, p = kc & 7;
    size_t c = ((size_t)(rt * 32 + ks) * 8 + p) * 64 + r;
    bf16x8 o;
    if (row < NN && k < FIN) {
        const float4 v0 = *(const float4*)(x + (size_t)row * FIN + k);
        const float4 v1 = *(const float4*)(x + (size_t)row * FIN + k + 4);
        o[0] = (__bf16)v0.x; o[1] = (__bf16)v0.y; o[2] = (__bf16)v0.z; o[3] = (__bf16)v0.w;
        o[4] = (__bf16)v1.x; o[5] = (__bf16)v1.y; o[6] = (__bf16)v1.z; o[7] = (__bf16)v1.w;
    } else {
#pragma unroll
        for (int i = 0; i < 8; i++) o[i] = (__bf16)0.f;
    }
    *(bf16x8*)(xb + c * 8) = o;
}

#define NW1 (NPAD * KPAD / 8)
__global__ void conv_w_kernel(const float* __restrict__ Wg, const float* __restrict__ Ws,
                              const float* __restrict__ W2,
                              __bf16* __restrict__ wt, __bf16* __restrict__ w2t) {
    int g = blockIdx.x * blockDim.x + threadIdx.x;
    if (g < NW1) {
        int r = g & 127, p = (g >> 7) & 7, ks = (g >> 10) & 31, ct = g >> 15;
        int n = ct * 128 + r;
        int k0 = ks * 64 + p * 8;
        bf16x8 o;
#pragma unroll
        for (int j = 0; j < 8; j++) {
            int k = k0 + j;
            float v = 0.f;
            if (k < FIN) {
                if (n < 768)      v = Wg[(size_t)k * 768 + n];
                else if (n < 832) v = Ws[(size_t)k * 64 + (n - 768)];
            }
            o[j] = (__bf16)v;
        }
        *(bf16x8*)(wt + (size_t)g * 8) = o;
    } else if (g < NW1 + 512 * 128 / 8) {
        int g2 = g - NW1;
        int c = g2 & 2047;            // chunk within ct-tile (16 planes x 128)
        int ct = g2 >> 11;
        int p = c >> 7, r = c & 127;
        int n = ct * 128 + r;
        int k0 = p * 8;
        bf16x8 o;
#pragma unroll
        for (int j = 0; j < 8; j++)
            o[j] = (__bf16)W2[(size_t)(k0 + j) * 512 + n];
        *(bf16x8*)(w2t + (size_t)g2 * 8) = o;
    }
}

// ---------------------------------------------------------------------------
// MFMA GEMM 1: xb @ wt^T -> h1b bf16[NN,768], skippre f32[NN,64], + fused
// alpha1. 64M x 128N block, 4 waves (32x64 each, 2x2), BK=64. 256 threads.
// (4-wave shape: VGPR ~60, 4480 waves total — round-6 verified sweet spot)
// ---------------------------------------------------------------------------
__global__ __launch_bounds__(256)
void mfma_gemm1_kernel(const __bf16* __restrict__ xb, const __bf16* __restrict__ wt,
                       const float* __restrict__ a_src1, const float* __restrict__ a_dst1,
                       __bf16* __restrict__ h1b, float* __restrict__ skippre,
                       float* __restrict__ asrc, float* __restrict__ adst) {
    __shared__ __bf16 As[4096];    // 8 planes x 64 rows x 8  (8 KB)
    __shared__ __bf16 Bs[8192];    // 8 planes x 128 rows x 8 (16 KB)
    __shared__ float sA[64], sD[64];
    __shared__ float asd[256];
    int b = blockIdx.x;
    int xcd = b & 7, j = b >> 3;          // j 0..139
    int jq = j / 7;                        // 0..19
    int rt = xcd + 8 * jq;                 // 0..159
    int ct = j - 7 * jq;                   // 0..6
    if (rt >= MPAD / 64) return;
    const int bi = rt * 64;
    const int bn = ct * 128;

    const int tid = threadIdx.x;
    const int lane = tid & 63;
    const int w = tid >> 6;                // 0..3
    const int wm = w >> 1, wn = w & 1;
    const int q = lane >> 4, m16 = lane & 15;

    if (tid < 64) { sA[tid] = 0.f; sD[tid] = 0.f; }
    if (ct < 6) {
        if (tid < 128) asd[tid] = a_src1[ct * 128 + tid];
        else           asd[tid] = a_dst1[ct * 128 + (tid - 128)];
    }

    f32x4 acc[2][4] = {};

    for (int ks = 0; ks < KPAD / 64; ks++) {
        const size_t slabA = (size_t)(rt * 32 + ks) * 512;
        const size_t slabB = (size_t)(ct * 32 + ks) * 1024;
#pragma unroll
        for (int i = 0; i < 2; i++) {
            int seg = i * 4 + w;           // 0..7
            GLL(xb + (slabA + seg * 64 + lane) * 8, As + seg * 512);
        }
#pragma unroll
        for (int i = 0; i < 4; i++) {
            int seg = i * 4 + w;           // 0..15
            GLL(wt + (slabB + seg * 64 + lane) * 8, Bs + seg * 512);
        }
        __syncthreads();

#pragma unroll
        for (int kk = 0; kk < 2; kk++) {
            const int pb = kk * 4 + q;
            bf16x8 af[2], bfr[4];
#pragma unroll
            for (int mt = 0; mt < 2; mt++)
                af[mt] = *(const bf16x8*)(As + (pb * 64 + wm * 32 + mt * 16 + m16) * 8);
#pragma unroll
            for (int nt = 0; nt < 4; nt++)
                bfr[nt] = *(const bf16x8*)(Bs + (pb * 128 + wn * 64 + nt * 16 + m16) * 8);
#pragma unroll
            for (int mt = 0; mt < 2; mt++)
#pragma unroll
                for (int nt = 0; nt < 4; nt++)
                    acc[mt][nt] = __builtin_amdgcn_mfma_f32_16x16x32_bf16(af[mt], bfr[nt], acc[mt][nt], 0, 0, 0);
        }
        __syncthreads();
    }

    // epilogue: stores + fused alpha. row=bi+wm*32+mt*16+q*4+r, col=bn+wn*64+nt*16+m16
#pragma unroll
    for (int mt = 0; mt < 2; mt++) {
#pragma unroll
        for (int r = 0; r < 4; r++) {
            int rowl = wm * 32 + mt * 16 + q * 4 + r;
            int row = bi + rowl;
            float ps = 0.f, pd = 0.f;
#pragma unroll
            for (int nt = 0; nt < 4; nt++) {
                int coll = wn * 64 + nt * 16 + m16;
                int col = bn + coll;
                float v = acc[mt][nt][r];
                if (ct < 6) { ps += v * asd[coll]; pd += v * asd[128 + coll]; }
                if (row < NN) {
                    if (col < 768)      h1b[(size_t)row * 768 + col] = (__bf16)v;
                    else if (col < 832) skippre[(size_t)row * 64 + (col - 768)] = v;
                }
            }
            if (ct < 6) {
#pragma unroll
                for (int off = 1; off < 16; off <<= 1) {
                    ps += __shfl_xor(ps, off);
                    pd += __shfl_xor(pd, off);
                }
                if (m16 == 0) { atomicAdd(&sA[rowl], ps); atomicAdd(&sD[rowl], pd); }
            }
        }
    }
    if (ct < 6) {
        __syncthreads();
        if (tid < 64) {
            int row = bi + tid;
            if (row < NN) { asrc[row * 6 + ct] = sA[tid]; adst[row * 6 + ct] = sD[tid]; }
        }
    }
}

// ---------------------------------------------------------------------------
// MFMA GEMM 2: x1gcnb(swizzled)[MPAD,128] @ w2t(swizzled)[512,128]^T -> h2b
// bf16[NN,512], + fused alpha2. 64x128 block, 4 waves (32x64), BK=64, 256 thr.
// ---------------------------------------------------------------------------
__global__ __launch_bounds__(256)
void mfma_gemm2_kernel(const __bf16* __restrict__ A, const __bf16* __restrict__ B,
                       const float* __restrict__ a_src2, const float* __restrict__ a_dst2,
                       __bf16* __restrict__ h2b,
                       float* __restrict__ asrc, float* __restrict__ adst) {
    __shared__ __bf16 As[4096];
    __shared__ __bf16 Bs[8192];
    __shared__ float sA[64], sD[64];
    __shared__ float asd[256];
    const int rt = blockIdx.y, ct = blockIdx.x;
    const int bi = rt * 64, bn = ct * 128;
    const int tid = threadIdx.x, lane = tid & 63, w = tid >> 6;
    const int wm = w >> 1, wn = w & 1;
    const int q = lane >> 4, m16 = lane & 15;

    if (tid < 64) { sA[tid] = 0.f; sD[tid] = 0.f; }
    if (tid < 128) asd[tid] = a_src2[ct * 128 + tid];
    else           asd[tid] = a_dst2[ct * 128 + (tid - 128)];

    f32x4 acc[2][4] = {};

    for (int ks = 0; ks < 2; ks++) {
        const size_t slabA = (size_t)rt * 1024 + ks * 512;
        const size_t slabB = (size_t)ct * 2048 + ks * 1024;
#pragma unroll
        for (int i = 0; i < 2; i++) {
            int seg = i * 4 + w;
            GLL(A + (slabA + seg * 64 + lane) * 8, As + seg * 512);
        }
#pragma unroll
        for (int i = 0; i < 4; i++) {
            int seg = i * 4 + w;
            GLL(B + (slabB + seg * 64 + lane) * 8, Bs + seg * 512);
        }
        __syncthreads();

#pragma unroll
        for (int kk = 0; kk < 2; kk++) {
            const int pb = kk * 4 + q;
            bf16x8 af[2], bfr[4];
#pragma unroll
            for (int mt = 0; mt < 2; mt++)
                af[mt] = *(const bf16x8*)(As + (pb * 64 + wm * 32 + mt * 16 + m16) * 8);
#pragma unroll
            for (int nt = 0; nt < 4; nt++)
                bfr[nt] = *(const bf16x8*)(Bs + (pb * 128 + wn * 64 + nt * 16 + m16) * 8);
#pragma unroll
            for (int mt = 0; mt < 2; mt++)
#pragma unroll
                for (int nt = 0; nt < 4; nt++)
                    acc[mt][nt] = __builtin_amdgcn_mfma_f32_16x16x32_bf16(af[mt], bfr[nt], acc[mt][nt], 0, 0, 0);
        }
        __syncthreads();
    }

#pragma unroll
    for (int mt = 0; mt < 2; mt++) {
#pragma unroll
        for (int r = 0; r < 4; r++) {
            int rowl = wm * 32 + mt * 16 + q * 4 + r;
            int row = bi + rowl;
            float ps = 0.f, pd = 0.f;
#pragma unroll
            for (int nt = 0; nt < 4; nt++) {
                int coll = wn * 64 + nt * 16 + m16;
                float v = acc[mt][nt][r];
                ps += v * asd[coll]; pd += v * asd[128 + coll];
                if (row < NN) h2b[(size_t)row * 512 + bn + coll] = (__bf16)v;
            }
#pragma unroll
            for (int off = 1; off < 16; off <<= 1) {
                ps += __shfl_xor(ps, off);
                pd += __shfl_xor(pd, off);
            }
            if (m16 == 0) { atomicAdd(&sA[rowl], ps); atomicAdd(&sD[rowl], pd); }
        }
    }
    __syncthreads();
    if (tid < 64) {
        int row = bi + tid;
        if (row < NN) { asrc[row * 4 + ct] = sA[tid]; adst[row * 4 + ct] = sD[tid]; }
    }
}

// ---------------------------------------------------------------------------
// Generic fp32-accum tiled GEMM (small GEMMs), templated output type
// ---------------------------------------------------------------------------
template<bool RELU, bool BIAS, typename OUT>
__global__ void gemm_kernel(const float* __restrict__ A, int lda,
                            const float* __restrict__ B, int ldb,
                            OUT* __restrict__ C, int ldc,
                            const float* __restrict__ bias,
                            int M, int N, int K) {
    __shared__ float As[16][65];
    __shared__ float Bs[16][64];
    int bi = blockIdx.y * 64, bj = blockIdx.x * 64;
    int tid = threadIdx.x;
    int tx = tid & 15, ty = tid >> 4;
    float acc[4][4] = {};
    for (int k0 = 0; k0 < K; k0 += 16) {
        {
            int kk = tid & 15, mm = tid >> 4;
#pragma unroll
            for (int it = 0; it < 4; it++) {
                int row = mm + 16 * it;
                int gr = bi + row;
                As[kk][row] = (gr < M) ? A[(size_t)gr * lda + k0 + kk] : 0.f;
            }
        }
        {
            int nn = tid & 63, kk = tid >> 6;
#pragma unroll
            for (int it = 0; it < 4; it++)
                Bs[kk + 4 * it][nn] = B[(size_t)(k0 + kk + 4 * it) * ldb + bj + nn];
        }
        __syncthreads();
#pragma unroll
        for (int kk = 0; kk < 16; kk++) {
            float av[4], bv[4];
#pragma unroll
            for (int a = 0; a < 4; a++) av[a] = As[kk][ty * 4 + a];
#pragma unroll
            for (int b = 0; b < 4; b++) bv[b] = Bs[kk][tx * 4 + b];
#pragma unroll
            for (int a = 0; a < 4; a++)
#pragma unroll
                for (int b = 0; b < 4; b++)
                    acc[a][b] += av[a] * bv[b];
        }
        __syncthreads();
    }
#pragma unroll
    for (int a = 0; a < 4; a++) {
        int gr = bi + ty * 4 + a;
        if (gr >= M) continue;
#pragma unroll
        for (int b = 0; b < 4; b++) {
            int gc = bj + tx * 4 + b;
            float v = acc[a][b];
            if (BIAS) v += bias[gc];
            if (RELU) v = fmaxf(v, 0.f);
            C[(size_t)gr * ldc + gc] = (OUT)v;
        }
    }
}

// ---------------------------------------------------------------------------
// Fused segment-softmax + aggregation + head-mean + bias + LN + ReLU.
// Phase 2 processes edges in pairs for 2x memory-level parallelism.
// ---------------------------------------------------------------------------
template<int H>
__global__ void gat_agg_kernel(const __bf16* __restrict__ hb,
                               const float* __restrict__ asrc,
                               const float* __restrict__ adst,
                               const int* __restrict__ rowstart,
                               const int* __restrict__ csr_src,
                               const float* __restrict__ bias,
                               const float* __restrict__ gamma,
                               const float* __restrict__ beta,
                               float* __restrict__ out) {
    constexpr int CH = H * 128;
    int n = blockIdx.x;
    int t = threadIdx.x;
    int w = t >> 6, l = t & 63;
    __shared__ float invden[H];
    __shared__ float denw[4][H];
    __shared__ float sm[4 * CH];
    __shared__ float red[8];

    int s0 = rowstart[n], s1 = rowstart[n + 1];
    float adst_n = (l < H) ? adst[n * H + l] : 0.f;

    // phase 1: denominators
    float dloc = 0.f;
    for (int s = s0 + w; s < s1; s += 4) {
        int src = csr_src[s];
        if (l < H) {
            float al = asrc[src * H + l] + adst_n;
            al = al >= 0.f ? al : 0.2f * al;
            dloc += __expf(al);
        }
    }
    if (l < H) denw[w][l] = dloc;
    __syncthreads();
    if (t < H) invden[t] = 1.f / (denw[0][t] + denw[1][t] + denw[2][t] + denw[3][t]);
    __syncthreads();

    // phase 2: weighted feature accumulation, 2-edge pipelined, bf16x8 loads
    constexpr int NA = (H == 6) ? 12 : 8;
    float acc[NA] = {};
    int s = s0 + w;
    for (; s + 4 < s1; s += 8) {
        int src0 = csr_src[s], src1 = csr_src[s + 4];
        float ev0 = 0.f, ev1 = 0.f;
        if (l < H) {
            float a0 = asrc[src0 * H + l] + adst_n;
            a0 = a0 >= 0.f ? a0 : 0.2f * a0;
            float a1 = asrc[src1 * H + l] + adst_n;
            a1 = a1 >= 0.f ? a1 : 0.2f * a1;
            ev0 = __expf(a0); ev1 = __expf(a1);
        }
        const __bf16* hp0 = hb + (size_t)src0 * CH;
        const __bf16* hp1 = hb + (size_t)src1 * CH;
        bf16x8 g00 = *(const bf16x8*)(hp0 + l * 8);
        bf16x8 g10 = *(const bf16x8*)(hp1 + l * 8);
        float w00 = __shfl(ev0, l >> 4), w10 = __shfl(ev1, l >> 4);
#pragma unroll
        for (int jj = 0; jj < 8; jj++)
            acc[jj] += (float)g00[jj] * w00 + (float)g10[jj] * w10;
        if (H == 6) {
            bf16x4 g01 = *(const bf16x4*)(hp0 + 512 + l * 4);
            bf16x4 g11 = *(const bf16x4*)(hp1 + 512 + l * 4);
            float w01 = __shfl(ev0, 4 + (l >> 5)), w11 = __shfl(ev1, 4 + (l >> 5));
#pragma unroll
            for (int jj = 0; jj < 4; jj++)
                acc[8 + jj] += (float)g01[jj] * w01 + (float)g11[jj] * w11;
        }
    }
    if (s < s1) {
        int src = csr_src[s];
        float ev = 0.f;
        if (l < H) {
            float al = asrc[src * H + l] + adst_n;
            al = al >= 0.f ? al : 0.2f * al;
            ev = __expf(al);
        }
        const __bf16* hp = hb + (size_t)src * CH;
        float wgt = __shfl(ev, l >> 4);
        bf16x8 hv = *(const bf16x8*)(hp + l * 8);
#pragma unroll
        for (int jj = 0; jj < 8; jj++) acc[jj] += (float)hv[jj] * wgt;
        if (H == 6) {
            float wg1 = __shfl(ev, 4 + (l >> 5));
            bf16x4 hv1 = *(const bf16x4*)(hp + 512 + l * 4);
#pragma unroll
            for (int jj = 0; jj < 4; jj++) acc[8 + jj] += (float)hv1[jj] * wg1;
        }
    }
    *(f32x4*)(sm + w * CH + l * 8)     = *(f32x4*)(acc);
    *(f32x4*)(sm + w * CH + l * 8 + 4) = *(f32x4*)(acc + 4);
    if (H == 6)
        *(f32x4*)(sm + w * CH + 512 + l * 4) = *(f32x4*)(acc + 8);
    __syncthreads();

    float v = 0.f;
    if (t < 128) {
#pragma unroll
        for (int hh = 0; hh < H; hh++) {
            float hsum = 0.f;
#pragma unroll
            for (int ww = 0; ww < 4; ww++) hsum += sm[ww * CH + hh * 128 + t];
            v += hsum * invden[hh];
        }
        v = v * (1.f / H) + bias[t];
    }
    float sv = (t < 128) ? v : 0.f;
    float sq = (t < 128) ? v * v : 0.f;
#pragma unroll
    for (int off = 32; off; off >>= 1) {
        sv += __shfl_down(sv, off);
        sq += __shfl_down(sq, off);
    }
    if ((t & 63) == 0) { red[w * 2] = sv; red[w * 2 + 1] = sq; }
    __syncthreads();
    float tot = red[0] + red[2] + red[4] + red[6];
    float tsq = red[1] + red[3] + red[5] + red[7];
    float mu = tot * (1.f / 128.f);
    float var = tsq * (1.f / 128.f) - mu * mu;
    float r = rsqrtf(var + 1e-5f);
    if (t < 128) {
        float o = (v - mu) * r * gamma[t] + beta[t];
        out[(size_t)n * 128 + t] = fmaxf(o, 0.f);
    }
}

// per-node GCN aggregation from bf16 y; fp32 cat slice + optional swizzled bf16
__global__ void gcn_agg_kernel(const __bf16* __restrict__ y, int C,
                               const float* __restrict__ dinv,
                               const int* __restrict__ rowstart,
                               const int* __restrict__ csr_src,
                               const float* __restrict__ bias,
                               float* __restrict__ out, int ldo, int coloff,
                               __bf16* __restrict__ bout) {
    int n = blockIdx.x;
    int t = threadIdx.x;  // blockDim == C
    float acc = 0.f;
    int s0 = rowstart[n], s1 = rowstart[n + 1];
    for (int s = s0; s < s1; s++) {
        int src = csr_src[s];
        acc += (float)y[(size_t)src * C + t] * dinv[src];
    }
    float v = fmaxf(acc * dinv[n] + bias[t], 0.f);
    out[(size_t)n * ldo + coloff + t] = v;
    if (bout) {
        // swizzled layout for mfma_gemm2: idx = ((rt*16 + p)*64 + r)*8 + off
        int rt = n >> 6, r = n & 63, p = t >> 3, off = t & 7;
        bout[((size_t)(rt * 16 + p) * 64 + r) * 8 + off] = (__bf16)v;
    }
}

// final = LN(fused + relu(skippre + b_skip)); then 64->32->16->5 MLP.
__global__ void final_kernel(const float* __restrict__ fused,
                             const float* __restrict__ skippre,
                             const float* __restrict__ b_skip,
                             const float* __restrict__ g3, const float* __restrict__ be3,
                             const float* __restrict__ Wc1, const float* __restrict__ bc1,
                             const float* __restrict__ Wc2, const float* __restrict__ bc2,
                             const float* __restrict__ Wc3, const float* __restrict__ bc3,
                             float* __restrict__ out) {
    int n = blockIdx.x;
    int l = threadIdx.x;  // 64
    __shared__ float f[64], h1s[32], h2s[16];
    float sk = fmaxf(skippre[(size_t)n * 64 + l] + b_skip[l], 0.f);
    float v = fused[(size_t)n * 64 + l] + sk;
    float sv = v, sq = v * v;
#pragma unroll
    for (int off = 32; off; off >>= 1) {
        sv += __shfl_xor(sv, off);
        sq += __shfl_xor(sq, off);
    }
    float mu = sv * (1.f / 64.f);
    float var = sq * (1.f / 64.f) - mu * mu;
    float r = rsqrtf(var + 1e-5f);
    f[l] = (v - mu) * r * g3[l] + be3[l];
    __syncthreads();
    if (l < 32) {
        float a = bc1[l];
        for (int i = 0; i < 64; i++) a += f[i] * Wc1[i * 32 + l];
        h1s[l] = fmaxf(a, 0.f);
    }
    __syncthreads();
    if (l < 16) {
        float a = bc2[l];
        for (int i = 0; i < 32; i++) a += h1s[i] * Wc2[i * 16 + l];
        h2s[l] = fmaxf(a, 0.f);
    }
    __syncthreads();
    if (l < 5) {
        float a = bc3[l];
        for (int i = 0; i < 16; i++) a += h2s[i] * Wc3[i * 5 + l];
        out[(size_t)n * 5 + l] = a;
    }
}

// ---------------------------------------------------------------------------
extern "C" void kernel_launch(void* const* d_in, const int* in_sizes, int n_in,
                              void* d_out, int out_size, void* d_ws, size_t ws_size,
                              hipStream_t stream) {
    const float* x      = (const float*)d_in[0];
    const int*   ei     = (const int*)d_in[1];
    const float* W_gat1 = (const float*)d_in[2];
    const float* a_src1 = (const float*)d_in[3];
    const float* a_dst1 = (const float*)d_in[4];
    const float* b_gat1 = (const float*)d_in[5];
    const float* W_gcn1 = (const float*)d_in[6];
    const float* b_gcn1 = (const float*)d_in[7];
    const float* W_gat2 = (const float*)d_in[8];
    const float* a_src2 = (const float*)d_in[9];
    const float* a_dst2 = (const float*)d_in[10];
    const float* b_gat2 = (const float*)d_in[11];
    const float* W_gcn2 = (const float*)d_in[12];
    const float* b_gcn2 = (const float*)d_in[13];
    const float* W_skip = (const float*)d_in[14];
    const float* b_skip = (const float*)d_in[15];
    const float* W_fuse = (const float*)d_in[16];
    const float* b_fuse = (const float*)d_in[17];
    const float* W_c1   = (const float*)d_in[18];
    const float* b_c1   = (const float*)d_in[19];
    const float* W_c2   = (const float*)d_in[20];
    const float* b_c2   = (const float*)d_in[21];
    const float* W_c3   = (const float*)d_in[22];
    const float* b_c3   = (const float*)d_in[23];
    const float* g1     = (const float*)d_in[24];
    const float* be1    = (const float*)d_in[25];
    const float* g2     = (const float*)d_in[26];
    const float* be2    = (const float*)d_in[27];
    const float* g3     = (const float*)d_in[28];
    const float* be3    = (const float*)d_in[29];
    float* out = (float*)d_out;

    // workspace arena
    char* p = (char*)d_ws;
    auto alloc = [&](size_t bytes) {
        char* r = p; p += (bytes + 255) & ~(size_t)255; return r;
    };
    __bf16* xb      = (__bf16*)alloc((size_t)MPAD * KPAD * 2);   // 41.4 MB (swizzled)
    __bf16* wt      = (__bf16*)alloc((size_t)NPAD * KPAD * 2);   // 3.7 MB  (swizzled)
    __bf16* w2t     = (__bf16*)alloc((size_t)512 * 128 * 2);     // swizzled
    __bf16* h1b     = (__bf16*)alloc((size_t)NN * 768 * 2);      // 15.4 MB
    __bf16* h2b     = (__bf16*)alloc((size_t)NN * 512 * 2);      // 10.2 MB
    __bf16* ybufb   = (__bf16*)alloc((size_t)NN * 128 * 2);      // y1 reused y2
    __bf16* x1gcnb  = (__bf16*)alloc((size_t)MPAD * 128 * 2);    // swizzled, MFMA2 A
    float* asrc     = (float*)alloc((size_t)NN * 6 * 4);
    float* adst     = (float*)alloc((size_t)NN * 6 * 4);
    int*   deg      = (int*)  alloc((size_t)2 * NN * 4);         // deg | cursor
    int*   cursor   = deg + NN;
    float* dinv     = (float*)alloc((size_t)NN * 4);
    int*   rowst    = (int*)  alloc((size_t)(NN + 1) * 4);
    int*   csrc     = (int*)  alloc((size_t)ET * 4);
    float* x1gat    = (float*)alloc((size_t)NN * 128 * 4);
    float* cat      = (float*)alloc((size_t)NN * 192 * 4);
    float* x2gat    = (float*)alloc((size_t)NN * 128 * 4);
    float* skippre  = (float*)alloc((size_t)NN * 64 * 4);
    float* fusedb   = (float*)alloc((size_t)NN * 64 * 4);

    hipMemsetAsync(deg, 0, (size_t)2 * NN * 4, stream);
    hipMemsetAsync(x1gcnb, 0, (size_t)MPAD * 128 * 2, stream);  // pad rows interleaved

    const int EB = (ET + 255) / 256;
    const int MB = (NN + 63) / 64;

    // bf16 conversions (swizzled layouts)
    conv_x_kernel<<<(MPAD / 4) * (KPAD / 512), 256, 0, stream>>>(x, xb);
    conv_w_kernel<<<(NW1 + 512 * 128 / 8 + 255) / 256, 256, 0, stream>>>(
        W_gat1, W_skip, W_gat2, wt, w2t);

    // CSR by dst
    count_kernel  <<<EB, 256, 0, stream>>>(ei, deg);
    scan_kernel   <<<1, 256, 0, stream>>>(deg, rowst, dinv);
    scatter_kernel<<<EB, 256, 0, stream>>>(ei, rowst, cursor, csrc);

    // h1 (bf16) + skippre + fused alpha1, XCD-swizzled 64x128 BK=64, 4 waves
    mfma_gemm1_kernel<<<1120, 256, 0, stream>>>(xb, wt, a_src1, a_dst1,
                                                h1b, skippre, asrc, adst);

    // ---- GAT layer 1 (H=6) ----
    gat_agg_kernel<6><<<NN, 256, 0, stream>>>(h1b, asrc, adst, rowst, csrc,
                                              b_gat1, g1, be1, x1gat);
    // ---- GCN layer 1 (fp32 GEMM -> bf16 y) ----
    gemm_kernel<false, false, __bf16><<<dim3(2, MB), 256, 0, stream>>>(
        x1gat, 128, W_gcn1, 128, ybufb, 128, nullptr, NN, 128, 128);
    gcn_agg_kernel<<<NN, 128, 0, stream>>>(ybufb, 128, dinv, rowst, csrc,
                                           b_gcn1, cat, 192, 0, x1gcnb);
    // ---- GAT layer 2 (H=4): h2 + fused alpha2 (bf16 MFMA, 4 waves) ----
    mfma_gemm2_kernel<<<dim3(4, MPAD / 64), 256, 0, stream>>>(
        x1gcnb, w2t, a_src2, a_dst2, h2b, asrc, adst);
    gat_agg_kernel<4><<<NN, 256, 0, stream>>>(h2b, asrc, adst, rowst, csrc,
                                              b_gat2, g2, be2, x2gat);
    // ---- GCN layer 2 (fp32 GEMM -> bf16 y) -> cat[:, 128:192] ----
    gemm_kernel<false, false, __bf16><<<dim3(1, MB), 256, 0, stream>>>(
        x2gat, 128, W_gcn2, 64, ybufb, 64, nullptr, NN, 64, 128);
    gcn_agg_kernel<<<NN, 64, 0, stream>>>(ybufb, 64, dinv, rowst, csrc,
                                          b_gcn2, cat, 192, 128, nullptr);
    // ---- fuse (fp32) + final ----
    gemm_kernel<true, true, float><<<dim3(1, MB), 256, 0, stream>>>(
        cat, 192, W_fuse, 64, fusedb, 64, b_fuse, NN, 64, 192);
    final_kernel<<<NN, 64, 0, stream>>>(fusedb, skippre, b_skip, g3, be3,
                                        W_c1, b_c1, W_c2, b_c2, W_c3, b_c3, out);
}

// Round 9
// 499.505 us; speedup vs baseline: 2.9971x; 1.0093x over previous
//
#include <hip/hip_runtime.h>
#include <cstdint>
#include <cstddef>

#define NN 10000
#define NE 160000
#define ET (NE + NN)          // edges + self loops
#define FIN 2000
#define MPAD 10112            // 158 * 64
#define KPAD 2048
#define NPAD 896              // 7 * 128 (768 gat1 cols + 64 skip + 64 pad)

typedef __bf16 bf16x8 __attribute__((ext_vector_type(8)));
typedef __bf16 bf16x4 __attribute__((ext_vector_type(4)));
typedef float  f32x4  __attribute__((ext_vector_type(4)));

#define GLL(src, dst) __builtin_amdgcn_global_load_lds( \
    (const __attribute__((address_space(1))) void*)(src), \
    (__attribute__((address_space(3))) void*)(dst), 16, 0, 0)

// ---------------------------------------------------------------------------
// CSR build
// ---------------------------------------------------------------------------
__device__ __forceinline__ void edge_sd(const int* ei, int e, int& s, int& d) {
    if (e < NE) { s = ei[e]; d = ei[NE + e]; }
    else        { s = e - NE; d = e - NE; }
}

__global__ void count_kernel(const int* ei, int* deg) {
    int e = blockIdx.x * blockDim.x + threadIdx.x;
    if (e >= ET) return;
    int s, d; edge_sd(ei, e, s, d);
    atomicAdd(&deg[d], 1);
}

// exclusive scan over deg -> rowstart[0..NN]; also dinv = deg^-1/2
__global__ void scan_kernel(const int* deg, int* rowstart, float* dinv) {
    __shared__ int partial[256];
    const int T = 256;
    int chunk = (NN + T - 1) / T;
    int t = threadIdx.x;
    int begin = t * chunk;
    int end = begin + chunk; if (end > NN) end = NN;
    int s = 0;
    for (int i = begin; i < end && i >= begin; i++) s += deg[i];
    partial[t] = s;
    __syncthreads();
    if (t == 0) {
        int run = 0;
        for (int i = 0; i < T; i++) { int v = partial[i]; partial[i] = run; run += v; }
    }
    __syncthreads();
    int run = partial[t];
    for (int i = begin; i < end && i >= begin; i++) {
        rowstart[i] = run; run += deg[i];
        int dg = deg[i];
        dinv[i] = dg > 0 ? rsqrtf((float)dg) : 0.f;
    }
    if (end == NN && begin <= NN) rowstart[NN] = run;
}

__global__ void scatter_kernel(const int* ei, const int* rowstart, int* cursor,
                               int* csr_src) {
    int e = blockIdx.x * blockDim.x + threadIdx.x;
    if (e >= ET) return;
    int s, d; edge_sd(ei, e, s, d);
    int pos = atomicAdd(&cursor[d], 1);
    csr_src[rowstart[d] + pos] = s;
}

// ---------------------------------------------------------------------------
// Merged swizzled bf16 conversion.
// xb chunk c = ((rt*32 + ks)*8 + p)*64 + r holds x[rt*64+r][ks*64+p*8 ..+8)
// Blocks 0..5055: one (rt,ks) slab via LDS (coalesced read AND write).
// Blocks 5056.. : wt / w2t conversion (flat, per-thread).
// wt chunk: ((ct*32 + ks)*8 + p)*128 + r ; w2t chunk: (ct*16 + p)*128 + r
// ---------------------------------------------------------------------------
#define NBX (158 * 32)
#define NW1 (NPAD * KPAD / 8)
__global__ void conv_kernel(const float* __restrict__ x, __bf16* __restrict__ xb,
                            const float* __restrict__ Wg, const float* __restrict__ Ws,
                            const float* __restrict__ W2,
                            __bf16* __restrict__ wt, __bf16* __restrict__ w2t) {
    __shared__ __bf16 slab[4096];   // 8 planes x 64 rows x 8 = output chunk layout
    int bid = blockIdx.x;
    int tid = threadIdx.x;
    if (bid < NBX) {
        int rt = bid >> 5, ks = bid & 31;
        int r = tid >> 2;                 // 0..63
        int row = rt * 64 + r;
        int c0 = (tid & 3) * 16;          // 0,16,32,48
        int kbase = ks * 64;
#pragma unroll
        for (int j = 0; j < 4; j++) {
            int kl = c0 + j * 4;          // local k, mult of 4
            int k = kbase + kl;
            bf16x4 o;
            if (row < NN && k + 3 < FIN) {
                float4 v = *(const float4*)(x + (size_t)row * FIN + k);
                o[0] = (__bf16)v.x; o[1] = (__bf16)v.y;
                o[2] = (__bf16)v.z; o[3] = (__bf16)v.w;
            } else {
                o[0] = o[1] = o[2] = o[3] = (__bf16)0.f;
            }
            int p = kl >> 3, off = kl & 7;
            *(bf16x4*)(slab + (p * 64 + r) * 8 + off) = o;
        }
        __syncthreads();
        size_t base = (size_t)(rt * 32 + ks) * 512;   // chunk index
#pragma unroll
        for (int i = 0; i < 2; i++) {
            int c = i * 256 + tid;
            *(bf16x8*)(xb + (base + c) * 8) = *(const bf16x8*)(slab + c * 8);
        }
    } else {
        int g = (bid - NBX) * 256 + tid;
        if (g < NW1) {
            int r = g & 127, p = (g >> 7) & 7, ks = (g >> 10) & 31, ct = g >> 15;
            int n = ct * 128 + r;
            int k0 = ks * 64 + p * 8;
            bf16x8 o;
#pragma unroll
            for (int j = 0; j < 8; j++) {
                int k = k0 + j;
                float v = 0.f;
                if (k < FIN) {
                    if (n < 768)      v = Wg[(size_t)k * 768 + n];
                    else if (n < 832) v = Ws[(size_t)k * 64 + (n - 768)];
                }
                o[j] = (__bf16)v;
            }
            *(bf16x8*)(wt + (size_t)g * 8) = o;
        } else if (g < NW1 + 512 * 128 / 8) {
            int g2 = g - NW1;
            int c = g2 & 2047;
            int ct = g2 >> 11;
            int p = c >> 7, r = c & 127;
            int n = ct * 128 + r;
            int k0 = p * 8;
            bf16x8 o;
#pragma unroll
            for (int j = 0; j < 8; j++)
                o[j] = (__bf16)W2[(size_t)(k0 + j) * 512 + n];
            *(bf16x8*)(w2t + (size_t)g2 * 8) = o;
        }
    }
}

// ---------------------------------------------------------------------------
// MFMA GEMM 1: xb @ wt^T -> h1b bf16[NN,768], skippre f32[NN,64], + fused
// alpha1. 64M x 128N block, 4 waves (32x64 each, 2x2), BK=64. 256 threads.
// ---------------------------------------------------------------------------
__global__ __launch_bounds__(256)
void mfma_gemm1_kernel(const __bf16* __restrict__ xb, const __bf16* __restrict__ wt,
                       const float* __restrict__ a_src1, const float* __restrict__ a_dst1,
                       __bf16* __restrict__ h1b, float* __restrict__ skippre,
                       float* __restrict__ asrc, float* __restrict__ adst) {
    __shared__ __bf16 As[4096];    // 8 planes x 64 rows x 8  (8 KB)
    __shared__ __bf16 Bs[8192];    // 8 planes x 128 rows x 8 (16 KB)
    __shared__ float sA[64], sD[64];
    __shared__ float asd[256];
    int b = blockIdx.x;
    int xcd = b & 7, j = b >> 3;
    int jq = j / 7;
    int rt = xcd + 8 * jq;
    int ct = j - 7 * jq;
    if (rt >= MPAD / 64) return;
    const int bi = rt * 64;
    const int bn = ct * 128;

    const int tid = threadIdx.x;
    const int lane = tid & 63;
    const int w = tid >> 6;
    const int wm = w >> 1, wn = w & 1;
    const int q = lane >> 4, m16 = lane & 15;

    if (tid < 64) { sA[tid] = 0.f; sD[tid] = 0.f; }
    if (ct < 6) {
        if (tid < 128) asd[tid] = a_src1[ct * 128 + tid];
        else           asd[tid] = a_dst1[ct * 128 + (tid - 128)];
    }

    f32x4 acc[2][4] = {};

    for (int ks = 0; ks < KPAD / 64; ks++) {
        const size_t slabA = (size_t)(rt * 32 + ks) * 512;
        const size_t slabB = (size_t)(ct * 32 + ks) * 1024;
#pragma unroll
        for (int i = 0; i < 2; i++) {
            int seg = i * 4 + w;
            GLL(xb + (slabA + seg * 64 + lane) * 8, As + seg * 512);
        }
#pragma unroll
        for (int i = 0; i < 4; i++) {
            int seg = i * 4 + w;
            GLL(wt + (slabB + seg * 64 + lane) * 8, Bs + seg * 512);
        }
        __syncthreads();

#pragma unroll
        for (int kk = 0; kk < 2; kk++) {
            const int pb = kk * 4 + q;
            bf16x8 af[2], bfr[4];
#pragma unroll
            for (int mt = 0; mt < 2; mt++)
                af[mt] = *(const bf16x8*)(As + (pb * 64 + wm * 32 + mt * 16 + m16) * 8);
#pragma unroll
            for (int nt = 0; nt < 4; nt++)
                bfr[nt] = *(const bf16x8*)(Bs + (pb * 128 + wn * 64 + nt * 16 + m16) * 8);
#pragma unroll
            for (int mt = 0; mt < 2; mt++)
#pragma unroll
                for (int nt = 0; nt < 4; nt++)
                    acc[mt][nt] = __builtin_amdgcn_mfma_f32_16x16x32_bf16(af[mt], bfr[nt], acc[mt][nt], 0, 0, 0);
        }
        __syncthreads();
    }

#pragma unroll
    for (int mt = 0; mt < 2; mt++) {
#pragma unroll
        for (int r = 0; r < 4; r++) {
            int rowl = wm * 32 + mt * 16 + q * 4 + r;
            int row = bi + rowl;
            float ps = 0.f, pd = 0.f;
#pragma unroll
            for (int nt = 0; nt < 4; nt++) {
                int coll = wn * 64 + nt * 16 + m16;
                int col = bn + coll;
                float v = acc[mt][nt][r];
                if (ct < 6) { ps += v * asd[coll]; pd += v * asd[128 + coll]; }
                if (row < NN) {
                    if (col < 768)      h1b[(size_t)row * 768 + col] = (__bf16)v;
                    else if (col < 832) skippre[(size_t)row * 64 + (col - 768)] = v;
                }
            }
            if (ct < 6) {
#pragma unroll
                for (int off = 1; off < 16; off <<= 1) {
                    ps += __shfl_xor(ps, off);
                    pd += __shfl_xor(pd, off);
                }
                if (m16 == 0) { atomicAdd(&sA[rowl], ps); atomicAdd(&sD[rowl], pd); }
            }
        }
    }
    if (ct < 6) {
        __syncthreads();
        if (tid < 64) {
            int row = bi + tid;
            if (row < NN) { asrc[row * 6 + ct] = sA[tid]; adst[row * 6 + ct] = sD[tid]; }
        }
    }
}

// ---------------------------------------------------------------------------
// MFMA GEMM 2: x1gcnb(swizzled)[MPAD,128] @ w2t(swizzled)[512,128]^T -> h2b
// bf16[NN,512], + fused alpha2. 64x128 block, 4 waves (32x64), BK=64, 256 thr.
// ---------------------------------------------------------------------------
__global__ __launch_bounds__(256)
void mfma_gemm2_kernel(const __bf16* __restrict__ A, const __bf16* __restrict__ B,
                       const float* __restrict__ a_src2, const float* __restrict__ a_dst2,
                       __bf16* __restrict__ h2b,
                       float* __restrict__ asrc, float* __restrict__ adst) {
    __shared__ __bf16 As[4096];
    __shared__ __bf16 Bs[8192];
    __shared__ float sA[64], sD[64];
    __shared__ float asd[256];
    const int rt = blockIdx.y, ct = blockIdx.x;
    const int bi = rt * 64, bn = ct * 128;
    const int tid = threadIdx.x, lane = tid & 63, w = tid >> 6;
    const int wm = w >> 1, wn = w & 1;
    const int q = lane >> 4, m16 = lane & 15;

    if (tid < 64) { sA[tid] = 0.f; sD[tid] = 0.f; }
    if (tid < 128) asd[tid] = a_src2[ct * 128 + tid];
    else           asd[tid] = a_dst2[ct * 128 + (tid - 128)];

    f32x4 acc[2][4] = {};

    for (int ks = 0; ks < 2; ks++) {
        const size_t slabA = (size_t)rt * 1024 + ks * 512;
        const size_t slabB = (size_t)ct * 2048 + ks * 1024;
#pragma unroll
        for (int i = 0; i < 2; i++) {
            int seg = i * 4 + w;
            GLL(A + (slabA + seg * 64 + lane) * 8, As + seg * 512);
        }
#pragma unroll
        for (int i = 0; i < 4; i++) {
            int seg = i * 4 + w;
            GLL(B + (slabB + seg * 64 + lane) * 8, Bs + seg * 512);
        }
        __syncthreads();

#pragma unroll
        for (int kk = 0; kk < 2; kk++) {
            const int pb = kk * 4 + q;
            bf16x8 af[2], bfr[4];
#pragma unroll
            for (int mt = 0; mt < 2; mt++)
                af[mt] = *(const bf16x8*)(As + (pb * 64 + wm * 32 + mt * 16 + m16) * 8);
#pragma unroll
            for (int nt = 0; nt < 4; nt++)
                bfr[nt] = *(const bf16x8*)(Bs + (pb * 128 + wn * 64 + nt * 16 + m16) * 8);
#pragma unroll
            for (int mt = 0; mt < 2; mt++)
#pragma unroll
                for (int nt = 0; nt < 4; nt++)
                    acc[mt][nt] = __builtin_amdgcn_mfma_f32_16x16x32_bf16(af[mt], bfr[nt], acc[mt][nt], 0, 0, 0);
        }
        __syncthreads();
    }

#pragma unroll
    for (int mt = 0; mt < 2; mt++) {
#pragma unroll
        for (int r = 0; r < 4; r++) {
            int rowl = wm * 32 + mt * 16 + q * 4 + r;
            int row = bi + rowl;
            float ps = 0.f, pd = 0.f;
#pragma unroll
            for (int nt = 0; nt < 4; nt++) {
                int coll = wn * 64 + nt * 16 + m16;
                float v = acc[mt][nt][r];
                ps += v * asd[coll]; pd += v * asd[128 + coll];
                if (row < NN) h2b[(size_t)row * 512 + bn + coll] = (__bf16)v;
            }
#pragma unroll
            for (int off = 1; off < 16; off <<= 1) {
                ps += __shfl_xor(ps, off);
                pd += __shfl_xor(pd, off);
            }
            if (m16 == 0) { atomicAdd(&sA[rowl], ps); atomicAdd(&sD[rowl], pd); }
        }
    }
    __syncthreads();
    if (tid < 64) {
        int row = bi + tid;
        if (row < NN) { asrc[row * 4 + ct] = sA[tid]; adst[row * 4 + ct] = sD[tid]; }
    }
}

// ---------------------------------------------------------------------------
// Generic fp32-accum tiled GEMM (small GEMMs), templated output type
// ---------------------------------------------------------------------------
template<bool RELU, bool BIAS, typename OUT>
__global__ void gemm_kernel(const float* __restrict__ A, int lda,
                            const float* __restrict__ B, int ldb,
                            OUT* __restrict__ C, int ldc,
                            const float* __restrict__ bias,
                            int M, int N, int K) {
    __shared__ float As[16][65];
    __shared__ float Bs[16][64];
    int bi = blockIdx.y * 64, bj = blockIdx.x * 64;
    int tid = threadIdx.x;
    int tx = tid & 15, ty = tid >> 4;
    float acc[4][4] = {};
    for (int k0 = 0; k0 < K; k0 += 16) {
        {
            int kk = tid & 15, mm = tid >> 4;
#pragma unroll
            for (int it = 0; it < 4; it++) {
                int row = mm + 16 * it;
                int gr = bi + row;
                As[kk][row] = (gr < M) ? A[(size_t)gr * lda + k0 + kk] : 0.f;
            }
        }
        {
            int nn = tid & 63, kk = tid >> 6;
#pragma unroll
            for (int it = 0; it < 4; it++)
                Bs[kk + 4 * it][nn] = B[(size_t)(k0 + kk + 4 * it) * ldb + bj + nn];
        }
        __syncthreads();
#pragma unroll
        for (int kk = 0; kk < 16; kk++) {
            float av[4], bv[4];
#pragma unroll
            for (int a = 0; a < 4; a++) av[a] = As[kk][ty * 4 + a];
#pragma unroll
            for (int b = 0; b < 4; b++) bv[b] = Bs[kk][tx * 4 + b];
#pragma unroll
            for (int a = 0; a < 4; a++)
#pragma unroll
                for (int b = 0; b < 4; b++)
                    acc[a][b] += av[a] * bv[b];
        }
        __syncthreads();
    }
#pragma unroll
    for (int a = 0; a < 4; a++) {
        int gr = bi + ty * 4 + a;
        if (gr >= M) continue;
#pragma unroll
        for (int b = 0; b < 4; b++) {
            int gc = bj + tx * 4 + b;
            float v = acc[a][b];
            if (BIAS) v += bias[gc];
            if (RELU) v = fmaxf(v, 0.f);
            C[(size_t)gr * ldc + gc] = (OUT)v;
        }
    }
}

// ---------------------------------------------------------------------------
// Fused segment-softmax + aggregation + head-mean + bias + LN + ReLU.
// Phase 1 caches src ids + exp values in LDS (CAP edges); phase 2's critical
// path is then LDS-read -> h gather only. Fallback recompute for deg > CAP.
// ---------------------------------------------------------------------------
template<int H>
__global__ void gat_agg_kernel(const __bf16* __restrict__ hb,
                               const float* __restrict__ asrc,
                               const float* __restrict__ adst,
                               const int* __restrict__ rowstart,
                               const int* __restrict__ csr_src,
                               const float* __restrict__ bias,
                               const float* __restrict__ gamma,
                               const float* __restrict__ beta,
                               float* __restrict__ out) {
    constexpr int CH = H * 128;
    constexpr int CAP = 128;
    int n = blockIdx.x;
    int t = threadIdx.x;
    int w = t >> 6, l = t & 63;
    __shared__ float invden[H];
    __shared__ float denw[4][H];
    __shared__ int   srcs[CAP];
    __shared__ float evs[CAP * H];
    __shared__ float sm[4 * CH];
    __shared__ float red[8];

    int s0 = rowstart[n];
    int deg = rowstart[n + 1] - s0;
    float adst_n = (l < H) ? adst[n * H + l] : 0.f;

    // phase 1: denominators + cache src/ev
    float dloc = 0.f;
    for (int idx = w; idx < deg; idx += 4) {
        int src = csr_src[s0 + idx];
        if (idx < CAP && l == 0) srcs[idx] = src;
        if (l < H) {
            float al = asrc[src * H + l] + adst_n;
            al = al >= 0.f ? al : 0.2f * al;
            float ev = __expf(al);
            dloc += ev;
            if (idx < CAP) evs[idx * H + l] = ev;
        }
    }
    if (l < H) denw[w][l] = dloc;
    __syncthreads();
    if (t < H) invden[t] = 1.f / (denw[0][t] + denw[1][t] + denw[2][t] + denw[3][t]);
    __syncthreads();

    // phase 2: weighted feature accumulation from cached LDS, 2-edge pipelined
    constexpr int NA = (H == 6) ? 12 : 8;
    float acc[NA] = {};
    const int h0 = l >> 4;
    const int h1i = 4 + (l >> 5);
    int degc = deg < CAP ? deg : CAP;
    int idx = w;
    for (; idx + 4 < degc; idx += 8) {
        int src0 = srcs[idx], src1 = srcs[idx + 4];
        float w00 = evs[idx * H + h0];
        float w10 = evs[(idx + 4) * H + h0];
        const __bf16* hp0 = hb + (size_t)src0 * CH;
        const __bf16* hp1 = hb + (size_t)src1 * CH;
        bf16x8 g00 = *(const bf16x8*)(hp0 + l * 8);
        bf16x8 g10 = *(const bf16x8*)(hp1 + l * 8);
#pragma unroll
        for (int jj = 0; jj < 8; jj++)
            acc[jj] += (float)g00[jj] * w00 + (float)g10[jj] * w10;
        if (H == 6) {
            float w01 = evs[idx * H + h1i];
            float w11 = evs[(idx + 4) * H + h1i];
            bf16x4 g01 = *(const bf16x4*)(hp0 + 512 + l * 4);
            bf16x4 g11 = *(const bf16x4*)(hp1 + 512 + l * 4);
#pragma unroll
            for (int jj = 0; jj < 4; jj++)
                acc[8 + jj] += (float)g01[jj] * w01 + (float)g11[jj] * w11;
        }
    }
    if (idx < degc) {
        int src = srcs[idx];
        float w0 = evs[idx * H + h0];
        const __bf16* hp = hb + (size_t)src * CH;
        bf16x8 hv = *(const bf16x8*)(hp + l * 8);
#pragma unroll
        for (int jj = 0; jj < 8; jj++) acc[jj] += (float)hv[jj] * w0;
        if (H == 6) {
            float w1 = evs[idx * H + h1i];
            bf16x4 hv1 = *(const bf16x4*)(hp + 512 + l * 4);
#pragma unroll
            for (int jj = 0; jj < 4; jj++) acc[8 + jj] += (float)hv1[jj] * w1;
        }
    }
    // fallback: uncached edges (deg > CAP; effectively never for this graph)
    for (int i2 = CAP + w; i2 < deg; i2 += 4) {
        int src = csr_src[s0 + i2];
        float ev = 0.f;
        if (l < H) {
            float al = asrc[src * H + l] + adst_n;
            al = al >= 0.f ? al : 0.2f * al;
            ev = __expf(al);
        }
        const __bf16* hp = hb + (size_t)src * CH;
        float wgt = __shfl(ev, h0);
        bf16x8 hv = *(const bf16x8*)(hp + l * 8);
#pragma unroll
        for (int jj = 0; jj < 8; jj++) acc[jj] += (float)hv[jj] * wgt;
        if (H == 6) {
            float wg1 = __shfl(ev, h1i);
            bf16x4 hv1 = *(const bf16x4*)(hp + 512 + l * 4);
#pragma unroll
            for (int jj = 0; jj < 4; jj++) acc[8 + jj] += (float)hv1[jj] * wg1;
        }
    }

    *(f32x4*)(sm + w * CH + l * 8)     = *(f32x4*)(acc);
    *(f32x4*)(sm + w * CH + l * 8 + 4) = *(f32x4*)(acc + 4);
    if (H == 6)
        *(f32x4*)(sm + w * CH + 512 + l * 4) = *(f32x4*)(acc + 8);
    __syncthreads();

    float v = 0.f;
    if (t < 128) {
#pragma unroll
        for (int hh = 0; hh < H; hh++) {
            float hsum = 0.f;
#pragma unroll
            for (int ww = 0; ww < 4; ww++) hsum += sm[ww * CH + hh * 128 + t];
            v += hsum * invden[hh];
        }
        v = v * (1.f / H) + bias[t];
    }
    float sv = (t < 128) ? v : 0.f;
    float sq = (t < 128) ? v * v : 0.f;
#pragma unroll
    for (int off = 32; off; off >>= 1) {
        sv += __shfl_down(sv, off);
        sq += __shfl_down(sq, off);
    }
    if ((t & 63) == 0) { red[w * 2] = sv; red[w * 2 + 1] = sq; }
    __syncthreads();
    float tot = red[0] + red[2] + red[4] + red[6];
    float tsq = red[1] + red[3] + red[5] + red[7];
    float mu = tot * (1.f / 128.f);
    float var = tsq * (1.f / 128.f) - mu * mu;
    float r = rsqrtf(var + 1e-5f);
    if (t < 128) {
        float o = (v - mu) * r * gamma[t] + beta[t];
        out[(size_t)n * 128 + t] = fmaxf(o, 0.f);
    }
}

// per-node GCN aggregation from bf16 y; fp32 cat slice + optional swizzled bf16
__global__ void gcn_agg_kernel(const __bf16* __restrict__ y, int C,
                               const float* __restrict__ dinv,
                               const int* __restrict__ rowstart,
                               const int* __restrict__ csr_src,
                               const float* __restrict__ bias,
                               float* __restrict__ out, int ldo, int coloff,
                               __bf16* __restrict__ bout) {
    int n = blockIdx.x;
    int t = threadIdx.x;  // blockDim == C
    float acc = 0.f;
    int s0 = rowstart[n], s1 = rowstart[n + 1];
    for (int s = s0; s < s1; s++) {
        int src = csr_src[s];
        acc += (float)y[(size_t)src * C + t] * dinv[src];
    }
    float v = fmaxf(acc * dinv[n] + bias[t], 0.f);
    out[(size_t)n * ldo + coloff + t] = v;
    if (bout) {
        // swizzled layout for mfma_gemm2: idx = ((rt*16 + p)*64 + r)*8 + off
        int rt = n >> 6, r = n & 63, p = t >> 3, off = t & 7;
        bout[((size_t)(rt * 16 + p) * 64 + r) * 8 + off] = (__bf16)v;
    }
}

// ---------------------------------------------------------------------------
// Fused: fused=relu(cat@W_fuse+b_fuse); v=fused+relu(skippre+b_skip);
// LN(v) -> 64->32->16->5 MLP. 4 nodes/block (one per wave), W_fuse in LDS.
// ---------------------------------------------------------------------------
__global__ __launch_bounds__(256)
void fuse_final_kernel(const float* __restrict__ cat,
                       const float* __restrict__ skippre,
                       const float* __restrict__ Wf, const float* __restrict__ bfz,
                       const float* __restrict__ b_skip,
                       const float* __restrict__ g3, const float* __restrict__ be3,
                       const float* __restrict__ Wc1, const float* __restrict__ bc1,
                       const float* __restrict__ Wc2, const float* __restrict__ bc2,
                       const float* __restrict__ Wc3, const float* __restrict__ bc3,
                       float* __restrict__ out) {
    __shared__ float WfS[192 * 64];     // 48 KB
    __shared__ float catS[4][196];
    __shared__ float fS[4][64], h1S[4][32], h2S[4][16];
    int tid = threadIdx.x;
    int w = tid >> 6, l = tid & 63;
#pragma unroll
    for (int i = 0; i < 12; i++) {
        int idx = (i * 256 + tid) * 4;
        *(f32x4*)(WfS + idx) = *(const f32x4*)(Wf + idx);
    }
    int n = blockIdx.x * 4 + w;
    bool act = n < NN;
    float sk = 0.f;
    if (act) {
        catS[w][l]       = cat[(size_t)n * 192 + l];
        catS[w][64 + l]  = cat[(size_t)n * 192 + 64 + l];
        catS[w][128 + l] = cat[(size_t)n * 192 + 128 + l];
        sk = fmaxf(skippre[(size_t)n * 64 + l] + b_skip[l], 0.f);
    }
    __syncthreads();

    float fu = bfz[l];
#pragma unroll 4
    for (int k = 0; k < 192; k++)
        fu += catS[w][k] * WfS[k * 64 + l];
    float v = fmaxf(fu, 0.f) + sk;

    float sv = v, sq = v * v;
#pragma unroll
    for (int off = 32; off; off >>= 1) {
        sv += __shfl_xor(sv, off);
        sq += __shfl_xor(sq, off);
    }
    float mu = sv * (1.f / 64.f);
    float var = sq * (1.f / 64.f) - mu * mu;
    float r = rsqrtf(var + 1e-5f);
    fS[w][l] = (v - mu) * r * g3[l] + be3[l];
    __syncthreads();
    if (l < 32) {
        float a = bc1[l];
        for (int i = 0; i < 64; i++) a += fS[w][i] * Wc1[i * 32 + l];
        h1S[w][l] = fmaxf(a, 0.f);
    }
    __syncthreads();
    if (l < 16) {
        float a = bc2[l];
        for (int i = 0; i < 32; i++) a += h1S[w][i] * Wc2[i * 16 + l];
        h2S[w][l] = fmaxf(a, 0.f);
    }
    __syncthreads();
    if (l < 5 && act) {
        float a = bc3[l];
        for (int i = 0; i < 16; i++) a += h2S[w][i] * Wc3[i * 5 + l];
        out[(size_t)n * 5 + l] = a;
    }
}

// ---------------------------------------------------------------------------
extern "C" void kernel_launch(void* const* d_in, const int* in_sizes, int n_in,
                              void* d_out, int out_size, void* d_ws, size_t ws_size,
                              hipStream_t stream) {
    const float* x      = (const float*)d_in[0];
    const int*   ei     = (const int*)d_in[1];
    const float* W_gat1 = (const float*)d_in[2];
    const float* a_src1 = (const float*)d_in[3];
    const float* a_dst1 = (const float*)d_in[4];
    const float* b_gat1 = (const float*)d_in[5];
    const float* W_gcn1 = (const float*)d_in[6];
    const float* b_gcn1 = (const float*)d_in[7];
    const float* W_gat2 = (const float*)d_in[8];
    const float* a_src2 = (const float*)d_in[9];
    const float* a_dst2 = (const float*)d_in[10];
    const float* b_gat2 = (const float*)d_in[11];
    const float* W_gcn2 = (const float*)d_in[12];
    const float* b_gcn2 = (const float*)d_in[13];
    const float* W_skip = (const float*)d_in[14];
    const float* b_skip = (const float*)d_in[15];
    const float* W_fuse = (const float*)d_in[16];
    const float* b_fuse = (const float*)d_in[17];
    const float* W_c1   = (const float*)d_in[18];
    const float* b_c1   = (const float*)d_in[19];
    const float* W_c2   = (const float*)d_in[20];
    const float* b_c2   = (const float*)d_in[21];
    const float* W_c3   = (const float*)d_in[22];
    const float* b_c3   = (const float*)d_in[23];
    const float* g1     = (const float*)d_in[24];
    const float* be1    = (const float*)d_in[25];
    const float* g2     = (const float*)d_in[26];
    const float* be2    = (const float*)d_in[27];
    const float* g3     = (const float*)d_in[28];
    const float* be3    = (const float*)d_in[29];
    float* out = (float*)d_out;

    // workspace arena
    char* p = (char*)d_ws;
    auto alloc = [&](size_t bytes) {
        char* r = p; p += (bytes + 255) & ~(size_t)255; return r;
    };
    __bf16* xb      = (__bf16*)alloc((size_t)MPAD * KPAD * 2);   // 41.4 MB (swizzled)
    __bf16* wt      = (__bf16*)alloc((size_t)NPAD * KPAD * 2);   // 3.7 MB  (swizzled)
    __bf16* w2t     = (__bf16*)alloc((size_t)512 * 128 * 2);     // swizzled
    __bf16* h1b     = (__bf16*)alloc((size_t)NN * 768 * 2);      // 15.4 MB
    __bf16* h2b     = (__bf16*)alloc((size_t)NN * 512 * 2);      // 10.2 MB
    __bf16* ybufb   = (__bf16*)alloc((size_t)NN * 128 * 2);      // y1 reused y2
    __bf16* x1gcnb  = (__bf16*)alloc((size_t)MPAD * 128 * 2);    // swizzled, MFMA2 A
    float* asrc     = (float*)alloc((size_t)NN * 6 * 4);
    float* adst     = (float*)alloc((size_t)NN * 6 * 4);
    int*   deg      = (int*)  alloc((size_t)2 * NN * 4);         // deg | cursor
    int*   cursor   = deg + NN;
    float* dinv     = (float*)alloc((size_t)NN * 4);
    int*   rowst    = (int*)  alloc((size_t)(NN + 1) * 4);
    int*   csrc     = (int*)  alloc((size_t)ET * 4);
    float* x1gat    = (float*)alloc((size_t)NN * 128 * 4);
    float* cat      = (float*)alloc((size_t)NN * 192 * 4);
    float* x2gat    = (float*)alloc((size_t)NN * 128 * 4);
    float* skippre  = (float*)alloc((size_t)NN * 64 * 4);

    hipMemsetAsync(deg, 0, (size_t)2 * NN * 4, stream);
    hipMemsetAsync(x1gcnb, 0, (size_t)MPAD * 128 * 2, stream);  // pad rows interleaved

    const int EB = (ET + 255) / 256;
    const int MB = (NN + 63) / 64;

    // merged bf16 conversions (swizzled layouts)
    const int WBLK = (NW1 + 512 * 128 / 8 + 255) / 256;
    conv_kernel<<<NBX + WBLK, 256, 0, stream>>>(x, xb, W_gat1, W_skip, W_gat2, wt, w2t);

    // CSR by dst
    count_kernel  <<<EB, 256, 0, stream>>>(ei, deg);
    scan_kernel   <<<1, 256, 0, stream>>>(deg, rowst, dinv);
    scatter_kernel<<<EB, 256, 0, stream>>>(ei, rowst, cursor, csrc);

    // h1 (bf16) + skippre + fused alpha1, XCD-swizzled 64x128 BK=64, 4 waves
    mfma_gemm1_kernel<<<1120, 256, 0, stream>>>(xb, wt, a_src1, a_dst1,
                                                h1b, skippre, asrc, adst);

    // ---- GAT layer 1 (H=6) ----
    gat_agg_kernel<6><<<NN, 256, 0, stream>>>(h1b, asrc, adst, rowst, csrc,
                                              b_gat1, g1, be1, x1gat);
    // ---- GCN layer 1 (fp32 GEMM -> bf16 y) ----
    gemm_kernel<false, false, __bf16><<<dim3(2, MB), 256, 0, stream>>>(
        x1gat, 128, W_gcn1, 128, ybufb, 128, nullptr, NN, 128, 128);
    gcn_agg_kernel<<<NN, 128, 0, stream>>>(ybufb, 128, dinv, rowst, csrc,
                                           b_gcn1, cat, 192, 0, x1gcnb);
    // ---- GAT layer 2 (H=4): h2 + fused alpha2 (bf16 MFMA, 4 waves) ----
    mfma_gemm2_kernel<<<dim3(4, MPAD / 64), 256, 0, stream>>>(
        x1gcnb, w2t, a_src2, a_dst2, h2b, asrc, adst);
    gat_agg_kernel<4><<<NN, 256, 0, stream>>>(h2b, asrc, adst, rowst, csrc,
                                              b_gat2, g2, be2, x2gat);
    // ---- GCN layer 2 (fp32 GEMM -> bf16 y) -> cat[:, 128:192] ----
    gemm_kernel<false, false, __bf16><<<dim3(1, MB), 256, 0, stream>>>(
        x2gat, 128, W_gcn2, 64, ybufb, 64, nullptr, NN, 64, 128);
    gcn_agg_kernel<<<NN, 64, 0, stream>>>(ybufb, 64, dinv, rowst, csrc,
                                          b_gcn2, cat, 192, 128, nullptr);
    // ---- fuse + final (merged) ----
    fuse_final_kernel<<<(NN + 3) / 4, 256, 0, stream>>>(
        cat, skippre, W_fuse, b_fuse, b_skip, g3, be3,
        W_c1, b_c1, W_c2, b_c2, W_c3, b_c3, out);
}